// Round 1
// baseline (5552.928 us; speedup 1.0000x reference)
//
#include <hip/hip_runtime.h>
#include <math.h>

// Problem constants
constexpr int kB = 8, kT = 128, kN = 24, kD = 128, kM = 9, kH = 8, kL = 4, kFF = 1024;
constexpr int kF = 16;          // D/H
constexpr int kHD = 16;         // D/H
constexpr int kND = kN * kD;    // 3072
constexpr int kNM = kN * kM;    // 216
constexpr int kP = kB * kT;     // 1024 tokens, p = t*B + b

constexpr int BM = 64, BN = 64, BK = 16;

// Generic grouped GEMM: C[i,j] = sum_k A[i,k]*B[k,j] + bias[j]
// A idx = offAg1*g1 + offAg2*g2 + i*sAi + k          (k contiguous)
// B idx = offBg1*g1 + offBg2*g2 + (TRANSB ? j*ldB + k : k*ldB + j)
// C idx = offCg1*g1 + offCg2*g2 + i*sCi + j          (j contiguous)
// bias idx = sBg1*g1 + sBg2*g2 + j
template<bool TRANSB>
__global__ __launch_bounds__(256) void gemm_kernel(
    const float* __restrict__ A, const float* __restrict__ Bm,
    const float* __restrict__ bias, float* __restrict__ C,
    int Mr, int Nc, int K,
    int sAi, long offAg1, long offAg2,
    int ldB, long offBg1, long offBg2,
    int sCi, long offCg1, long offCg2,
    int sBg1, int sBg2, int G2)
{
  int g = blockIdx.z;
  int g1 = g / G2, g2 = g - g1 * G2;
  A += offAg1 * g1 + offAg2 * g2;
  Bm += offBg1 * g1 + offBg2 * g2;
  C += offCg1 * g1 + offCg2 * g2;
  long bOff = (long)sBg1 * g1 + (long)sBg2 * g2;

  int m0 = blockIdx.y * BM, n0 = blockIdx.x * BN;
  __shared__ float As[BK][BM + 4];
  __shared__ float Bs[BK][BN + 4];
  int tid = threadIdx.x;
  int tx = tid & 15, ty = tid >> 4;
  int r0 = ty * 4, c0 = tx * 4;
  float acc[4][4] = {};

  for (int kk = 0; kk < K; kk += BK) {
#pragma unroll
    for (int l = 0; l < 4; l++) {
      int idx = tid + l * 256;
      int k_l = idx & (BK - 1), m_l = idx / BK;
      int row = m0 + m_l, kg = kk + k_l;
      As[k_l][m_l] = (row < Mr && kg < K) ? A[(size_t)row * sAi + kg] : 0.f;
    }
#pragma unroll
    for (int l = 0; l < 4; l++) {
      int idx = tid + l * 256;
      int k_l, j_l;
      if (TRANSB) { k_l = idx & (BK - 1); j_l = idx / BK; }
      else        { j_l = idx & (BN - 1); k_l = idx / BN; }
      int col = n0 + j_l, kg = kk + k_l;
      float v = 0.f;
      if (col < Nc && kg < K)
        v = TRANSB ? Bm[(size_t)col * ldB + kg] : Bm[(size_t)kg * ldB + col];
      Bs[k_l][j_l] = v;
    }
    __syncthreads();
#pragma unroll
    for (int k = 0; k < BK; k++) {
      float av[4], bv[4];
#pragma unroll
      for (int i = 0; i < 4; i++) av[i] = As[k][r0 + i];
#pragma unroll
      for (int j = 0; j < 4; j++) bv[j] = Bs[k][c0 + j];
#pragma unroll
      for (int i = 0; i < 4; i++)
#pragma unroll
        for (int j = 0; j < 4; j++) acc[i][j] += av[i] * bv[j];
    }
    __syncthreads();
  }

#pragma unroll
  for (int i = 0; i < 4; i++) {
    int row = m0 + r0 + i;
    if (row >= Mr) continue;
#pragma unroll
    for (int j = 0; j < 4; j++) {
      int col = n0 + c0 + j;
      if (col >= Nc) continue;
      float bv = bias ? bias[bOff + col] : 0.f;
      C[(size_t)row * sCi + col] = acc[i][j] + bv;
    }
  }
}

// Embedding: h[p, n*D+d] = sum_m x4[b,t,n,m]*emb_W[n,m,d] + emb_b[n,d] + pe[b,c]
__global__ __launch_bounds__(256) void emb_kernel(
    const float* __restrict__ inp, const float* __restrict__ W,
    const float* __restrict__ bias, float* __restrict__ h)
{
  int p = blockIdx.x;
  int t = p / kB, b = p % kB;
  __shared__ float xs[kNM];
  for (int i = threadIdx.x; i < kNM; i += 256)
    xs[i] = inp[((size_t)b * kT + t) * kNM + i];
  __syncthreads();
  const float c1 = -logf(10000.f) / (float)kND;
  for (int c = threadIdx.x; c < kND; c += 256) {
    int n = c / kD, d = c % kD;
    float acc = bias[n * kD + d];
#pragma unroll
    for (int m = 0; m < kM; m++)
      acc += xs[n * kM + m] * W[(n * kM + m) * kD + d];
    float ang = (float)b * expf((float)(c & ~1) * c1);
    acc += (c & 1) ? cosf(ang) : sinf(ang);
    h[(size_t)p * kND + c] = acc;
  }
}

// Spatial attention: q,k,v in (H,P,N,F) layout; out sp[p, n*D + h*F + f]
__global__ __launch_bounds__(192) void sp_attn_kernel(
    const float* __restrict__ q, const float* __restrict__ k,
    const float* __restrict__ v, float* __restrict__ out)
{
  int p = blockIdx.x;
  __shared__ float qs[kH * kN * kF], ks[kH * kN * kF], vs[kH * kN * kF];
  for (int i = threadIdx.x; i < kH * kN * kF; i += 192) {
    int hh = i / (kN * kF), r = i % (kN * kF);
    size_t g = (size_t)(hh * kP + p) * (kN * kF) + r;
    qs[i] = q[g]; ks[i] = k[g]; vs[i] = v[g];
  }
  __syncthreads();
  int hh = threadIdx.x / kN, n = threadIdx.x % kN;  // 192 = H*N threads
  const float* qr = qs + (hh * kN + n) * kF;
  float sc[kN];
  float mx = -1e30f;
#pragma unroll
  for (int m = 0; m < kN; m++) {
    const float* kr = ks + (hh * kN + m) * kF;
    float s = 0.f;
#pragma unroll
    for (int f = 0; f < kF; f++) s += qr[f] * kr[f];
    s *= 0.25f;  // 1/sqrt(F)
    sc[m] = s;
    mx = fmaxf(mx, s);
  }
  float sum = 0.f;
#pragma unroll
  for (int m = 0; m < kN; m++) { float e = __expf(sc[m] - mx); sc[m] = e; sum += e; }
  float inv = 1.f / sum;
  float* orow = out + (size_t)p * kND + n * kD + hh * kF;
#pragma unroll
  for (int f = 0; f < kF; f++) {
    float acc = 0.f;
#pragma unroll
    for (int m = 0; m < kN; m++) acc += sc[m] * vs[(hh * kN + m) * kF + f];
    orow[f] = acc * inv;
  }
}

// Temporal attention, flash-style online softmax. qkv layout (P, N, 384):
// q at e, k at 128+e, v at 256+e with e = h*16+hd. mask adds +1.0 where s<t.
__global__ __launch_bounds__(128) void t_attn_kernel(
    const float* __restrict__ qkv, float* __restrict__ ot)
{
  int g = blockIdx.x;
  int hh = g % kH, n = (g / kH) % kN, b = g / (kH * kN);
  __shared__ float qs[kT][kHD], ks[kT][kHD], vs[kT][kHD];
  for (int i = threadIdx.x; i < kT * kHD; i += 128) {
    int tt = i / kHD, e = i % kHD;
    size_t base = ((size_t)(tt * kB + b) * kN + n) * (3 * kD) + hh * kHD + e;
    qs[tt][e] = qkv[base];
    ks[tt][e] = qkv[base + kD];
    vs[tt][e] = qkv[base + 2 * kD];
  }
  __syncthreads();
  int t = threadIdx.x;
  float qr[kHD];
#pragma unroll
  for (int e = 0; e < kHD; e++) qr[e] = qs[t][e];
  float m = -1e30f, lsum = 0.f;
  float acc[kHD] = {};
  for (int s = 0; s < kT; s++) {
    float x = 0.f;
#pragma unroll
    for (int e = 0; e < kHD; e++) x += qr[e] * ks[s][e];
    x = x * 0.25f + ((s < t) ? 1.f : 0.f);  // 1/sqrt(HD) + tril(-1) mask
    float mn = fmaxf(m, x);
    float scale = __expf(m - mn);
    float pp = __expf(x - mn);
    lsum = lsum * scale + pp;
#pragma unroll
    for (int e = 0; e < kHD; e++) acc[e] = acc[e] * scale + pp * vs[s][e];
    m = mn;
  }
  float inv = 1.f / lsum;
  float* orow = ot + (size_t)(t * kB + b) * kND + n * kD + hh * kHD;
#pragma unroll
  for (int e = 0; e < kHD; e++) orow[e] = acc[e] * inv;
}

// out[row] = LayerNorm(a[row] + b[row]) * g + be  (row length ND=3072, 256 thr)
__global__ __launch_bounds__(256) void add_ln_kernel(
    const float* __restrict__ a, const float* __restrict__ b,
    const float* __restrict__ g, const float* __restrict__ be,
    float* __restrict__ out)
{
  int row = blockIdx.x;
  const float* ar = a + (size_t)row * kND;
  const float* br = b + (size_t)row * kND;
  float* orow = out + (size_t)row * kND;
  float v[12];
  float s = 0.f;
#pragma unroll
  for (int i = 0; i < 12; i++) {
    int c = threadIdx.x + 256 * i;
    float x = ar[c] + br[c];
    v[i] = x; s += x;
  }
  __shared__ float red[4];
#pragma unroll
  for (int o = 32; o > 0; o >>= 1) s += __shfl_down(s, o, 64);
  int wid = threadIdx.x >> 6;
  if ((threadIdx.x & 63) == 0) red[wid] = s;
  __syncthreads();
  float mean = (red[0] + red[1] + red[2] + red[3]) * (1.f / kND);
  __syncthreads();
  float vs = 0.f;
#pragma unroll
  for (int i = 0; i < 12; i++) { float d = v[i] - mean; vs += d * d; }
#pragma unroll
  for (int o = 32; o > 0; o >>= 1) vs += __shfl_down(vs, o, 64);
  if ((threadIdx.x & 63) == 0) red[wid] = vs;
  __syncthreads();
  float var = (red[0] + red[1] + red[2] + red[3]) * (1.f / kND);
  float rstd = rsqrtf(var + 1e-5f);
#pragma unroll
  for (int i = 0; i < 12; i++) {
    int c = threadIdx.x + 256 * i;
    orow[c] = (v[i] - mean) * rstd * g[c] + be[c];
  }
}

__global__ __launch_bounds__(256) void add2_kernel(
    const float* __restrict__ a, const float* __restrict__ b, float* __restrict__ out)
{
  size_t i = (size_t)blockIdx.x * 256 + threadIdx.x;
  out[i] = a[i] + b[i];
}

// out[b,t,c] = fin[(t*B+b), c] + inputs[b,t,c]
__global__ __launch_bounds__(256) void final_add_kernel(
    const float* __restrict__ fin, const float* __restrict__ inp, float* __restrict__ out)
{
  int i = blockIdx.x * 256 + threadIdx.x;
  int c = i % kNM;
  int rem = i / kNM;
  int t = rem % kT, b = rem / kT;
  out[i] = fin[((size_t)(t * kB + b)) * kNM + c] + inp[i];
}

extern "C" void kernel_launch(void* const* d_in, const int* in_sizes, int n_in,
                              void* d_out, int out_size, void* d_ws, size_t ws_size,
                              hipStream_t stream)
{
  const float* inputs   = (const float*)d_in[0];
  const float* emb_W    = (const float*)d_in[1];
  const float* emb_b    = (const float*)d_in[2];
  const float* sp_Wq    = (const float*)d_in[3];
  const float* sp_bq    = (const float*)d_in[4];
  const float* sp_Wk    = (const float*)d_in[5];
  const float* sp_bk    = (const float*)d_in[6];
  const float* sp_Wv    = (const float*)d_in[7];
  const float* sp_bv    = (const float*)d_in[8];
  const float* tmp_Win  = (const float*)d_in[9];
  const float* tmp_bin  = (const float*)d_in[10];
  const float* tmp_Wout = (const float*)d_in[11];
  const float* tmp_bout = (const float*)d_in[12];
  const float* ff_W1    = (const float*)d_in[13];
  const float* ff_b1    = (const float*)d_in[14];
  const float* ff_W2    = (const float*)d_in[15];
  const float* ff_b2    = (const float*)d_in[16];
  const float* ln_g     = (const float*)d_in[17];
  const float* ln_b     = (const float*)d_in[18];
  const float* fin_W    = (const float*)d_in[19];
  const float* fin_b    = (const float*)d_in[20];
  float* out = (float*)d_out;

  // Workspace layout: 6 buffers of P*ND fp32 = 75.5 MB total
  float* ws = (float*)d_ws;
  const size_t SZ = (size_t)kP * kND;
  float* hb  = ws;           // h (residual stream), (P, ND)
  float* bA  = ws + SZ;      // spatial q (H,P,N,F) / tqkv part0 / tp / f1 / fin
  float* bB  = ws + 2 * SZ;  // spatial k / tqkv part1 / f2
  float* bC  = ws + 3 * SZ;  // spatial v / tqkv part2
  float* sp  = ws + 4 * SZ;  // sp_raw -> sp_ln -> a2
  float* otb = ws + 5 * SZ;  // temporal attn output (P, ND)

  emb_kernel<<<kP, 256, 0, stream>>>(inputs, emb_W, emb_b, hb);

  for (int l = 0; l < kL; l++) {
    const float* Wq  = sp_Wq    + (size_t)l * kH * kN * kD * kF;
    const float* bq  = sp_bq    + (size_t)l * kH * kN * kF;
    const float* Wk  = sp_Wk    + (size_t)l * kH * kD * kF;
    const float* bk  = sp_bk    + (size_t)l * kH * kF;
    const float* Wv  = sp_Wv    + (size_t)l * kH * kD * kF;
    const float* bv  = sp_bv    + (size_t)l * kH * kF;
    const float* Win = tmp_Win  + (size_t)l * kN * 3 * kD * kD;
    const float* bin = tmp_bin  + (size_t)l * kN * 3 * kD;
    const float* Wo  = tmp_Wout + (size_t)l * kN * kD * kD;
    const float* bo  = tmp_bout + (size_t)l * kN * kD;
    const float* W1  = ff_W1    + (size_t)l * kND * kFF;
    const float* b1  = ff_b1    + (size_t)l * kFF;
    const float* W2  = ff_W2    + (size_t)l * kFF * kND;
    const float* b2  = ff_b2    + (size_t)l * kND;
    const float* lg  = ln_g     + (size_t)l * kND;
    const float* lb  = ln_b     + (size_t)l * kND;

    // spatial q: groups (h,n); C layout (H,P,N,F)
    gemm_kernel<false><<<dim3(1, kP / BM, kH * kN), 256, 0, stream>>>(
        hb, Wq, bq, bA, kP, kF, kD,
        kND, 0L, (long)kD,
        kF, (long)kN * kD * kF, (long)kD * kF,
        kN * kF, (long)kP * kN * kF, (long)kF,
        kN * kF, kF, kN);
    // spatial k: rows (p,n), groups h
    gemm_kernel<false><<<dim3(1, (kP * kN) / BM, kH), 256, 0, stream>>>(
        hb, Wk, bk, bB, kP * kN, kF, kD,
        kD, 0L, 0L,
        kF, (long)kD * kF, 0L,
        kF, (long)kP * kN * kF, 0L,
        kF, 0, 1);
    // spatial v
    gemm_kernel<false><<<dim3(1, (kP * kN) / BM, kH), 256, 0, stream>>>(
        hb, Wv, bv, bC, kP * kN, kF, kD,
        kD, 0L, 0L,
        kF, (long)kD * kF, 0L,
        kF, (long)kP * kN * kF, 0L,
        kF, 0, 1);

    sp_attn_kernel<<<kP, 192, 0, stream>>>(bA, bB, bC, sp);
    add_ln_kernel<<<kP, 256, 0, stream>>>(sp, hb, lg, lb, sp);

    // temporal qkv: groups n, transposed-B; C layout (P, N, 384) in bA..bC
    gemm_kernel<true><<<dim3((3 * kD) / BN, kP / BM, kN), 256, 0, stream>>>(
        hb, Win, bin, bA, kP, 3 * kD, kD,
        kND, (long)kD, 0L,
        kD, (long)3 * kD * kD, 0L,
        kN * 3 * kD, (long)3 * kD, 0L,
        3 * kD, 0, 1);

    t_attn_kernel<<<kB * kN * kH, 128, 0, stream>>>(bA, otb);

    // temporal out-proj: groups n, transposed-B; writes tp into bA
    gemm_kernel<true><<<dim3(kD / BN, kP / BM, kN), 256, 0, stream>>>(
        otb, Wo, bo, bA, kP, kD, kD,
        kND, (long)kD, 0L,
        kD, (long)kD * kD, 0L,
        kND, (long)kD, 0L,
        kD, 0, 1);

    add_ln_kernel<<<kP, 256, 0, stream>>>(bA, hb, lg, lb, bA);   // tp_ln
    add2_kernel<<<(kP * kND) / 256, 256, 0, stream>>>(sp, bA, sp); // a2

    // FF1: (P,ND)@(ND,FF)
    gemm_kernel<false><<<dim3(kFF / BN, kP / BM, 1), 256, 0, stream>>>(
        sp, W1, b1, bA, kP, kFF, kND,
        kND, 0L, 0L,
        kFF, 0L, 0L,
        kFF, 0L, 0L,
        0, 0, 1);
    // FF2: (P,FF)@(FF,ND)
    gemm_kernel<false><<<dim3(kND / BN, kP / BM, 1), 256, 0, stream>>>(
        bA, W2, b2, bB, kP, kND, kFF,
        kFF, 0L, 0L,
        kND, 0L, 0L,
        kND, 0L, 0L,
        0, 0, 1);

    add_ln_kernel<<<kP, 256, 0, stream>>>(bB, sp, lg, lb, hb);   // h_next
  }

  // final projection + transpose + residual
  gemm_kernel<false><<<dim3((kNM + BN - 1) / BN, kP / BM, 1), 256, 0, stream>>>(
      hb, fin_W, fin_b, bA, kP, kNM, kND,
      kND, 0L, 0L,
      kNM, 0L, 0L,
      kNM, 0L, 0L,
      0, 0, 1);
  final_add_kernel<<<(kB * kT * kNM) / 256, 256, 0, stream>>>(bA, inputs, out);
}

// Round 2
// 1128.652 us; speedup vs baseline: 4.9200x; 4.9200x over previous
//
#include <hip/hip_runtime.h>
#include <hip/hip_bf16.h>
#include <math.h>

// Problem constants
constexpr int kB = 8, kT = 128, kN = 24, kD = 128, kM = 9, kH = 8, kL = 4, kFF = 1024;
constexpr int kF = 16;          // D/H
constexpr int kHD = 16;         // D/H
constexpr int kND = kN * kD;    // 3072
constexpr int kNM = kN * kM;    // 216
constexpr int kP = kB * kT;     // 1024 tokens, p = t*B + b

using bf16x8 = __attribute__((ext_vector_type(8))) short;
using f32x4  = __attribute__((ext_vector_type(4))) float;
typedef __hip_bfloat16 bf16;

__device__ __forceinline__ void load_lds16(const void* g, void* l) {
  __builtin_amdgcn_global_load_lds(
      (const __attribute__((address_space(1))) void*)g,
      (__attribute__((address_space(3))) void*)l, 16, 0, 0);
}

// ---------------------------------------------------------------------------
// MFMA bf16 GEMM. A (M x K) bf16, row stride sAi (k contiguous).
// B (Nc x K) bf16 pre-transposed, row stride K (k contiguous).
// C (M x Nc), row stride sCi, fp32 or bf16. Optional group dim g = blockIdx.z.
// Tile BM x BN per 256-thread block; 4 waves in 2x2; wave tile (BM/2)x(BN/2).
// ---------------------------------------------------------------------------
template<int BM, int BN, bool OUTBF>
__global__ __launch_bounds__(256) void mfma_gemm(
    const bf16* __restrict__ A, const bf16* __restrict__ Bm,
    const float* __restrict__ bias, void* __restrict__ Cv,
    int M, int Nc, int K, int sAi, int sCi,
    long offAg, long offBg, long offCg, int sBg)
{
  constexpr int WM = BM / 2, WN = BN / 2;
  constexpr int MT = WM / 16, NT = WN / 16;
  constexpr int ASLOTS = BM * 4;   // 16-B slots per A k-chunk (BM rows x 64 B)
  constexpr int BSLOTS = BN * 4;
  __shared__ __align__(16) bf16 As[BM * 32];
  __shared__ __align__(16) bf16 Bs[BN * 32];

  int g = blockIdx.z;
  A  += offAg * g;
  Bm += offBg * g;
  long cbase = offCg * (long)g;
  int bOff = sBg * g;

  int m0 = blockIdx.y * BM, n0 = blockIdx.x * BN;
  int tid = threadIdx.x, lane = tid & 63, wave = tid >> 6;
  int wm = wave >> 1, wn = wave & 1;
  int fr = lane & 15, fq = lane >> 4;

  f32x4 acc[MT][NT] = {};

  for (int kk = 0; kk < K; kk += 32) {
#pragma unroll
    for (int s = tid; s < ASLOTS; s += 256) {
      int m = s >> 2, k8 = (s & 3) * 8;
      load_lds16(A + (size_t)(m0 + m) * sAi + (kk + k8), &As[s * 8]);
    }
#pragma unroll
    for (int s = tid; s < BSLOTS; s += 256) {
      int n = s >> 2, k8 = (s & 3) * 8;
      int nr = n0 + n; if (nr > Nc - 1) nr = Nc - 1;   // clamp ragged N (garbage cols never stored)
      load_lds16(Bm + (size_t)nr * K + (kk + k8), &Bs[s * 8]);
    }
    __syncthreads();
    bf16x8 af[MT], bf[NT];
#pragma unroll
    for (int i = 0; i < MT; i++)
      af[i] = *(const bf16x8*)&As[(wm * WM + i * 16 + fr) * 32 + fq * 8];
#pragma unroll
    for (int j = 0; j < NT; j++)
      bf[j] = *(const bf16x8*)&Bs[(wn * WN + j * 16 + fr) * 32 + fq * 8];
#pragma unroll
    for (int i = 0; i < MT; i++)
#pragma unroll
      for (int j = 0; j < NT; j++)
        acc[i][j] = __builtin_amdgcn_mfma_f32_16x16x32_bf16(af[i], bf[j], acc[i][j], 0, 0, 0);
    __syncthreads();
  }

#pragma unroll
  for (int i = 0; i < MT; i++) {
    int row = m0 + wm * WM + i * 16 + fq * 4;
#pragma unroll
    for (int j = 0; j < NT; j++) {
      int col = n0 + wn * WN + j * 16 + fr;
      if (col < Nc) {
        float bv = bias ? bias[bOff + col] : 0.f;
#pragma unroll
        for (int r = 0; r < 4; r++) {
          long ci = cbase + (size_t)(row + r) * sCi + col;
          float v = acc[i][j][r] + bv;
          if (OUTBF) ((bf16*)Cv)[ci] = __float2bfloat16(v);
          else       ((float*)Cv)[ci] = v;
        }
      }
    }
  }
}

// ---------------------------------------------------------------------------
// Weight prep kernels (run every call; weights restored by harness each call)
// ---------------------------------------------------------------------------

// fp32 (R x C) -> bf16 (C x R), batched over z
__global__ __launch_bounds__(256) void trans_cvt_kernel(
    const float* __restrict__ in, bf16* __restrict__ out,
    int R, int C, long inStrideZ, long outStrideZ)
{
  __shared__ float t[64][65];
  int c0 = blockIdx.x * 64, r0 = blockIdx.y * 64;
  in  += inStrideZ  * blockIdx.z;
  out += outStrideZ * blockIdx.z;
  int tx = threadIdx.x & 63, ty = threadIdx.x >> 6;
  for (int rr = ty; rr < 64; rr += 4) {
    int r = r0 + rr, c = c0 + tx;
    t[rr][tx] = (r < R && c < C) ? in[(size_t)r * C + c] : 0.f;
  }
  __syncthreads();
  for (int cc = ty; cc < 64; cc += 4) {
    int c = c0 + cc, r = r0 + tx;
    if (c < C && r < R) out[(size_t)c * R + r] = __float2bfloat16(t[tx][cc]);
  }
}

__global__ __launch_bounds__(256) void cvt_kernel(
    const float* __restrict__ in, bf16* __restrict__ out, int n)
{
  int i = blockIdx.x * 256 + threadIdx.x;
  if (i < n) out[i] = __float2bfloat16(in[i]);
}

// Combined spatial qkv weight: out[((l*24+n)*384 + r)*128 + d]
// r<128: q row h*16+f from sp_Wq[l,h,n,d,f]; 128..255: k from sp_Wk[l,h,d,f]; 256..: v
__global__ __launch_bounds__(256) void build_spW_kernel(
    const float* __restrict__ Wq, const float* __restrict__ Wk,
    const float* __restrict__ Wv, bf16* __restrict__ outW)
{
  int i = blockIdx.x * 256 + threadIdx.x;   // total L*24*384*128
  int d = i & 127;
  int rest = i >> 7;
  int r = rest % 384;
  int n = (rest / 384) % 24;
  int l = rest / (384 * 24);
  int hh = (r & 127) >> 4, f = r & 15;
  float v;
  if (r < 128)      v = Wq[((((size_t)l * kH + hh) * kN + n) * kD + d) * kF + f];
  else if (r < 256) v = Wk[(((size_t)l * kH + hh) * kD + d) * kF + f];
  else              v = Wv[(((size_t)l * kH + hh) * kD + d) * kF + f];
  outW[i] = __float2bfloat16(v);
}

__global__ __launch_bounds__(256) void build_spb_kernel(
    const float* __restrict__ bq, const float* __restrict__ bk,
    const float* __restrict__ bv, float* __restrict__ outb)
{
  int i = blockIdx.x * 256 + threadIdx.x;   // total L*24*384
  if (i >= kL * 24 * 384) return;
  int r = i % 384;
  int n = (i / 384) % 24;
  int l = i / (384 * 24);
  int hh = (r & 127) >> 4, f = r & 15;
  float v;
  if (r < 128)      v = bq[(((size_t)l * kH + hh) * kN + n) * kF + f];
  else if (r < 256) v = bk[((size_t)l * kH + hh) * kF + f];
  else              v = bv[((size_t)l * kH + hh) * kF + f];
  outb[i] = v;
}

// ---------------------------------------------------------------------------
// Embedding: h[p, n*D+d] = sum_m x4[b,t,n,m]*emb_W[n,m,d] + emb_b + pos_enc
// ---------------------------------------------------------------------------
__global__ __launch_bounds__(256) void emb_kernel(
    const float* __restrict__ inp, const float* __restrict__ W,
    const float* __restrict__ bias, float* __restrict__ h, bf16* __restrict__ hbb)
{
  int p = blockIdx.x;
  int t = p / kB, b = p % kB;
  __shared__ float xs[kNM];
  for (int i = threadIdx.x; i < kNM; i += 256)
    xs[i] = inp[((size_t)b * kT + t) * kNM + i];
  __syncthreads();
  const float c1 = -logf(10000.f) / (float)kND;
  for (int c = threadIdx.x; c < kND; c += 256) {
    int n = c / kD, d = c % kD;
    float acc = bias[n * kD + d];
#pragma unroll
    for (int m = 0; m < kM; m++)
      acc += xs[n * kM + m] * W[(n * kM + m) * kD + d];
    float ang = (float)b * expf((float)(c & ~1) * c1);
    acc += (c & 1) ? cosf(ang) : sinf(ang);
    h[(size_t)p * kND + c] = acc;
    hbb[(size_t)p * kND + c] = __float2bfloat16(acc);
  }
}

// ---------------------------------------------------------------------------
// Spatial attention. qkv layout (n, p, 384): q at c=h*16+f, k at +128, v at +256
// out sp[p, n*128 + h*16 + f]
// ---------------------------------------------------------------------------
__global__ __launch_bounds__(192) void sp_attn_kernel(
    const float* __restrict__ qkv, float* __restrict__ out)
{
  int p = blockIdx.x;
  __shared__ float s[24 * 385];
  for (int i = threadIdx.x; i < 24 * 384; i += 192) {
    int n = i / 384, c = i % 384;
    s[n * 385 + c] = qkv[((size_t)n * kP + p) * 384 + c];
  }
  __syncthreads();
  int hh = threadIdx.x / 24, n = threadIdx.x % 24;
  const float* qr = s + n * 385 + hh * 16;
  float sc[24];
  float mx = -1e30f;
#pragma unroll
  for (int m = 0; m < 24; m++) {
    const float* kr = s + m * 385 + 128 + hh * 16;
    float d = 0.f;
#pragma unroll
    for (int f = 0; f < 16; f++) d += qr[f] * kr[f];
    d *= 0.25f;
    sc[m] = d;
    mx = fmaxf(mx, d);
  }
  float sum = 0.f;
#pragma unroll
  for (int m = 0; m < 24; m++) { float e = __expf(sc[m] - mx); sc[m] = e; sum += e; }
  float inv = 1.f / sum;
  float* orow = out + (size_t)p * kND + n * kD + hh * 16;
#pragma unroll
  for (int f = 0; f < 16; f++) {
    float acc = 0.f;
#pragma unroll
    for (int m = 0; m < 24; m++) acc += sc[m] * s[m * 385 + 256 + hh * 16 + f];
    orow[f] = acc * inv;
  }
}

// ---------------------------------------------------------------------------
// Temporal attention (flash-style). qkv layout (n, p, 384).
// out otb bf16 (n, p, 128), col h*16+e
// ---------------------------------------------------------------------------
__global__ __launch_bounds__(128) void t_attn_kernel(
    const float* __restrict__ qkv, bf16* __restrict__ ot)
{
  int g = blockIdx.x;
  int hh = g & 7, n = (g >> 3) % 24, b = g / (8 * 24);
  __shared__ float qs[kT][kHD], ks[kT][kHD], vs[kT][kHD];
  for (int i = threadIdx.x; i < kT * kHD; i += 128) {
    int tt = i / kHD, e = i % kHD;
    size_t base = ((size_t)n * kP + tt * kB + b) * 384 + hh * 16 + e;
    qs[tt][e] = qkv[base];
    ks[tt][e] = qkv[base + 128];
    vs[tt][e] = qkv[base + 256];
  }
  __syncthreads();
  int t = threadIdx.x;
  float qr[kHD];
#pragma unroll
  for (int e = 0; e < kHD; e++) qr[e] = qs[t][e];
  float m = -1e30f, lsum = 0.f;
  float acc[kHD] = {};
  for (int s = 0; s < kT; s++) {
    float x = 0.f;
#pragma unroll
    for (int e = 0; e < kHD; e++) x += qr[e] * ks[s][e];
    x = x * 0.25f + ((s < t) ? 1.f : 0.f);  // /sqrt(16) + tril(-1) additive mask
    float mn = fmaxf(m, x);
    float scale = __expf(m - mn);
    float pp = __expf(x - mn);
    lsum = lsum * scale + pp;
#pragma unroll
    for (int e = 0; e < kHD; e++) acc[e] = acc[e] * scale + pp * vs[s][e];
    m = mn;
  }
  float inv = 1.f / lsum;
  bf16* orow = ot + ((size_t)n * kP + t * kB + b) * 128 + hh * 16;
#pragma unroll
  for (int e = 0; e < kHD; e++) orow[e] = __float2bfloat16(acc[e] * inv);
}

// ---------------------------------------------------------------------------
// Fused: a2 = LN(sp+h) + LN(tp+h); writes a2 fp32 + bf16
// ---------------------------------------------------------------------------
__global__ __launch_bounds__(256) void fuse_a2_kernel(
    const float* __restrict__ sp, const float* __restrict__ tp,
    const float* __restrict__ h, const float* __restrict__ g,
    const float* __restrict__ be, float* __restrict__ a2, bf16* __restrict__ a2b)
{
  int row = blockIdx.x;
  const float* s1p = sp + (size_t)row * kND;
  const float* s2p = tp + (size_t)row * kND;
  const float* hp  = h  + (size_t)row * kND;
  float x1[12], x2[12];
  float sum1 = 0.f, sum2 = 0.f;
#pragma unroll
  for (int i = 0; i < 12; i++) {
    int c = threadIdx.x + 256 * i;
    float hv = hp[c];
    x1[i] = s1p[c] + hv; x2[i] = s2p[c] + hv;
    sum1 += x1[i]; sum2 += x2[i];
  }
  __shared__ float red1[4], red2[4];
#pragma unroll
  for (int o = 32; o > 0; o >>= 1) { sum1 += __shfl_down(sum1, o, 64); sum2 += __shfl_down(sum2, o, 64); }
  int wid = threadIdx.x >> 6;
  if ((threadIdx.x & 63) == 0) { red1[wid] = sum1; red2[wid] = sum2; }
  __syncthreads();
  float mean1 = (red1[0] + red1[1] + red1[2] + red1[3]) * (1.f / kND);
  float mean2 = (red2[0] + red2[1] + red2[2] + red2[3]) * (1.f / kND);
  __syncthreads();
  float v1 = 0.f, v2 = 0.f;
#pragma unroll
  for (int i = 0; i < 12; i++) {
    float d1 = x1[i] - mean1, d2 = x2[i] - mean2;
    v1 += d1 * d1; v2 += d2 * d2;
  }
#pragma unroll
  for (int o = 32; o > 0; o >>= 1) { v1 += __shfl_down(v1, o, 64); v2 += __shfl_down(v2, o, 64); }
  if ((threadIdx.x & 63) == 0) { red1[wid] = v1; red2[wid] = v2; }
  __syncthreads();
  float r1 = rsqrtf((red1[0] + red1[1] + red1[2] + red1[3]) * (1.f / kND) + 1e-5f);
  float r2 = rsqrtf((red2[0] + red2[1] + red2[2] + red2[3]) * (1.f / kND) + 1e-5f);
#pragma unroll
  for (int i = 0; i < 12; i++) {
    int c = threadIdx.x + 256 * i;
    float gc = g[c], bc = be[c];
    float o = (x1[i] - mean1) * r1 * gc + bc + (x2[i] - mean2) * r2 * gc + bc;
    a2[(size_t)row * kND + c] = o;
    a2b[(size_t)row * kND + c] = __float2bfloat16(o);
  }
}

// out = LN(a + b); writes fp32 + bf16
__global__ __launch_bounds__(256) void add_ln_dual_kernel(
    const float* __restrict__ a, const float* __restrict__ b,
    const float* __restrict__ g, const float* __restrict__ be,
    float* __restrict__ out, bf16* __restrict__ outb)
{
  int row = blockIdx.x;
  const float* ar = a + (size_t)row * kND;
  const float* br = b + (size_t)row * kND;
  float v[12];
  float s = 0.f;
#pragma unroll
  for (int i = 0; i < 12; i++) {
    int c = threadIdx.x + 256 * i;
    float x = ar[c] + br[c];
    v[i] = x; s += x;
  }
  __shared__ float red[4];
#pragma unroll
  for (int o = 32; o > 0; o >>= 1) s += __shfl_down(s, o, 64);
  int wid = threadIdx.x >> 6;
  if ((threadIdx.x & 63) == 0) red[wid] = s;
  __syncthreads();
  float mean = (red[0] + red[1] + red[2] + red[3]) * (1.f / kND);
  __syncthreads();
  float vs = 0.f;
#pragma unroll
  for (int i = 0; i < 12; i++) { float d = v[i] - mean; vs += d * d; }
#pragma unroll
  for (int o = 32; o > 0; o >>= 1) vs += __shfl_down(vs, o, 64);
  if ((threadIdx.x & 63) == 0) red[wid] = vs;
  __syncthreads();
  float rstd = rsqrtf((red[0] + red[1] + red[2] + red[3]) * (1.f / kND) + 1e-5f);
#pragma unroll
  for (int i = 0; i < 12; i++) {
    int c = threadIdx.x + 256 * i;
    float o = (v[i] - mean) * rstd * g[c] + be[c];
    out[(size_t)row * kND + c] = o;
    outb[(size_t)row * kND + c] = __float2bfloat16(o);
  }
}

// out[b,t,c] = fin[(t*B+b), c] + inputs[b,t,c]
__global__ __launch_bounds__(256) void final_add_kernel(
    const float* __restrict__ fin, const float* __restrict__ inp, float* __restrict__ out)
{
  int i = blockIdx.x * 256 + threadIdx.x;
  int c = i % kNM;
  int rem = i / kNM;
  int t = rem % kT, b = rem / kT;
  out[i] = fin[((size_t)(t * kB + b)) * kNM + c] + inp[i];
}

// ---------------------------------------------------------------------------
extern "C" void kernel_launch(void* const* d_in, const int* in_sizes, int n_in,
                              void* d_out, int out_size, void* d_ws, size_t ws_size,
                              hipStream_t stream)
{
  const float* inputs   = (const float*)d_in[0];
  const float* emb_W    = (const float*)d_in[1];
  const float* emb_b    = (const float*)d_in[2];
  const float* sp_Wq    = (const float*)d_in[3];
  const float* sp_bq    = (const float*)d_in[4];
  const float* sp_Wk    = (const float*)d_in[5];
  const float* sp_bk    = (const float*)d_in[6];
  const float* sp_Wv    = (const float*)d_in[7];
  const float* sp_bv    = (const float*)d_in[8];
  const float* tmp_Win  = (const float*)d_in[9];
  const float* tmp_bin  = (const float*)d_in[10];
  const float* tmp_Wout = (const float*)d_in[11];
  const float* tmp_bout = (const float*)d_in[12];
  const float* ff_W1    = (const float*)d_in[13];
  const float* ff_b1    = (const float*)d_in[14];
  const float* ff_W2    = (const float*)d_in[15];
  const float* ff_b2    = (const float*)d_in[16];
  const float* ln_g     = (const float*)d_in[17];
  const float* ln_b     = (const float*)d_in[18];
  const float* fin_W    = (const float*)d_in[19];
  const float* fin_b    = (const float*)d_in[20];
  float* out = (float*)d_out;

  // ---- workspace layout (all 256-B aligned) ----
  char* wp = (char*)d_ws;
  size_t off = 0;
  auto alloc = [&](size_t bytes) { void* p = wp + off; off += (bytes + 255) & ~(size_t)255; return p; };
  bf16* spW   = (bf16*)alloc((size_t)kL * 24 * 384 * 128 * 2);
  bf16* tWb   = (bf16*)alloc((size_t)kL * 24 * 384 * 128 * 2);
  bf16* toWb  = (bf16*)alloc((size_t)kL * 24 * 128 * 128 * 2);
  bf16* W1t   = (bf16*)alloc((size_t)kL * kFF * kND * 2);
  bf16* W2t   = (bf16*)alloc((size_t)kL * kND * kFF * 2);
  bf16* finWt = (bf16*)alloc((size_t)kNM * kND * 2);
  float* spb  = (float*)alloc((size_t)kL * 24 * 384 * 4);
  float* hb   = (float*)alloc((size_t)kP * kND * 4);
  bf16*  hbb  = (bf16*) alloc((size_t)kP * kND * 2);
  float* qkv  = (float*)alloc((size_t)24 * kP * 384 * 4);   // shared spatial/temporal
  float* sp   = (float*)alloc((size_t)kP * kND * 4);        // also final GEMM out
  float* tp   = (float*)alloc((size_t)kP * kND * 4);        // also FF2 out
  float* a2   = (float*)alloc((size_t)kP * kND * 4);
  bf16*  a2b  = (bf16*) alloc((size_t)kP * kND * 2);
  bf16*  f1b  = (bf16*) alloc((size_t)kP * kFF * 2);
  bf16*  otb  = (bf16*) alloc((size_t)24 * kP * 128 * 2);
  float* finout = sp;

  // ---- weight prep ----
  trans_cvt_kernel<<<dim3(kFF / 64, kND / 64, kL), 256, 0, stream>>>(
      ff_W1, W1t, kND, kFF, (long)kND * kFF, (long)kFF * kND);
  trans_cvt_kernel<<<dim3(kND / 64, kFF / 64, kL), 256, 0, stream>>>(
      ff_W2, W2t, kFF, kND, (long)kFF * kND, (long)kND * kFF);
  trans_cvt_kernel<<<dim3((kNM + 63) / 64, kND / 64, 1), 256, 0, stream>>>(
      fin_W, finWt, kND, kNM, 0L, 0L);
  cvt_kernel<<<(kL * 24 * 384 * 128 + 255) / 256, 256, 0, stream>>>(
      tmp_Win, tWb, kL * 24 * 384 * 128);
  cvt_kernel<<<(kL * 24 * 128 * 128 + 255) / 256, 256, 0, stream>>>(
      tmp_Wout, toWb, kL * 24 * 128 * 128);
  build_spW_kernel<<<(kL * 24 * 384 * 128) / 256, 256, 0, stream>>>(
      sp_Wq, sp_Wk, sp_Wv, spW);
  build_spb_kernel<<<(kL * 24 * 384 + 255) / 256, 256, 0, stream>>>(
      sp_bq, sp_bk, sp_bv, spb);

  emb_kernel<<<kP, 256, 0, stream>>>(inputs, emb_W, emb_b, hb, hbb);

  for (int l = 0; l < kL; l++) {
    const float* lg = ln_g + (size_t)l * kND;
    const float* lb = ln_b + (size_t)l * kND;

    // spatial qkv: groups n; C = qkv (n, p, 384) fp32
    mfma_gemm<128, 128, false><<<dim3(3, 8, 24), 256, 0, stream>>>(
        hbb, spW + (size_t)l * 24 * 384 * 128, spb + (size_t)l * 24 * 384, qkv,
        kP, 384, 128, /*sAi*/kND, /*sCi*/384,
        /*offAg*/128, /*offBg*/384 * 128, /*offCg*/(long)kP * 384, /*sBg*/384);
    sp_attn_kernel<<<kP, 192, 0, stream>>>(qkv, sp);

    // temporal qkv: same shape, Win weights; reuses qkv buffer
    mfma_gemm<128, 128, false><<<dim3(3, 8, 24), 256, 0, stream>>>(
        hbb, tWb + (size_t)l * 24 * 384 * 128, tmp_bin + (size_t)l * 24 * 384, qkv,
        kP, 384, 128, kND, 384,
        128, 384 * 128, (long)kP * 384, 384);
    t_attn_kernel<<<kB * 24 * 8, 128, 0, stream>>>(qkv, otb);

    // temporal out-proj: A = otb (n,p,128) bf16 -> tp (p, ND) fp32
    mfma_gemm<128, 128, false><<<dim3(1, 8, 24), 256, 0, stream>>>(
        otb, toWb + (size_t)l * 24 * 128 * 128, tmp_bout + (size_t)l * 24 * 128, tp,
        kP, 128, 128, /*sAi*/128, /*sCi*/kND,
        /*offAg*/(long)kP * 128, /*offBg*/128 * 128, /*offCg*/128, /*sBg*/128);

    fuse_a2_kernel<<<kP, 256, 0, stream>>>(sp, tp, hb, lg, lb, a2, a2b);

    // FF1: (P,ND)@(ND,FF) -> f1b bf16. 64-tile for 256 blocks.
    mfma_gemm<64, 64, true><<<dim3(kFF / 64, kP / 64, 1), 256, 0, stream>>>(
        a2b, W1t + (size_t)l * kFF * kND, ff_b1 + (size_t)l * kFF, f1b,
        kP, kFF, kND, kND, kFF, 0, 0, 0, 0);
    // FF2: (P,FF)@(FF,ND) -> tp (reused) fp32
    mfma_gemm<128, 128, false><<<dim3(kND / 128, kP / 128, 1), 256, 0, stream>>>(
        f1b, W2t + (size_t)l * kND * kFF, ff_b2 + (size_t)l * kND, tp,
        kP, kND, kFF, kFF, kND, 0, 0, 0, 0);

    add_ln_dual_kernel<<<kP, 256, 0, stream>>>(tp, a2, lg, lb, hb, hbb);
  }

  // final projection (ragged N=216) + transpose + residual
  mfma_gemm<64, 64, false><<<dim3((kNM + 63) / 64, kP / 64, 1), 256, 0, stream>>>(
      hbb, finWt, fin_b, finout,
      kP, kNM, kND, kND, kNM, 0, 0, 0, 0);
  final_add_kernel<<<(kB * kT * kNM) / 256, 256, 0, stream>>>(finout, inputs, out);
}

// Round 3
// 1009.114 us; speedup vs baseline: 5.5028x; 1.1185x over previous
//
#include <hip/hip_runtime.h>
#include <hip/hip_bf16.h>
#include <math.h>

// Problem constants
constexpr int kB = 8, kT = 128, kN = 24, kD = 128, kM = 9, kH = 8, kL = 4, kFF = 1024;
constexpr int kF = 16;          // D/H
constexpr int kHD = 16;         // D/H
constexpr int kND = kN * kD;    // 3072
constexpr int kNM = kN * kM;    // 216
constexpr int kP = kB * kT;     // 1024 tokens, p = t*B + b

using bf16x8 = __attribute__((ext_vector_type(8))) short;
using f32x4  = __attribute__((ext_vector_type(4))) float;
typedef __hip_bfloat16 bf16;

__device__ __forceinline__ void load_lds16(const void* g, void* l) {
  __builtin_amdgcn_global_load_lds(
      (const __attribute__((address_space(1))) void*)g,
      (__attribute__((address_space(3))) void*)l, 16, 0, 0);
}

// ---------------------------------------------------------------------------
// MFMA bf16 GEMM. A (M x K) bf16, row stride sAi (k contiguous).
// B (Nc x K) bf16 pre-transposed, row stride K (k contiguous).
// C (M x Nc), row stride sCi, fp32 or bf16. Optional group dim g = blockIdx.z.
// 256 threads, 4 waves in 2x2; wave tile (BM/2)x(BN/2).
// ---------------------------------------------------------------------------
template<int BM, int BN, bool OUTBF>
__global__ __launch_bounds__(256) void mfma_gemm(
    const bf16* __restrict__ A, const bf16* __restrict__ Bm,
    const float* __restrict__ bias, void* __restrict__ Cv,
    int M, int Nc, int K, int sAi, int sCi,
    long offAg, long offBg, long offCg, int sBg)
{
  constexpr int WM = BM / 2, WN = BN / 2;
  constexpr int MT = WM / 16, NT = WN / 16;
  constexpr int ASLOTS = BM * 4;   // 16-B slots per A k-chunk (BM rows x 64 B)
  constexpr int BSLOTS = BN * 4;
  __shared__ __align__(16) bf16 As[BM * 32];
  __shared__ __align__(16) bf16 Bs[BN * 32];

  int g = blockIdx.z;
  A  += offAg * g;
  Bm += offBg * g;
  long cbase = offCg * (long)g;
  int bOff = sBg * g;

  int m0 = blockIdx.y * BM, n0 = blockIdx.x * BN;
  int tid = threadIdx.x, lane = tid & 63, wave = tid >> 6;
  int wm = wave >> 1, wn = wave & 1;
  int fr = lane & 15, fq = lane >> 4;

  f32x4 acc[MT][NT] = {};

  for (int kk = 0; kk < K; kk += 32) {
#pragma unroll
    for (int s = tid; s < ASLOTS; s += 256) {
      int m = s >> 2, k8 = (s & 3) * 8;
      load_lds16(A + (size_t)(m0 + m) * sAi + (kk + k8), &As[s * 8]);
    }
#pragma unroll
    for (int s = tid; s < BSLOTS; s += 256) {
      int n = s >> 2, k8 = (s & 3) * 8;
      int nr = n0 + n; if (nr > Nc - 1) nr = Nc - 1;   // clamp ragged N
      load_lds16(Bm + (size_t)nr * K + (kk + k8), &Bs[s * 8]);
    }
    __syncthreads();
    bf16x8 af[MT], bf[NT];
#pragma unroll
    for (int i = 0; i < MT; i++)
      af[i] = *(const bf16x8*)&As[(wm * WM + i * 16 + fr) * 32 + fq * 8];
#pragma unroll
    for (int j = 0; j < NT; j++)
      bf[j] = *(const bf16x8*)&Bs[(wn * WN + j * 16 + fr) * 32 + fq * 8];
#pragma unroll
    for (int i = 0; i < MT; i++)
#pragma unroll
      for (int j = 0; j < NT; j++)
        acc[i][j] = __builtin_amdgcn_mfma_f32_16x16x32_bf16(af[i], bf[j], acc[i][j], 0, 0, 0);
    __syncthreads();
  }

#pragma unroll
  for (int i = 0; i < MT; i++) {
    int row = m0 + wm * WM + i * 16 + fq * 4;
#pragma unroll
    for (int j = 0; j < NT; j++) {
      int col = n0 + wn * WN + j * 16 + fr;
      if (col < Nc) {
        float bv = bias ? bias[bOff + col] : 0.f;
#pragma unroll
        for (int r = 0; r < 4; r++) {
          long ci = cbase + (size_t)(row + r) * sCi + col;
          float v = acc[i][j][r] + bv;
          if (OUTBF) ((bf16*)Cv)[ci] = __float2bfloat16(v);
          else       ((float*)Cv)[ci] = v;
        }
      }
    }
  }
}

// ---------------------------------------------------------------------------
// Weight prep kernels (run every call; harness re-poisons d_ws each call)
// ---------------------------------------------------------------------------

// fp32 (R x C) -> bf16 (C x R), batched over z
__global__ __launch_bounds__(256) void trans_cvt_kernel(
    const float* __restrict__ in, bf16* __restrict__ out,
    int R, int C, long inStrideZ, long outStrideZ)
{
  __shared__ float t[64][65];
  int c0 = blockIdx.x * 64, r0 = blockIdx.y * 64;
  in  += inStrideZ  * blockIdx.z;
  out += outStrideZ * blockIdx.z;
  int tx = threadIdx.x & 63, ty = threadIdx.x >> 6;
  for (int rr = ty; rr < 64; rr += 4) {
    int r = r0 + rr, c = c0 + tx;
    t[rr][tx] = (r < R && c < C) ? in[(size_t)r * C + c] : 0.f;
  }
  __syncthreads();
  for (int cc = ty; cc < 64; cc += 4) {
    int c = c0 + cc, r = r0 + tx;
    if (c < C && r < R) out[(size_t)c * R + r] = __float2bfloat16(t[tx][cc]);
  }
}

__global__ __launch_bounds__(256) void cvt_kernel(
    const float* __restrict__ in, bf16* __restrict__ out, int n)
{
  int i = blockIdx.x * 256 + threadIdx.x;
  if (i < n) out[i] = __float2bfloat16(in[i]);
}

// Combined qkv weight (spatial + temporal): out[((l*24+n)*768 + r)*128 + d]
// r<128: spatial q (row h*16+f); 128..255: spatial k; 256..383: spatial v;
// 384..767: temporal Win row (r-384)
__global__ __launch_bounds__(256) void build_spW_kernel(
    const float* __restrict__ Wq, const float* __restrict__ Wk,
    const float* __restrict__ Wv, const float* __restrict__ Win,
    bf16* __restrict__ outW)
{
  int i = blockIdx.x * 256 + threadIdx.x;   // total L*24*768*128
  int d = i & 127;
  int rest = i >> 7;
  int r = rest % 768;
  int n = (rest / 768) % 24;
  int l = rest / (768 * 24);
  int hh = (r & 127) >> 4, f = r & 15;
  float v;
  if (r < 128)      v = Wq[((((size_t)l * kH + hh) * kN + n) * kD + d) * kF + f];
  else if (r < 256) v = Wk[(((size_t)l * kH + hh) * kD + d) * kF + f];
  else if (r < 384) v = Wv[(((size_t)l * kH + hh) * kD + d) * kF + f];
  else              v = Win[(((size_t)l * kN + n) * 384 + (r - 384)) * kD + d];
  outW[i] = __float2bfloat16(v);
}

__global__ __launch_bounds__(256) void build_spb_kernel(
    const float* __restrict__ bq, const float* __restrict__ bk,
    const float* __restrict__ bv, const float* __restrict__ bin,
    float* __restrict__ outb)
{
  int i = blockIdx.x * 256 + threadIdx.x;   // total L*24*768
  if (i >= kL * 24 * 768) return;
  int r = i % 768;
  int n = (i / 768) % 24;
  int l = i / (768 * 24);
  int hh = (r & 127) >> 4, f = r & 15;
  float v;
  if (r < 128)      v = bq[(((size_t)l * kH + hh) * kN + n) * kF + f];
  else if (r < 256) v = bk[((size_t)l * kH + hh) * kF + f];
  else if (r < 384) v = bv[((size_t)l * kH + hh) * kF + f];
  else              v = bin[((size_t)l * kN + n) * 384 + (r - 384)];
  outb[i] = v;
}

// ---------------------------------------------------------------------------
// Embedding
// ---------------------------------------------------------------------------
__global__ __launch_bounds__(256) void emb_kernel(
    const float* __restrict__ inp, const float* __restrict__ W,
    const float* __restrict__ bias, float* __restrict__ h, bf16* __restrict__ hbb)
{
  int p = blockIdx.x;
  int t = p / kB, b = p % kB;
  __shared__ float xs[kNM];
  for (int i = threadIdx.x; i < kNM; i += 256)
    xs[i] = inp[((size_t)b * kT + t) * kNM + i];
  __syncthreads();
  const float c1 = -logf(10000.f) / (float)kND;
  for (int c = threadIdx.x; c < kND; c += 256) {
    int n = c / kD, d = c % kD;
    float acc = bias[n * kD + d];
#pragma unroll
    for (int m = 0; m < kM; m++)
      acc += xs[n * kM + m] * W[(n * kM + m) * kD + d];
    float ang = (float)b * expf((float)(c & ~1) * c1);
    acc += (c & 1) ? cosf(ang) : sinf(ang);
    h[(size_t)p * kND + c] = acc;
    hbb[(size_t)p * kND + c] = __float2bfloat16(acc);
  }
}

// ---------------------------------------------------------------------------
// Spatial attention. qkv bf16 (n, p, 768): q at c=h*16+f, k at +128, v at +256
// out sp[p, n*128 + h*16 + f] fp32
// ---------------------------------------------------------------------------
__global__ __launch_bounds__(192) void sp_attn_kernel(
    const bf16* __restrict__ qkv, float* __restrict__ out)
{
  int p = blockIdx.x;
  __shared__ float s[24 * 385];
  for (int i = threadIdx.x; i < 24 * 384; i += 192) {
    int n = i / 384, c = i % 384;
    s[n * 385 + c] = __bfloat162float(qkv[((size_t)n * kP + p) * 768 + c]);
  }
  __syncthreads();
  int hh = threadIdx.x / 24, n = threadIdx.x % 24;
  const float* qr = s + n * 385 + hh * 16;
  float sc[24];
  float mx = -1e30f;
#pragma unroll
  for (int m = 0; m < 24; m++) {
    const float* kr = s + m * 385 + 128 + hh * 16;
    float d = 0.f;
#pragma unroll
    for (int f = 0; f < 16; f++) d += qr[f] * kr[f];
    d *= 0.25f;
    sc[m] = d;
    mx = fmaxf(mx, d);
  }
  float sum = 0.f;
#pragma unroll
  for (int m = 0; m < 24; m++) { float e = __expf(sc[m] - mx); sc[m] = e; sum += e; }
  float inv = 1.f / sum;
  float* orow = out + (size_t)p * kND + n * kD + hh * 16;
#pragma unroll
  for (int f = 0; f < 16; f++) {
    float acc = 0.f;
#pragma unroll
    for (int m = 0; m < 24; m++) acc += sc[m] * s[m * 385 + 256 + hh * 16 + f];
    orow[f] = acc * inv;
  }
}

// ---------------------------------------------------------------------------
// Temporal attention via MFMA. qkv bf16 (n, p, 768): temporal q at 384+h*16+e,
// k at 512+h*16+e, v at 640+h*16+e. One block per (b,n,h), 128 threads (2 waves).
// Wave w computes S rows [w*64, w*64+64) = Q·K^T (K-dim 16 padded to 32),
// softmax in C-layout regs, P->LDS [t][s] bf16, O = P·V via mfma.
// ot bf16 (n, p, 128) col h*16+e.
// ---------------------------------------------------------------------------
__global__ __launch_bounds__(128) void t_attn_mfma(
    const bf16* __restrict__ qkv, bf16* __restrict__ ot)
{
  int g = blockIdx.x;
  int hh = g & 7, n = (g >> 3) % 24, b = g / 192;
  __shared__ __align__(16) ushort Qs[128][32];    // 8 KB, cols 16..31 zero
  __shared__ __align__(16) ushort Ks[128][32];    // 8 KB
  __shared__ __align__(16) ushort Vt[16][136];    // V^T [e][s], padded
  __shared__ __align__(16) ushort Ps[128][136];   // P [t][s], padded

  // stage: ushort2 loads (e pairs)
  for (int idx = threadIdx.x; idx < 1024; idx += 128) {
    int t = idx >> 3, e2 = (idx & 7) * 2;
    const ushort* src = (const ushort*)qkv +
        ((size_t)n * kP + (size_t)t * kB + b) * 768 + 384 + hh * 16 + e2;
    ushort2 q2 = *(const ushort2*)(src);
    ushort2 k2 = *(const ushort2*)(src + 128);
    ushort2 v2 = *(const ushort2*)(src + 256);
    *(ushort2*)&Qs[t][e2] = q2;
    *(ushort2*)&Ks[t][e2] = k2;
    *(ushort2*)&Qs[t][16 + e2] = make_ushort2(0, 0);
    *(ushort2*)&Ks[t][16 + e2] = make_ushort2(0, 0);
    Vt[e2][t] = v2.x;
    Vt[e2 + 1][t] = v2.y;
  }
  __syncthreads();

  int lane = threadIdx.x & 63, w = threadIdx.x >> 6;
  int c = lane & 15, quad = lane >> 4;

  // S = Q K^T : M=64 rows per wave (4 m-tiles), N=128 (8 n-tiles), K=32 (padded)
  bf16x8 aq[4];
#pragma unroll
  for (int mt = 0; mt < 4; mt++)
    aq[mt] = *(const bf16x8*)&Qs[w * 64 + mt * 16 + c][quad * 8];
  f32x4 acc[4][8];
#pragma unroll
  for (int nt = 0; nt < 8; nt++) {
    bf16x8 bk = *(const bf16x8*)&Ks[nt * 16 + c][quad * 8];
#pragma unroll
    for (int mt = 0; mt < 4; mt++) {
      f32x4 z = {0.f, 0.f, 0.f, 0.f};
      acc[mt][nt] = __builtin_amdgcn_mfma_f32_16x16x32_bf16(aq[mt], bk, z, 0, 0, 0);
    }
  }

  // softmax per row; rows t = w*64 + mt*16 + quad*4 + r, cols s = nt*16 + c
  f32x4 invv[4];
#pragma unroll
  for (int mt = 0; mt < 4; mt++) {
    int tbase = w * 64 + mt * 16 + quad * 4;
    f32x4 rm = {-1e30f, -1e30f, -1e30f, -1e30f};
#pragma unroll
    for (int nt = 0; nt < 8; nt++) {
      int s = nt * 16 + c;
#pragma unroll
      for (int r = 0; r < 4; r++) {
        float x = acc[mt][nt][r] * 0.25f + ((s < tbase + r) ? 1.f : 0.f);
        acc[mt][nt][r] = x;
        rm[r] = fmaxf(rm[r], x);
      }
    }
#pragma unroll
    for (int off = 1; off < 16; off <<= 1)
#pragma unroll
      for (int r = 0; r < 4; r++) rm[r] = fmaxf(rm[r], __shfl_xor(rm[r], off, 64));
    f32x4 rs = {0.f, 0.f, 0.f, 0.f};
#pragma unroll
    for (int nt = 0; nt < 8; nt++)
#pragma unroll
      for (int r = 0; r < 4; r++) {
        float pp = __expf(acc[mt][nt][r] - rm[r]);
        acc[mt][nt][r] = pp;
        rs[r] += pp;
      }
#pragma unroll
    for (int off = 1; off < 16; off <<= 1)
#pragma unroll
      for (int r = 0; r < 4; r++) rs[r] += __shfl_xor(rs[r], off, 64);
#pragma unroll
    for (int r = 0; r < 4; r++) invv[mt][r] = 1.f / rs[r];
    // write P bf16 into [t][s]
#pragma unroll
    for (int nt = 0; nt < 8; nt++)
#pragma unroll
      for (int r = 0; r < 4; r++) {
        bf16 pb = __float2bfloat16(acc[mt][nt][r]);
        Ps[tbase + r][nt * 16 + c] = *(ushort*)&pb;
      }
  }

  // O = P V : M=64/wave (4 m-tiles), N=16 (1 n-tile, col e=c), K=128 (4 steps)
  // (each wave reads only the Ps rows it wrote; in-wave DS ordering suffices)
  f32x4 o[4] = {};
#pragma unroll
  for (int ks = 0; ks < 128; ks += 32) {
    bf16x8 bv = *(const bf16x8*)&Vt[c][ks + quad * 8];
#pragma unroll
    for (int mt = 0; mt < 4; mt++) {
      bf16x8 ap = *(const bf16x8*)&Ps[w * 64 + mt * 16 + c][ks + quad * 8];
      o[mt] = __builtin_amdgcn_mfma_f32_16x16x32_bf16(ap, bv, o[mt], 0, 0, 0);
    }
  }

  // epilogue: row t = w*64+mt*16+quad*4+r, col e = c
#pragma unroll
  for (int mt = 0; mt < 4; mt++) {
#pragma unroll
    for (int r = 0; r < 4; r++) {
      int t = w * 64 + mt * 16 + quad * 4 + r;
      float val = o[mt][r] * invv[mt][r];
      ot[((size_t)n * kP + (size_t)t * kB + b) * 128 + hh * 16 + c] = __float2bfloat16(val);
    }
  }
}

// ---------------------------------------------------------------------------
// Fused: a2 = LN(sp+h) + LN(tp+h); writes a2 fp32 + bf16
// ---------------------------------------------------------------------------
__global__ __launch_bounds__(256) void fuse_a2_kernel(
    const float* __restrict__ sp, const float* __restrict__ tp,
    const float* __restrict__ h, const float* __restrict__ g,
    const float* __restrict__ be, float* __restrict__ a2, bf16* __restrict__ a2b)
{
  int row = blockIdx.x;
  const float* s1p = sp + (size_t)row * kND;
  const float* s2p = tp + (size_t)row * kND;
  const float* hp  = h  + (size_t)row * kND;
  float x1[12], x2[12];
  float sum1 = 0.f, sum2 = 0.f;
#pragma unroll
  for (int i = 0; i < 12; i++) {
    int c = threadIdx.x + 256 * i;
    float hv = hp[c];
    x1[i] = s1p[c] + hv; x2[i] = s2p[c] + hv;
    sum1 += x1[i]; sum2 += x2[i];
  }
  __shared__ float red1[4], red2[4];
#pragma unroll
  for (int o = 32; o > 0; o >>= 1) { sum1 += __shfl_down(sum1, o, 64); sum2 += __shfl_down(sum2, o, 64); }
  int wid = threadIdx.x >> 6;
  if ((threadIdx.x & 63) == 0) { red1[wid] = sum1; red2[wid] = sum2; }
  __syncthreads();
  float mean1 = (red1[0] + red1[1] + red1[2] + red1[3]) * (1.f / kND);
  float mean2 = (red2[0] + red2[1] + red2[2] + red2[3]) * (1.f / kND);
  __syncthreads();
  float v1 = 0.f, v2 = 0.f;
#pragma unroll
  for (int i = 0; i < 12; i++) {
    float d1 = x1[i] - mean1, d2 = x2[i] - mean2;
    v1 += d1 * d1; v2 += d2 * d2;
  }
#pragma unroll
  for (int o = 32; o > 0; o >>= 1) { v1 += __shfl_down(v1, o, 64); v2 += __shfl_down(v2, o, 64); }
  if ((threadIdx.x & 63) == 0) { red1[wid] = v1; red2[wid] = v2; }
  __syncthreads();
  float r1 = rsqrtf((red1[0] + red1[1] + red1[2] + red1[3]) * (1.f / kND) + 1e-5f);
  float r2 = rsqrtf((red2[0] + red2[1] + red2[2] + red2[3]) * (1.f / kND) + 1e-5f);
#pragma unroll
  for (int i = 0; i < 12; i++) {
    int c = threadIdx.x + 256 * i;
    float gc = g[c], bc = be[c];
    float o = (x1[i] - mean1) * r1 * gc + bc + (x2[i] - mean2) * r2 * gc + bc;
    a2[(size_t)row * kND + c] = o;
    a2b[(size_t)row * kND + c] = __float2bfloat16(o);
  }
}

// out = LN(a + b); writes fp32 + bf16
__global__ __launch_bounds__(256) void add_ln_dual_kernel(
    const float* __restrict__ a, const float* __restrict__ b,
    const float* __restrict__ g, const float* __restrict__ be,
    float* __restrict__ out, bf16* __restrict__ outb)
{
  int row = blockIdx.x;
  const float* ar = a + (size_t)row * kND;
  const float* br = b + (size_t)row * kND;
  float v[12];
  float s = 0.f;
#pragma unroll
  for (int i = 0; i < 12; i++) {
    int c = threadIdx.x + 256 * i;
    float x = ar[c] + br[c];
    v[i] = x; s += x;
  }
  __shared__ float red[4];
#pragma unroll
  for (int o = 32; o > 0; o >>= 1) s += __shfl_down(s, o, 64);
  int wid = threadIdx.x >> 6;
  if ((threadIdx.x & 63) == 0) red[wid] = s;
  __syncthreads();
  float mean = (red[0] + red[1] + red[2] + red[3]) * (1.f / kND);
  __syncthreads();
  float vs = 0.f;
#pragma unroll
  for (int i = 0; i < 12; i++) { float d = v[i] - mean; vs += d * d; }
#pragma unroll
  for (int o = 32; o > 0; o >>= 1) vs += __shfl_down(vs, o, 64);
  if ((threadIdx.x & 63) == 0) red[wid] = vs;
  __syncthreads();
  float rstd = rsqrtf((red[0] + red[1] + red[2] + red[3]) * (1.f / kND) + 1e-5f);
#pragma unroll
  for (int i = 0; i < 12; i++) {
    int c = threadIdx.x + 256 * i;
    float o = (v[i] - mean) * rstd * g[c] + be[c];
    out[(size_t)row * kND + c] = o;
    outb[(size_t)row * kND + c] = __float2bfloat16(o);
  }
}

// out[b,t,c] = fin[(t*B+b), c] + inputs[b,t,c]
__global__ __launch_bounds__(256) void final_add_kernel(
    const float* __restrict__ fin, const float* __restrict__ inp, float* __restrict__ out)
{
  int i = blockIdx.x * 256 + threadIdx.x;
  int c = i % kNM;
  int rem = i / kNM;
  int t = rem % kT, b = rem / kT;
  out[i] = fin[((size_t)(t * kB + b)) * kNM + c] + inp[i];
}

// ---------------------------------------------------------------------------
extern "C" void kernel_launch(void* const* d_in, const int* in_sizes, int n_in,
                              void* d_out, int out_size, void* d_ws, size_t ws_size,
                              hipStream_t stream)
{
  const float* inputs   = (const float*)d_in[0];
  const float* emb_W    = (const float*)d_in[1];
  const float* emb_b    = (const float*)d_in[2];
  const float* sp_Wq    = (const float*)d_in[3];
  const float* sp_bq    = (const float*)d_in[4];
  const float* sp_Wk    = (const float*)d_in[5];
  const float* sp_bk    = (const float*)d_in[6];
  const float* sp_Wv    = (const float*)d_in[7];
  const float* sp_bv    = (const float*)d_in[8];
  const float* tmp_Win  = (const float*)d_in[9];
  const float* tmp_bin  = (const float*)d_in[10];
  const float* tmp_Wout = (const float*)d_in[11];
  const float* tmp_bout = (const float*)d_in[12];
  const float* ff_W1    = (const float*)d_in[13];
  const float* ff_b1    = (const float*)d_in[14];
  const float* ff_W2    = (const float*)d_in[15];
  const float* ff_b2    = (const float*)d_in[16];
  const float* ln_g     = (const float*)d_in[17];
  const float* ln_b     = (const float*)d_in[18];
  const float* fin_W    = (const float*)d_in[19];
  const float* fin_b    = (const float*)d_in[20];
  float* out = (float*)d_out;

  // ---- workspace layout ----
  char* wp = (char*)d_ws;
  size_t off = 0;
  auto alloc = [&](size_t bytes) { void* p = wp + off; off += (bytes + 255) & ~(size_t)255; return p; };
  bf16* spW   = (bf16*)alloc((size_t)kL * 24 * 768 * 128 * 2);  // fused qkv weights
  bf16* toWb  = (bf16*)alloc((size_t)kL * 24 * 128 * 128 * 2);
  bf16* W1t   = (bf16*)alloc((size_t)kL * kFF * kND * 2);
  bf16* W2t   = (bf16*)alloc((size_t)kL * kND * kFF * 2);
  bf16* finWt = (bf16*)alloc((size_t)kNM * kND * 2);
  float* spbc = (float*)alloc((size_t)kL * 24 * 768 * 4);
  float* hb   = (float*)alloc((size_t)kP * kND * 4);
  bf16*  hbb  = (bf16*) alloc((size_t)kP * kND * 2);
  bf16*  qkvb = (bf16*) alloc((size_t)24 * kP * 768 * 2);   // fused spatial+temporal qkv
  float* sp   = (float*)alloc((size_t)kP * kND * 4);        // also final GEMM out
  float* tp   = (float*)alloc((size_t)kP * kND * 4);        // also FF2 out
  float* a2   = (float*)alloc((size_t)kP * kND * 4);
  bf16*  a2b  = (bf16*) alloc((size_t)kP * kND * 2);
  bf16*  f1b  = (bf16*) alloc((size_t)kP * kFF * 2);
  bf16*  otb  = (bf16*) alloc((size_t)24 * kP * 128 * 2);
  float* finout = sp;

  // ---- weight prep ----
  trans_cvt_kernel<<<dim3(kFF / 64, kND / 64, kL), 256, 0, stream>>>(
      ff_W1, W1t, kND, kFF, (long)kND * kFF, (long)kFF * kND);
  trans_cvt_kernel<<<dim3(kND / 64, kFF / 64, kL), 256, 0, stream>>>(
      ff_W2, W2t, kFF, kND, (long)kFF * kND, (long)kND * kFF);
  trans_cvt_kernel<<<dim3((kNM + 63) / 64, kND / 64, 1), 256, 0, stream>>>(
      fin_W, finWt, kND, kNM, 0L, 0L);
  cvt_kernel<<<(kL * 24 * 128 * 128 + 255) / 256, 256, 0, stream>>>(
      tmp_Wout, toWb, kL * 24 * 128 * 128);
  build_spW_kernel<<<(kL * 24 * 768 * 128) / 256, 256, 0, stream>>>(
      sp_Wq, sp_Wk, sp_Wv, tmp_Win, spW);
  build_spb_kernel<<<(kL * 24 * 768 + 255) / 256, 256, 0, stream>>>(
      sp_bq, sp_bk, sp_bv, tmp_bin, spbc);

  emb_kernel<<<kP, 256, 0, stream>>>(inputs, emb_W, emb_b, hb, hbb);

  for (int l = 0; l < kL; l++) {
    const float* lg = ln_g + (size_t)l * kND;
    const float* lb = ln_b + (size_t)l * kND;

    // fused spatial+temporal qkv: groups n; C = qkvb (n, p, 768) bf16
    mfma_gemm<128, 128, true><<<dim3(6, 8, 24), 256, 0, stream>>>(
        hbb, spW + (size_t)l * 24 * 768 * 128, spbc + (size_t)l * 24 * 768, qkvb,
        kP, 768, 128, /*sAi*/kND, /*sCi*/768,
        /*offAg*/128, /*offBg*/768 * 128, /*offCg*/(long)kP * 768, /*sBg*/768);

    sp_attn_kernel<<<kP, 192, 0, stream>>>(qkvb, sp);
    t_attn_mfma<<<kB * 24 * 8, 128, 0, stream>>>(qkvb, otb);

    // temporal out-proj: A = otb (n,p,128) bf16 -> tp (p, ND) fp32
    mfma_gemm<128, 128, false><<<dim3(1, 8, 24), 256, 0, stream>>>(
        otb, toWb + (size_t)l * 24 * 128 * 128, tmp_bout + (size_t)l * 24 * 128, tp,
        kP, 128, 128, /*sAi*/128, /*sCi*/kND,
        /*offAg*/(long)kP * 128, /*offBg*/128 * 128, /*offCg*/128, /*sBg*/128);

    fuse_a2_kernel<<<kP, 256, 0, stream>>>(sp, tp, hb, lg, lb, a2, a2b);

    // FF1: (P,ND)@(ND,FF) -> f1b bf16. 64-tile => 256 blocks.
    mfma_gemm<64, 64, true><<<dim3(kFF / 64, kP / 64, 1), 256, 0, stream>>>(
        a2b, W1t + (size_t)l * kFF * kND, ff_b1 + (size_t)l * kFF, f1b,
        kP, kFF, kND, kND, kFF, 0, 0, 0, 0);
    // FF2: (P,FF)@(FF,ND) -> tp (reused) fp32. 64x128 tile => 384 blocks.
    mfma_gemm<64, 128, false><<<dim3(kND / 128, kP / 64, 1), 256, 0, stream>>>(
        f1b, W2t + (size_t)l * kND * kFF, ff_b2 + (size_t)l * kND, tp,
        kP, kND, kFF, kFF, kND, 0, 0, 0, 0);

    add_ln_dual_kernel<<<kP, 256, 0, stream>>>(tp, a2, lg, lb, hb, hbb);
  }

  // final projection (ragged N=216) + transpose + residual
  mfma_gemm<64, 64, false><<<dim3((kNM + 63) / 64, kP / 64, 1), 256, 0, stream>>>(
      hbb, finWt, fin_b, finout,
      kP, kNM, kND, kND, kNM, 0, 0, 0, 0);
  final_add_kernel<<<(kB * kT * kNM) / 256, 256, 0, stream>>>(finout, inputs, out);
}

// Round 4
// 903.043 us; speedup vs baseline: 6.1491x; 1.1175x over previous
//
#include <hip/hip_runtime.h>
#include <hip/hip_bf16.h>
#include <math.h>

// Problem constants
constexpr int kB = 8, kT = 128, kN = 24, kD = 128, kM = 9, kH = 8, kL = 4, kFF = 1024;
constexpr int kF = 16;          // D/H
constexpr int kHD = 16;         // D/H
constexpr int kND = kN * kD;    // 3072
constexpr int kNM = kN * kM;    // 216
constexpr int kP = kB * kT;     // 1024 tokens, p = t*B + b

using bf16x8 = __attribute__((ext_vector_type(8))) short;
using f32x4  = __attribute__((ext_vector_type(4))) float;
typedef __hip_bfloat16 bf16;

__device__ __forceinline__ void load_lds16(const void* g, void* l) {
  __builtin_amdgcn_global_load_lds(
      (const __attribute__((address_space(1))) void*)g,
      (__attribute__((address_space(3))) void*)l, 16, 0, 0);
}

// ---------------------------------------------------------------------------
// MFMA bf16 GEMM. A (M x K) bf16, row stride sAi (k contiguous).
// B (Nc x ldB) bf16 pre-transposed (row n = output col n, k contiguous).
// C (M x Nc), row stride sCi, fp32 or bf16. Group/split dim g = blockIdx.z:
//   A += offAg*g ; Bm += offBg*g ; C += offCg*g ; bias += sBg*g.
// Split-K is expressed via g: offAg=offBg=k-chunk, offCg=M*N partial stride.
// 256 threads, 4 waves in 2x2; wave tile (BM/2)x(BN/2).
// ---------------------------------------------------------------------------
template<int BM, int BN, bool OUTBF>
__global__ __launch_bounds__(256) void mfma_gemm(
    const bf16* __restrict__ A, const bf16* __restrict__ Bm,
    const float* __restrict__ bias, void* __restrict__ Cv,
    int M, int Nc, int K, int ldB, int sAi, int sCi,
    long offAg, long offBg, long offCg, int sBg)
{
  constexpr int WM = BM / 2, WN = BN / 2;
  constexpr int MT = WM / 16, NT = WN / 16;
  constexpr int ASLOTS = BM * 4;   // 16-B slots per A k-chunk (BM rows x 64 B)
  constexpr int BSLOTS = BN * 4;
  __shared__ __align__(16) bf16 As[BM * 32];
  __shared__ __align__(16) bf16 Bs[BN * 32];

  int g = blockIdx.z;
  A  += offAg * g;
  Bm += offBg * g;
  long cbase = offCg * (long)g;
  int bOff = sBg * g;

  int m0 = blockIdx.y * BM, n0 = blockIdx.x * BN;
  int tid = threadIdx.x, lane = tid & 63, wave = tid >> 6;
  int wm = wave >> 1, wn = wave & 1;
  int fr = lane & 15, fq = lane >> 4;

  f32x4 acc[MT][NT] = {};

  for (int kk = 0; kk < K; kk += 32) {
#pragma unroll
    for (int s = tid; s < ASLOTS; s += 256) {
      int m = s >> 2, k8 = (s & 3) * 8;
      load_lds16(A + (size_t)(m0 + m) * sAi + (kk + k8), &As[s * 8]);
    }
#pragma unroll
    for (int s = tid; s < BSLOTS; s += 256) {
      int n = s >> 2, k8 = (s & 3) * 8;
      int nr = n0 + n; if (nr > Nc - 1) nr = Nc - 1;   // clamp ragged N
      load_lds16(Bm + (size_t)nr * ldB + (kk + k8), &Bs[s * 8]);
    }
    __syncthreads();
    bf16x8 af[MT], bf[NT];
#pragma unroll
    for (int i = 0; i < MT; i++)
      af[i] = *(const bf16x8*)&As[(wm * WM + i * 16 + fr) * 32 + fq * 8];
#pragma unroll
    for (int j = 0; j < NT; j++)
      bf[j] = *(const bf16x8*)&Bs[(wn * WN + j * 16 + fr) * 32 + fq * 8];
#pragma unroll
    for (int i = 0; i < MT; i++)
#pragma unroll
      for (int j = 0; j < NT; j++)
        acc[i][j] = __builtin_amdgcn_mfma_f32_16x16x32_bf16(af[i], bf[j], acc[i][j], 0, 0, 0);
    __syncthreads();
  }

#pragma unroll
  for (int i = 0; i < MT; i++) {
    int row = m0 + wm * WM + i * 16 + fq * 4;
#pragma unroll
    for (int j = 0; j < NT; j++) {
      int col = n0 + wn * WN + j * 16 + fr;
      if (col < Nc) {
        float bv = bias ? bias[bOff + col] : 0.f;
#pragma unroll
        for (int r = 0; r < 4; r++) {
          long ci = cbase + (size_t)(row + r) * sCi + col;
          float v = acc[i][j][r] + bv;
          if (OUTBF) ((bf16*)Cv)[ci] = __float2bfloat16(v);
          else       ((float*)Cv)[ci] = v;
        }
      }
    }
  }
}

// ---------------------------------------------------------------------------
// Weight prep kernels (run every call; harness re-poisons d_ws each call)
// ---------------------------------------------------------------------------

// fp32 (R x C) -> bf16 (C x R), batched over z
__global__ __launch_bounds__(256) void trans_cvt_kernel(
    const float* __restrict__ in, bf16* __restrict__ out,
    int R, int C, long inStrideZ, long outStrideZ)
{
  __shared__ float t[64][65];
  int c0 = blockIdx.x * 64, r0 = blockIdx.y * 64;
  in  += inStrideZ  * blockIdx.z;
  out += outStrideZ * blockIdx.z;
  int tx = threadIdx.x & 63, ty = threadIdx.x >> 6;
  for (int rr = ty; rr < 64; rr += 4) {
    int r = r0 + rr, c = c0 + tx;
    t[rr][tx] = (r < R && c < C) ? in[(size_t)r * C + c] : 0.f;
  }
  __syncthreads();
  for (int cc = ty; cc < 64; cc += 4) {
    int c = c0 + cc, r = r0 + tx;
    if (c < C && r < R) out[(size_t)c * R + r] = __float2bfloat16(t[tx][cc]);
  }
}

__global__ __launch_bounds__(256) void cvt_kernel(
    const float* __restrict__ in, bf16* __restrict__ out, int n)
{
  int i = blockIdx.x * 256 + threadIdx.x;
  if (i < n) out[i] = __float2bfloat16(in[i]);
}

// Combined qkv weight (spatial + temporal): out[((l*24+n)*768 + r)*128 + d]
// r<128: spatial q (row h*16+f); 128..255: spatial k; 256..383: spatial v;
// 384..767: temporal Win row (r-384)
__global__ __launch_bounds__(256) void build_spW_kernel(
    const float* __restrict__ Wq, const float* __restrict__ Wk,
    const float* __restrict__ Wv, const float* __restrict__ Win,
    bf16* __restrict__ outW)
{
  int i = blockIdx.x * 256 + threadIdx.x;   // total L*24*768*128
  int d = i & 127;
  int rest = i >> 7;
  int r = rest % 768;
  int n = (rest / 768) % 24;
  int l = rest / (768 * 24);
  int hh = (r & 127) >> 4, f = r & 15;
  float v;
  if (r < 128)      v = Wq[((((size_t)l * kH + hh) * kN + n) * kD + d) * kF + f];
  else if (r < 256) v = Wk[(((size_t)l * kH + hh) * kD + d) * kF + f];
  else if (r < 384) v = Wv[(((size_t)l * kH + hh) * kD + d) * kF + f];
  else              v = Win[(((size_t)l * kN + n) * 384 + (r - 384)) * kD + d];
  outW[i] = __float2bfloat16(v);
}

__global__ __launch_bounds__(256) void build_spb_kernel(
    const float* __restrict__ bq, const float* __restrict__ bk,
    const float* __restrict__ bv, const float* __restrict__ bin,
    float* __restrict__ outb)
{
  int i = blockIdx.x * 256 + threadIdx.x;   // total L*24*768
  if (i >= kL * 24 * 768) return;
  int r = i % 768;
  int n = (i / 768) % 24;
  int l = i / (768 * 24);
  int hh = (r & 127) >> 4, f = r & 15;
  float v;
  if (r < 128)      v = bq[(((size_t)l * kH + hh) * kN + n) * kF + f];
  else if (r < 256) v = bk[((size_t)l * kH + hh) * kF + f];
  else if (r < 384) v = bv[((size_t)l * kH + hh) * kF + f];
  else              v = bin[((size_t)l * kN + n) * 384 + (r - 384)];
  outb[i] = v;
}

// ---------------------------------------------------------------------------
// Embedding
// ---------------------------------------------------------------------------
__global__ __launch_bounds__(256) void emb_kernel(
    const float* __restrict__ inp, const float* __restrict__ W,
    const float* __restrict__ bias, float* __restrict__ h, bf16* __restrict__ hbb)
{
  int p = blockIdx.x;
  int t = p / kB, b = p % kB;
  __shared__ float xs[kNM];
  for (int i = threadIdx.x; i < kNM; i += 256)
    xs[i] = inp[((size_t)b * kT + t) * kNM + i];
  __syncthreads();
  const float c1 = -logf(10000.f) / (float)kND;
  for (int c = threadIdx.x; c < kND; c += 256) {
    int n = c / kD, d = c % kD;
    float acc = bias[n * kD + d];
#pragma unroll
    for (int m = 0; m < kM; m++)
      acc += xs[n * kM + m] * W[(n * kM + m) * kD + d];
    float ang = (float)b * expf((float)(c & ~1) * c1);
    acc += (c & 1) ? cosf(ang) : sinf(ang);
    h[(size_t)p * kND + c] = acc;
    hbb[(size_t)p * kND + c] = __float2bfloat16(acc);
  }
}

// ---------------------------------------------------------------------------
// Spatial attention. qkv bf16 (n, p, 768): q at c=h*16+f, k at +128, v at +256
// out sp[p, n*128 + h*16 + f] fp32
// ---------------------------------------------------------------------------
__global__ __launch_bounds__(192) void sp_attn_kernel(
    const bf16* __restrict__ qkv, float* __restrict__ out)
{
  int p = blockIdx.x;
  __shared__ float s[24 * 385];
  for (int i = threadIdx.x; i < 24 * 384; i += 192) {
    int n = i / 384, c = i % 384;
    s[n * 385 + c] = __bfloat162float(qkv[((size_t)n * kP + p) * 768 + c]);
  }
  __syncthreads();
  int hh = threadIdx.x / 24, n = threadIdx.x % 24;
  const float* qr = s + n * 385 + hh * 16;
  float sc[24];
  float mx = -1e30f;
#pragma unroll
  for (int m = 0; m < 24; m++) {
    const float* kr = s + m * 385 + 128 + hh * 16;
    float d = 0.f;
#pragma unroll
    for (int f = 0; f < 16; f++) d += qr[f] * kr[f];
    d *= 0.25f;
    sc[m] = d;
    mx = fmaxf(mx, d);
  }
  float sum = 0.f;
#pragma unroll
  for (int m = 0; m < 24; m++) { float e = __expf(sc[m] - mx); sc[m] = e; sum += e; }
  float inv = 1.f / sum;
  float* orow = out + (size_t)p * kND + n * kD + hh * 16;
#pragma unroll
  for (int f = 0; f < 16; f++) {
    float acc = 0.f;
#pragma unroll
    for (int m = 0; m < 24; m++) acc += sc[m] * s[m * 385 + 256 + hh * 16 + f];
    orow[f] = acc * inv;
  }
}

// ---------------------------------------------------------------------------
// Temporal attention via MFMA. qkv bf16 (n, p, 768): temporal q at 384+h*16+e,
// k at 512+h*16+e, v at 640+h*16+e. One block per (b,n,h), 128 threads (2 waves).
// ---------------------------------------------------------------------------
__global__ __launch_bounds__(128) void t_attn_mfma(
    const bf16* __restrict__ qkv, bf16* __restrict__ ot)
{
  int g = blockIdx.x;
  int hh = g & 7, n = (g >> 3) % 24, b = g / 192;
  __shared__ __align__(16) ushort Qs[128][32];    // 8 KB, cols 16..31 zero
  __shared__ __align__(16) ushort Ks[128][32];    // 8 KB
  __shared__ __align__(16) ushort Vt[16][136];    // V^T [e][s], padded
  __shared__ __align__(16) ushort Ps[128][136];   // P [t][s], padded

  for (int idx = threadIdx.x; idx < 1024; idx += 128) {
    int t = idx >> 3, e2 = (idx & 7) * 2;
    const ushort* src = (const ushort*)qkv +
        ((size_t)n * kP + (size_t)t * kB + b) * 768 + 384 + hh * 16 + e2;
    ushort2 q2 = *(const ushort2*)(src);
    ushort2 k2 = *(const ushort2*)(src + 128);
    ushort2 v2 = *(const ushort2*)(src + 256);
    *(ushort2*)&Qs[t][e2] = q2;
    *(ushort2*)&Ks[t][e2] = k2;
    *(ushort2*)&Qs[t][16 + e2] = make_ushort2(0, 0);
    *(ushort2*)&Ks[t][16 + e2] = make_ushort2(0, 0);
    Vt[e2][t] = v2.x;
    Vt[e2 + 1][t] = v2.y;
  }
  __syncthreads();

  int lane = threadIdx.x & 63, w = threadIdx.x >> 6;
  int c = lane & 15, quad = lane >> 4;

  // S = Q K^T
  bf16x8 aq[4];
#pragma unroll
  for (int mt = 0; mt < 4; mt++)
    aq[mt] = *(const bf16x8*)&Qs[w * 64 + mt * 16 + c][quad * 8];
  f32x4 acc[4][8];
#pragma unroll
  for (int nt = 0; nt < 8; nt++) {
    bf16x8 bk = *(const bf16x8*)&Ks[nt * 16 + c][quad * 8];
#pragma unroll
    for (int mt = 0; mt < 4; mt++) {
      f32x4 z = {0.f, 0.f, 0.f, 0.f};
      acc[mt][nt] = __builtin_amdgcn_mfma_f32_16x16x32_bf16(aq[mt], bk, z, 0, 0, 0);
    }
  }

  // softmax per row; rows t = w*64 + mt*16 + quad*4 + r, cols s = nt*16 + c
  f32x4 invv[4];
#pragma unroll
  for (int mt = 0; mt < 4; mt++) {
    int tbase = w * 64 + mt * 16 + quad * 4;
    f32x4 rm = {-1e30f, -1e30f, -1e30f, -1e30f};
#pragma unroll
    for (int nt = 0; nt < 8; nt++) {
      int s = nt * 16 + c;
#pragma unroll
      for (int r = 0; r < 4; r++) {
        float x = acc[mt][nt][r] * 0.25f + ((s < tbase + r) ? 1.f : 0.f);
        acc[mt][nt][r] = x;
        rm[r] = fmaxf(rm[r], x);
      }
    }
#pragma unroll
    for (int off = 1; off < 16; off <<= 1)
#pragma unroll
      for (int r = 0; r < 4; r++) rm[r] = fmaxf(rm[r], __shfl_xor(rm[r], off, 64));
    f32x4 rs = {0.f, 0.f, 0.f, 0.f};
#pragma unroll
    for (int nt = 0; nt < 8; nt++)
#pragma unroll
      for (int r = 0; r < 4; r++) {
        float pp = __expf(acc[mt][nt][r] - rm[r]);
        acc[mt][nt][r] = pp;
        rs[r] += pp;
      }
#pragma unroll
    for (int off = 1; off < 16; off <<= 1)
#pragma unroll
      for (int r = 0; r < 4; r++) rs[r] += __shfl_xor(rs[r], off, 64);
#pragma unroll
    for (int r = 0; r < 4; r++) invv[mt][r] = 1.f / rs[r];
#pragma unroll
    for (int nt = 0; nt < 8; nt++)
#pragma unroll
      for (int r = 0; r < 4; r++) {
        bf16 pb = __float2bfloat16(acc[mt][nt][r]);
        Ps[tbase + r][nt * 16 + c] = *(ushort*)&pb;
      }
  }

  // O = P V (in-wave Ps reuse only)
  f32x4 o[4] = {};
#pragma unroll
  for (int ks = 0; ks < 128; ks += 32) {
    bf16x8 bv = *(const bf16x8*)&Vt[c][ks + quad * 8];
#pragma unroll
    for (int mt = 0; mt < 4; mt++) {
      bf16x8 ap = *(const bf16x8*)&Ps[w * 64 + mt * 16 + c][ks + quad * 8];
      o[mt] = __builtin_amdgcn_mfma_f32_16x16x32_bf16(ap, bv, o[mt], 0, 0, 0);
    }
  }

#pragma unroll
  for (int mt = 0; mt < 4; mt++) {
#pragma unroll
    for (int r = 0; r < 4; r++) {
      int t = w * 64 + mt * 16 + quad * 4 + r;
      float val = o[mt][r] * invv[mt][r];
      ot[((size_t)n * kP + (size_t)t * kB + b) * 128 + hh * 16 + c] = __float2bfloat16(val);
    }
  }
}

// ---------------------------------------------------------------------------
// Fused: a2 = LN(sp+h) + LN(tp+h); writes a2 fp32 + bf16
// ---------------------------------------------------------------------------
__global__ __launch_bounds__(256) void fuse_a2_kernel(
    const float* __restrict__ sp, const float* __restrict__ tp,
    const float* __restrict__ h, const float* __restrict__ g,
    const float* __restrict__ be, float* __restrict__ a2, bf16* __restrict__ a2b)
{
  int row = blockIdx.x;
  const float* s1p = sp + (size_t)row * kND;
  const float* s2p = tp + (size_t)row * kND;
  const float* hp  = h  + (size_t)row * kND;
  float x1[12], x2[12];
  float sum1 = 0.f, sum2 = 0.f;
#pragma unroll
  for (int i = 0; i < 12; i++) {
    int c = threadIdx.x + 256 * i;
    float hv = hp[c];
    x1[i] = s1p[c] + hv; x2[i] = s2p[c] + hv;
    sum1 += x1[i]; sum2 += x2[i];
  }
  __shared__ float red1[4], red2[4];
#pragma unroll
  for (int o = 32; o > 0; o >>= 1) { sum1 += __shfl_down(sum1, o, 64); sum2 += __shfl_down(sum2, o, 64); }
  int wid = threadIdx.x >> 6;
  if ((threadIdx.x & 63) == 0) { red1[wid] = sum1; red2[wid] = sum2; }
  __syncthreads();
  float mean1 = (red1[0] + red1[1] + red1[2] + red1[3]) * (1.f / kND);
  float mean2 = (red2[0] + red2[1] + red2[2] + red2[3]) * (1.f / kND);
  __syncthreads();
  float v1 = 0.f, v2 = 0.f;
#pragma unroll
  for (int i = 0; i < 12; i++) {
    float d1 = x1[i] - mean1, d2 = x2[i] - mean2;
    v1 += d1 * d1; v2 += d2 * d2;
  }
#pragma unroll
  for (int o = 32; o > 0; o >>= 1) { v1 += __shfl_down(v1, o, 64); v2 += __shfl_down(v2, o, 64); }
  if ((threadIdx.x & 63) == 0) { red1[wid] = v1; red2[wid] = v2; }
  __syncthreads();
  float r1 = rsqrtf((red1[0] + red1[1] + red1[2] + red1[3]) * (1.f / kND) + 1e-5f);
  float r2 = rsqrtf((red2[0] + red2[1] + red2[2] + red2[3]) * (1.f / kND) + 1e-5f);
#pragma unroll
  for (int i = 0; i < 12; i++) {
    int c = threadIdx.x + 256 * i;
    float gc = g[c], bc = be[c];
    float o = (x1[i] - mean1) * r1 * gc + bc + (x2[i] - mean2) * r2 * gc + bc;
    a2[(size_t)row * kND + c] = o;
    a2b[(size_t)row * kND + c] = __float2bfloat16(o);
  }
}

// out = LN(a + b); writes fp32 + bf16
__global__ __launch_bounds__(256) void add_ln_dual_kernel(
    const float* __restrict__ a, const float* __restrict__ b,
    const float* __restrict__ g, const float* __restrict__ be,
    float* __restrict__ out, bf16* __restrict__ outb)
{
  int row = blockIdx.x;
  const float* ar = a + (size_t)row * kND;
  const float* br = b + (size_t)row * kND;
  float v[12];
  float s = 0.f;
#pragma unroll
  for (int i = 0; i < 12; i++) {
    int c = threadIdx.x + 256 * i;
    float x = ar[c] + br[c];
    v[i] = x; s += x;
  }
  __shared__ float red[4];
#pragma unroll
  for (int o = 32; o > 0; o >>= 1) s += __shfl_down(s, o, 64);
  int wid = threadIdx.x >> 6;
  if ((threadIdx.x & 63) == 0) red[wid] = s;
  __syncthreads();
  float mean = (red[0] + red[1] + red[2] + red[3]) * (1.f / kND);
  __syncthreads();
  float vs = 0.f;
#pragma unroll
  for (int i = 0; i < 12; i++) { float d = v[i] - mean; vs += d * d; }
#pragma unroll
  for (int o = 32; o > 0; o >>= 1) vs += __shfl_down(vs, o, 64);
  if ((threadIdx.x & 63) == 0) red[wid] = vs;
  __syncthreads();
  float rstd = rsqrtf((red[0] + red[1] + red[2] + red[3]) * (1.f / kND) + 1e-5f);
#pragma unroll
  for (int i = 0; i < 12; i++) {
    int c = threadIdx.x + 256 * i;
    float o = (v[i] - mean) * rstd * g[c] + be[c];
    out[(size_t)row * kND + c] = o;
    outb[(size_t)row * kND + c] = __float2bfloat16(o);
  }
}

// FF1 split-K reduce: f1b[i] = bf16(p0+p1+p2 + bias[col]) over M*N=1M elems
__global__ __launch_bounds__(256) void ff1_reduce_kernel(
    const float* __restrict__ part, const float* __restrict__ bias,
    bf16* __restrict__ out)
{
  int i4 = (blockIdx.x * 256 + threadIdx.x) * 4;   // grid covers kP*kFF/4
  const size_t S = (size_t)kP * kFF;
  float4 p0 = *(const float4*)(part + i4);
  float4 p1 = *(const float4*)(part + S + i4);
  float4 p2 = *(const float4*)(part + 2 * S + i4);
  int col = i4 & (kFF - 1);
#pragma unroll
  for (int j = 0; j < 4; j++) {
    float v = ((const float*)&p0)[j] + ((const float*)&p1)[j] + ((const float*)&p2)[j]
            + bias[col + j];
    out[i4 + j] = __float2bfloat16(v);
  }
}

// Final: out[b,t,c] = sum_z part[z][(t*B+b)*216+c] + fin_b[c] + inputs[b,t,c]
__global__ __launch_bounds__(256) void final_reduce_add_kernel(
    const float* __restrict__ part, const float* __restrict__ fin_b,
    const float* __restrict__ inp, float* __restrict__ out)
{
  int i = blockIdx.x * 256 + threadIdx.x;
  if (i >= kB * kT * kNM) return;
  int c = i % kNM;
  int rem = i / kNM;
  int t = rem % kT, b = rem / kT;
  size_t pi = (size_t)(t * kB + b) * kNM + c;
  const size_t S = (size_t)kP * kNM;
  float v = fin_b[c] + inp[i];
#pragma unroll
  for (int z = 0; z < 8; z++) v += part[z * S + pi];
  out[i] = v;
}

// ---------------------------------------------------------------------------
extern "C" void kernel_launch(void* const* d_in, const int* in_sizes, int n_in,
                              void* d_out, int out_size, void* d_ws, size_t ws_size,
                              hipStream_t stream)
{
  const float* inputs   = (const float*)d_in[0];
  const float* emb_W    = (const float*)d_in[1];
  const float* emb_b    = (const float*)d_in[2];
  const float* sp_Wq    = (const float*)d_in[3];
  const float* sp_bq    = (const float*)d_in[4];
  const float* sp_Wk    = (const float*)d_in[5];
  const float* sp_bk    = (const float*)d_in[6];
  const float* sp_Wv    = (const float*)d_in[7];
  const float* sp_bv    = (const float*)d_in[8];
  const float* tmp_Win  = (const float*)d_in[9];
  const float* tmp_bin  = (const float*)d_in[10];
  const float* tmp_Wout = (const float*)d_in[11];
  const float* tmp_bout = (const float*)d_in[12];
  const float* ff_W1    = (const float*)d_in[13];
  const float* ff_b1    = (const float*)d_in[14];
  const float* ff_W2    = (const float*)d_in[15];
  const float* ff_b2    = (const float*)d_in[16];
  const float* ln_g     = (const float*)d_in[17];
  const float* ln_b     = (const float*)d_in[18];
  const float* fin_W    = (const float*)d_in[19];
  const float* fin_b    = (const float*)d_in[20];
  float* out = (float*)d_out;

  // ---- workspace layout ----
  char* wp = (char*)d_ws;
  size_t off = 0;
  auto alloc = [&](size_t bytes) { void* p = wp + off; off += (bytes + 255) & ~(size_t)255; return p; };
  bf16* spW   = (bf16*)alloc((size_t)kL * 24 * 768 * 128 * 2);  // fused qkv weights
  bf16* toWb  = (bf16*)alloc((size_t)kL * 24 * 128 * 128 * 2);
  bf16* W1t   = (bf16*)alloc((size_t)kL * kFF * kND * 2);
  bf16* W2t   = (bf16*)alloc((size_t)kL * kND * kFF * 2);
  bf16* finWt = (bf16*)alloc((size_t)kNM * kND * 2);
  float* spbc = (float*)alloc((size_t)kL * 24 * 768 * 4);
  float* hb   = (float*)alloc((size_t)kP * kND * 4);
  bf16*  hbb  = (bf16*) alloc((size_t)kP * kND * 2);
  bf16*  qkvb = (bf16*) alloc((size_t)24 * kP * 768 * 2);   // fused spatial+temporal qkv
  float* sp   = (float*)alloc((size_t)kP * kND * 4);        // spatial out; FF1 partials
  float* tp   = (float*)alloc((size_t)kP * kND * 4);        // temporal out; FF2 out; final partials
  float* a2   = (float*)alloc((size_t)kP * kND * 4);
  bf16*  a2b  = (bf16*) alloc((size_t)kP * kND * 2);
  bf16*  f1b  = (bf16*) alloc((size_t)kP * kFF * 2);
  bf16*  otb  = (bf16*) alloc((size_t)24 * kP * 128 * 2);
  float* ffpart  = sp;   // 3 * kP*kFF fp32 = 12 MB  <= 12.58 MB  (sp dead during FF)
  float* finpart = tp;   // 8 * kP*kNM fp32 = 6.9 MB <= 12.58 MB  (tp dead after loop)

  // ---- weight prep ----
  trans_cvt_kernel<<<dim3(kFF / 64, kND / 64, kL), 256, 0, stream>>>(
      ff_W1, W1t, kND, kFF, (long)kND * kFF, (long)kFF * kND);
  trans_cvt_kernel<<<dim3(kND / 64, kFF / 64, kL), 256, 0, stream>>>(
      ff_W2, W2t, kFF, kND, (long)kFF * kND, (long)kND * kFF);
  trans_cvt_kernel<<<dim3((kNM + 63) / 64, kND / 64, 1), 256, 0, stream>>>(
      fin_W, finWt, kND, kNM, 0L, 0L);
  cvt_kernel<<<(kL * 24 * 128 * 128 + 255) / 256, 256, 0, stream>>>(
      tmp_Wout, toWb, kL * 24 * 128 * 128);
  build_spW_kernel<<<(kL * 24 * 768 * 128) / 256, 256, 0, stream>>>(
      sp_Wq, sp_Wk, sp_Wv, tmp_Win, spW);
  build_spb_kernel<<<(kL * 24 * 768 + 255) / 256, 256, 0, stream>>>(
      sp_bq, sp_bk, sp_bv, tmp_bin, spbc);

  emb_kernel<<<kP, 256, 0, stream>>>(inputs, emb_W, emb_b, hb, hbb);

  for (int l = 0; l < kL; l++) {
    const float* lg = ln_g + (size_t)l * kND;
    const float* lb = ln_b + (size_t)l * kND;

    // fused spatial+temporal qkv: groups n; C = qkvb (n, p, 768) bf16
    mfma_gemm<128, 128, true><<<dim3(6, 8, 24), 256, 0, stream>>>(
        hbb, spW + (size_t)l * 24 * 768 * 128, spbc + (size_t)l * 24 * 768, qkvb,
        kP, 768, 128, /*ldB*/128, /*sAi*/kND, /*sCi*/768,
        /*offAg*/128, /*offBg*/768 * 128, /*offCg*/(long)kP * 768, /*sBg*/768);

    sp_attn_kernel<<<kP, 192, 0, stream>>>(qkvb, sp);
    t_attn_mfma<<<kB * 24 * 8, 128, 0, stream>>>(qkvb, otb);

    // temporal out-proj: 64x64 tiles -> 768 blocks (3 blocks/CU)
    mfma_gemm<64, 64, false><<<dim3(2, 16, 24), 256, 0, stream>>>(
        otb, toWb + (size_t)l * 24 * 128 * 128, tmp_bout + (size_t)l * 24 * 128, tp,
        kP, 128, 128, /*ldB*/128, /*sAi*/128, /*sCi*/kND,
        /*offAg*/(long)kP * 128, /*offBg*/128 * 128, /*offCg*/128, /*sBg*/128);

    fuse_a2_kernel<<<kP, 256, 0, stream>>>(sp, tp, hb, lg, lb, a2, a2b);

    // FF1 split-K=3: grid 768 blocks, K-chunk 1024, partials fp32 -> ffpart
    mfma_gemm<64, 64, false><<<dim3(kFF / 64, kP / 64, 3), 256, 0, stream>>>(
        a2b, W1t + (size_t)l * kFF * kND, nullptr, ffpart,
        kP, kFF, /*K*/kND / 3, /*ldB*/kND, /*sAi*/kND, /*sCi*/kFF,
        /*offAg*/kND / 3, /*offBg*/kND / 3, /*offCg*/(long)kP * kFF, /*sBg*/0);
    ff1_reduce_kernel<<<(kP * kFF / 4) / 256, 256, 0, stream>>>(
        ffpart, ff_b1 + (size_t)l * kFF, f1b);

    // FF2: 64x64 tiles -> 48x16 = 768 blocks
    mfma_gemm<64, 64, false><<<dim3(kND / 64, kP / 64, 1), 256, 0, stream>>>(
        f1b, W2t + (size_t)l * kND * kFF, ff_b2 + (size_t)l * kND, tp,
        kP, kND, kFF, /*ldB*/kFF, /*sAi*/kFF, /*sCi*/kND, 0, 0, 0, 0);

    add_ln_dual_kernel<<<kP, 256, 0, stream>>>(tp, a2, lg, lb, hb, hbb);
  }

  // final projection: split-K=8 (K-chunk 384) -> 512 blocks; fused reduce+residual
  mfma_gemm<64, 64, false><<<dim3((kNM + 63) / 64, kP / 64, 8), 256, 0, stream>>>(
      hbb, finWt, nullptr, finpart,
      kP, kNM, /*K*/kND / 8, /*ldB*/kND, /*sAi*/kND, /*sCi*/kNM,
      /*offAg*/kND / 8, /*offBg*/kND / 8, /*offCg*/(long)kP * kNM, /*sBg*/0);
  final_reduce_add_kernel<<<(kB * kT * kNM + 255) / 256, 256, 0, stream>>>(
      finpart, fin_b, inputs, out);
}

// Round 5
// 897.052 us; speedup vs baseline: 6.1902x; 1.0067x over previous
//
#include <hip/hip_runtime.h>
#include <hip/hip_bf16.h>
#include <math.h>

// Problem constants
constexpr int kB = 8, kT = 128, kN = 24, kD = 128, kM = 9, kH = 8, kL = 4, kFF = 1024;
constexpr int kF = 16;          // D/H
constexpr int kHD = 16;         // D/H
constexpr int kND = kN * kD;    // 3072
constexpr int kNM = kN * kM;    // 216
constexpr int kP = kB * kT;     // 1024 tokens, p = t*B + b

using bf16x8 = __attribute__((ext_vector_type(8))) short;
using f32x4  = __attribute__((ext_vector_type(4))) float;
typedef __hip_bfloat16 bf16;

__device__ __forceinline__ void load_lds16(const void* g, void* l) {
  __builtin_amdgcn_global_load_lds(
      (const __attribute__((address_space(1))) void*)g,
      (__attribute__((address_space(3))) void*)l, 16, 0, 0);
}

// ---------------------------------------------------------------------------
// MFMA bf16 GEMM, BK=64. A (M x K) bf16 row stride sAi (k contiguous).
// B (Nc x ldB) bf16 pre-transposed (row n = output col n, k contiguous).
// C (M x Nc) row stride sCi, fp32 or bf16. blockIdx.z = group/split index g:
//   A += offAg*g ; Bm += offBg*g ; C += offCg*g ; bias += sBg*g.
// 256 threads, 4 waves 2x2; wave tile (BM/2)x(BN/2).
// Epilogue: LDS repack (32 rows x BN fp32) -> vectorized coalesced stores.
// ---------------------------------------------------------------------------
template<int BM, int BN, bool OUTBF>
__global__ __launch_bounds__(256) void mfma_gemm(
    const bf16* __restrict__ A, const bf16* __restrict__ Bm,
    const float* __restrict__ bias, void* __restrict__ Cv,
    int M, int Nc, int K, int ldB, int sAi, int sCi,
    long offAg, long offBg, long offCg, int sBg)
{
  constexpr int WM = BM / 2, WN = BN / 2;
  constexpr int MT = WM / 16, NT = WN / 16;
  constexpr int ASLOTS = BM * 8;   // 16-B slots (BM rows x 128 B per k-chunk)
  constexpr int BSLOTS = BN * 8;
  constexpr int CSTR = BN + 4;     // repack stride (floats), 16-B aligned rows
  __shared__ __align__(16) char smem[(BM + BN) * 64 * 2];
  bf16* As = (bf16*)smem;
  bf16* Bs = (bf16*)(smem + BM * 64 * 2);
  float* Cs = (float*)smem;        // repack area (<= 32*CSTR*4 bytes)

  int g = blockIdx.z;
  A  += offAg * g;
  Bm += offBg * g;
  long cbase = offCg * (long)g;
  int bOff = sBg * g;

  int m0 = blockIdx.y * BM, n0 = blockIdx.x * BN;
  int tid = threadIdx.x, lane = tid & 63, wave = tid >> 6;
  int wm = wave >> 1, wn = wave & 1;
  int fr = lane & 15, fq = lane >> 4;

  f32x4 acc[MT][NT] = {};

  for (int kk = 0; kk < K; kk += 64) {
#pragma unroll
    for (int s = tid; s < ASLOTS; s += 256) {
      int m = s >> 3, k8 = (s & 7) * 8;
      load_lds16(A + (size_t)(m0 + m) * sAi + (kk + k8), &As[s * 8]);
    }
#pragma unroll
    for (int s = tid; s < BSLOTS; s += 256) {
      int n = s >> 3, k8 = (s & 7) * 8;
      int nr = n0 + n; if (nr > Nc - 1) nr = Nc - 1;   // clamp ragged N
      load_lds16(Bm + (size_t)nr * ldB + (kk + k8), &Bs[s * 8]);
    }
    __syncthreads();
#pragma unroll
    for (int ks = 0; ks < 2; ks++) {
      bf16x8 af[MT], bfr[NT];
#pragma unroll
      for (int i = 0; i < MT; i++)
        af[i] = *(const bf16x8*)&As[(wm * WM + i * 16 + fr) * 64 + ks * 32 + fq * 8];
#pragma unroll
      for (int j = 0; j < NT; j++)
        bfr[j] = *(const bf16x8*)&Bs[(wn * WN + j * 16 + fr) * 64 + ks * 32 + fq * 8];
#pragma unroll
      for (int i = 0; i < MT; i++)
#pragma unroll
        for (int j = 0; j < NT; j++)
          acc[i][j] = __builtin_amdgcn_mfma_f32_16x16x32_bf16(af[i], bfr[j], acc[i][j], 0, 0, 0);
    }
    __syncthreads();
  }

  // ---- epilogue: per m-tile round, repack 32 rows x BN through LDS ----
  constexpr int NCHUNK = BN / 16;
  int tcol = tid & (NCHUNK - 1);
  int trow = tid / NCHUNK;          // row within the 32-row round
  int colbase = n0 + tcol * 16;
  float vb[16];
  if (trow < 32) {
#pragma unroll
    for (int jj = 0; jj < 16; jj++)
      vb[jj] = bias ? bias[bOff + colbase + jj] : 0.f;
  }
#pragma unroll
  for (int i = 0; i < MT; i++) {
    __syncthreads();
#pragma unroll
    for (int j = 0; j < NT; j++)
#pragma unroll
      for (int r = 0; r < 4; r++)
        Cs[(wm * 16 + fq * 4 + r) * CSTR + wn * WN + j * 16 + fr] = acc[i][j][r];
    __syncthreads();
    if (trow < 32) {
      int row = m0 + (trow >> 4) * WM + i * 16 + (trow & 15);
      float vals[16];
#pragma unroll
      for (int jj = 0; jj < 4; jj++)
        *(float4*)&vals[jj * 4] = *(const float4*)&Cs[trow * CSTR + tcol * 16 + jj * 4];
#pragma unroll
      for (int jj = 0; jj < 16; jj++) vals[jj] += vb[jj];
      if (OUTBF) {
        bf16* cp = (bf16*)Cv + cbase + (size_t)row * sCi + colbase;
        union { bf16 h[8]; uint4 v; } pk;
#pragma unroll
        for (int half = 0; half < 2; half++) {
          if (colbase + half * 8 + 8 <= Nc) {
#pragma unroll
            for (int jj = 0; jj < 8; jj++) pk.h[jj] = __float2bfloat16(vals[half * 8 + jj]);
            *(uint4*)(cp + half * 8) = pk.v;
          }
        }
      } else {
        float* cp = (float*)Cv + cbase + (size_t)row * sCi + colbase;
#pragma unroll
        for (int jj = 0; jj < 4; jj++)
          if (colbase + jj * 4 + 4 <= Nc) *(float4*)(cp + jj * 4) = *(float4*)&vals[jj * 4];
      }
    }
  }
}

// ---------------------------------------------------------------------------
// Weight prep kernels (run every call; harness re-poisons d_ws each call)
// ---------------------------------------------------------------------------

// fp32 (R x C) -> bf16 (C x R), batched over z
__global__ __launch_bounds__(256) void trans_cvt_kernel(
    const float* __restrict__ in, bf16* __restrict__ out,
    int R, int C, long inStrideZ, long outStrideZ)
{
  __shared__ float t[64][65];
  int c0 = blockIdx.x * 64, r0 = blockIdx.y * 64;
  in  += inStrideZ  * blockIdx.z;
  out += outStrideZ * blockIdx.z;
  int tx = threadIdx.x & 63, ty = threadIdx.x >> 6;
  for (int rr = ty; rr < 64; rr += 4) {
    int r = r0 + rr, c = c0 + tx;
    t[rr][tx] = (r < R && c < C) ? in[(size_t)r * C + c] : 0.f;
  }
  __syncthreads();
  for (int cc = ty; cc < 64; cc += 4) {
    int c = c0 + cc, r = r0 + tx;
    if (c < C && r < R) out[(size_t)c * R + r] = __float2bfloat16(t[tx][cc]);
  }
}

__global__ __launch_bounds__(256) void cvt_kernel(
    const float* __restrict__ in, bf16* __restrict__ out, int n)
{
  int i = blockIdx.x * 256 + threadIdx.x;
  if (i < n) out[i] = __float2bfloat16(in[i]);
}

// Combined qkv weight (spatial + temporal): out[((l*24+n)*768 + r)*128 + d]
__global__ __launch_bounds__(256) void build_spW_kernel(
    const float* __restrict__ Wq, const float* __restrict__ Wk,
    const float* __restrict__ Wv, const float* __restrict__ Win,
    bf16* __restrict__ outW)
{
  int i = blockIdx.x * 256 + threadIdx.x;   // total L*24*768*128
  int d = i & 127;
  int rest = i >> 7;
  int r = rest % 768;
  int n = (rest / 768) % 24;
  int l = rest / (768 * 24);
  int hh = (r & 127) >> 4, f = r & 15;
  float v;
  if (r < 128)      v = Wq[((((size_t)l * kH + hh) * kN + n) * kD + d) * kF + f];
  else if (r < 256) v = Wk[(((size_t)l * kH + hh) * kD + d) * kF + f];
  else if (r < 384) v = Wv[(((size_t)l * kH + hh) * kD + d) * kF + f];
  else              v = Win[(((size_t)l * kN + n) * 384 + (r - 384)) * kD + d];
  outW[i] = __float2bfloat16(v);
}

__global__ __launch_bounds__(256) void build_spb_kernel(
    const float* __restrict__ bq, const float* __restrict__ bk,
    const float* __restrict__ bv, const float* __restrict__ bin,
    float* __restrict__ outb)
{
  int i = blockIdx.x * 256 + threadIdx.x;   // total L*24*768
  if (i >= kL * 24 * 768) return;
  int r = i % 768;
  int n = (i / 768) % 24;
  int l = i / (768 * 24);
  int hh = (r & 127) >> 4, f = r & 15;
  float v;
  if (r < 128)      v = bq[(((size_t)l * kH + hh) * kN + n) * kF + f];
  else if (r < 256) v = bk[((size_t)l * kH + hh) * kF + f];
  else if (r < 384) v = bv[((size_t)l * kH + hh) * kF + f];
  else              v = bin[((size_t)l * kN + n) * 384 + (r - 384)];
  outb[i] = v;
}

// ---------------------------------------------------------------------------
// Embedding
// ---------------------------------------------------------------------------
__global__ __launch_bounds__(256) void emb_kernel(
    const float* __restrict__ inp, const float* __restrict__ W,
    const float* __restrict__ bias, float* __restrict__ h, bf16* __restrict__ hbb)
{
  int p = blockIdx.x;
  int t = p / kB, b = p % kB;
  __shared__ float xs[kNM];
  for (int i = threadIdx.x; i < kNM; i += 256)
    xs[i] = inp[((size_t)b * kT + t) * kNM + i];
  __syncthreads();
  const float c1 = -logf(10000.f) / (float)kND;
  for (int c = threadIdx.x; c < kND; c += 256) {
    int n = c / kD, d = c % kD;
    float acc = bias[n * kD + d];
#pragma unroll
    for (int m = 0; m < kM; m++)
      acc += xs[n * kM + m] * W[(n * kM + m) * kD + d];
    float ang = (float)b * expf((float)(c & ~1) * c1);
    acc += (c & 1) ? cosf(ang) : sinf(ang);
    h[(size_t)p * kND + c] = acc;
    hbb[(size_t)p * kND + c] = __float2bfloat16(acc);
  }
}

// ---------------------------------------------------------------------------
// Spatial attention. qkv bf16 (n, p, 768): q at c=h*16+f, k at +128, v at +256
// out sp[p, n*128 + h*16 + f] fp32
// ---------------------------------------------------------------------------
__global__ __launch_bounds__(192) void sp_attn_kernel(
    const bf16* __restrict__ qkv, float* __restrict__ out)
{
  int p = blockIdx.x;
  __shared__ float s[24 * 388];
  // 24*384 bf16 staged as ushort4 -> float4 (2304 vec4 slots / 192 thr = 12)
  for (int i = threadIdx.x; i < 2304; i += 192) {
    int n = i / 96, c4 = (i % 96) * 4;
    ushort4 u = *(const ushort4*)((const ushort*)qkv + ((size_t)n * kP + p) * 768 + c4);
    float4 f;
    f.x = __bfloat162float(*(const bf16*)&u.x);
    f.y = __bfloat162float(*(const bf16*)&u.y);
    f.z = __bfloat162float(*(const bf16*)&u.z);
    f.w = __bfloat162float(*(const bf16*)&u.w);
    *(float4*)&s[n * 388 + c4] = f;
  }
  __syncthreads();
  int hh = threadIdx.x / 24, n = threadIdx.x % 24;
  const float* qr = s + n * 388 + hh * 16;
  float sc[24];
  float mx = -1e30f;
#pragma unroll
  for (int m = 0; m < 24; m++) {
    const float* kr = s + m * 388 + 128 + hh * 16;
    float d = 0.f;
#pragma unroll
    for (int f = 0; f < 16; f++) d += qr[f] * kr[f];
    d *= 0.25f;
    sc[m] = d;
    mx = fmaxf(mx, d);
  }
  float sum = 0.f;
#pragma unroll
  for (int m = 0; m < 24; m++) { float e = __expf(sc[m] - mx); sc[m] = e; sum += e; }
  float inv = 1.f / sum;
  float* orow = out + (size_t)p * kND + n * kD + hh * 16;
#pragma unroll
  for (int f = 0; f < 16; f++) {
    float acc = 0.f;
#pragma unroll
    for (int m = 0; m < 24; m++) acc += sc[m] * s[m * 388 + 256 + hh * 16 + f];
    orow[f] = acc * inv;
  }
}

// ---------------------------------------------------------------------------
// Temporal attention via MFMA. qkv bf16 (n, p, 768): temporal q at 384+h*16+e,
// k at 512+h*16+e, v at 640+h*16+e. One block per (b,n,h), 128 threads (2 waves).
// ---------------------------------------------------------------------------
__global__ __launch_bounds__(128) void t_attn_mfma(
    const bf16* __restrict__ qkv, bf16* __restrict__ ot)
{
  int g = blockIdx.x;
  int hh = g & 7, n = (g >> 3) % 24, b = g / 192;
  __shared__ __align__(16) ushort Qs[128][32];    // 8 KB, cols 16..31 zero
  __shared__ __align__(16) ushort Ks[128][32];    // 8 KB
  __shared__ __align__(16) ushort Vt[16][136];    // V^T [e][s], padded
  __shared__ __align__(16) ushort Ps[128][136];   // P [t][s], padded

  for (int idx = threadIdx.x; idx < 512; idx += 128) {
    int t = idx >> 2, e4 = (idx & 3) * 4;
    const ushort* src = (const ushort*)qkv +
        ((size_t)n * kP + (size_t)t * kB + b) * 768 + 384 + hh * 16 + e4;
    ushort4 q4 = *(const ushort4*)(src);
    ushort4 k4 = *(const ushort4*)(src + 128);
    ushort4 v4 = *(const ushort4*)(src + 256);
    *(ushort4*)&Qs[t][e4] = q4;
    *(ushort4*)&Ks[t][e4] = k4;
    *(ushort4*)&Qs[t][16 + e4] = make_ushort4(0, 0, 0, 0);
    *(ushort4*)&Ks[t][16 + e4] = make_ushort4(0, 0, 0, 0);
    Vt[e4][t] = v4.x; Vt[e4 + 1][t] = v4.y; Vt[e4 + 2][t] = v4.z; Vt[e4 + 3][t] = v4.w;
  }
  __syncthreads();

  int lane = threadIdx.x & 63, w = threadIdx.x >> 6;
  int c = lane & 15, quad = lane >> 4;

  // S = Q K^T
  bf16x8 aq[4];
#pragma unroll
  for (int mt = 0; mt < 4; mt++)
    aq[mt] = *(const bf16x8*)&Qs[w * 64 + mt * 16 + c][quad * 8];
  f32x4 acc[4][8];
#pragma unroll
  for (int nt = 0; nt < 8; nt++) {
    bf16x8 bk = *(const bf16x8*)&Ks[nt * 16 + c][quad * 8];
#pragma unroll
    for (int mt = 0; mt < 4; mt++) {
      f32x4 z = {0.f, 0.f, 0.f, 0.f};
      acc[mt][nt] = __builtin_amdgcn_mfma_f32_16x16x32_bf16(aq[mt], bk, z, 0, 0, 0);
    }
  }

  // softmax per row; rows t = w*64 + mt*16 + quad*4 + r, cols s = nt*16 + c
  f32x4 invv[4];
#pragma unroll
  for (int mt = 0; mt < 4; mt++) {
    int tbase = w * 64 + mt * 16 + quad * 4;
    f32x4 rm = {-1e30f, -1e30f, -1e30f, -1e30f};
#pragma unroll
    for (int nt = 0; nt < 8; nt++) {
      int s = nt * 16 + c;
#pragma unroll
      for (int r = 0; r < 4; r++) {
        float x = acc[mt][nt][r] * 0.25f + ((s < tbase + r) ? 1.f : 0.f);
        acc[mt][nt][r] = x;
        rm[r] = fmaxf(rm[r], x);
      }
    }
#pragma unroll
    for (int off = 1; off < 16; off <<= 1)
#pragma unroll
      for (int r = 0; r < 4; r++) rm[r] = fmaxf(rm[r], __shfl_xor(rm[r], off, 64));
    f32x4 rs = {0.f, 0.f, 0.f, 0.f};
#pragma unroll
    for (int nt = 0; nt < 8; nt++)
#pragma unroll
      for (int r = 0; r < 4; r++) {
        float pp = __expf(acc[mt][nt][r] - rm[r]);
        acc[mt][nt][r] = pp;
        rs[r] += pp;
      }
#pragma unroll
    for (int off = 1; off < 16; off <<= 1)
#pragma unroll
      for (int r = 0; r < 4; r++) rs[r] += __shfl_xor(rs[r], off, 64);
#pragma unroll
    for (int r = 0; r < 4; r++) invv[mt][r] = 1.f / rs[r];
#pragma unroll
    for (int nt = 0; nt < 8; nt++)
#pragma unroll
      for (int r = 0; r < 4; r++) {
        bf16 pb = __float2bfloat16(acc[mt][nt][r]);
        Ps[tbase + r][nt * 16 + c] = *(ushort*)&pb;
      }
  }

  // O = P V (in-wave Ps reuse only)
  f32x4 o[4] = {};
#pragma unroll
  for (int ks = 0; ks < 128; ks += 32) {
    bf16x8 bv = *(const bf16x8*)&Vt[c][ks + quad * 8];
#pragma unroll
    for (int mt = 0; mt < 4; mt++) {
      bf16x8 ap = *(const bf16x8*)&Ps[w * 64 + mt * 16 + c][ks + quad * 8];
      o[mt] = __builtin_amdgcn_mfma_f32_16x16x32_bf16(ap, bv, o[mt], 0, 0, 0);
    }
  }

#pragma unroll
  for (int mt = 0; mt < 4; mt++) {
#pragma unroll
    for (int r = 0; r < 4; r++) {
      int t = w * 64 + mt * 16 + quad * 4 + r;
      float val = o[mt][r] * invv[mt][r];
      ot[((size_t)n * kP + (size_t)t * kB + b) * 128 + hh * 16 + c] = __float2bfloat16(val);
    }
  }
}

// ---------------------------------------------------------------------------
// Fused: a2 = LN(sp+h) + LN(tp+h); writes a2 fp32 + bf16
// ---------------------------------------------------------------------------
__global__ __launch_bounds__(256) void fuse_a2_kernel(
    const float* __restrict__ sp, const float* __restrict__ tp,
    const float* __restrict__ h, const float* __restrict__ g,
    const float* __restrict__ be, float* __restrict__ a2, bf16* __restrict__ a2b)
{
  int row = blockIdx.x;
  const float* s1p = sp + (size_t)row * kND;
  const float* s2p = tp + (size_t)row * kND;
  const float* hp  = h  + (size_t)row * kND;
  float x1[12], x2[12];
  float sum1 = 0.f, sum2 = 0.f;
#pragma unroll
  for (int i = 0; i < 12; i++) {
    int c = threadIdx.x + 256 * i;
    float hv = hp[c];
    x1[i] = s1p[c] + hv; x2[i] = s2p[c] + hv;
    sum1 += x1[i]; sum2 += x2[i];
  }
  __shared__ float red1[4], red2[4];
#pragma unroll
  for (int o = 32; o > 0; o >>= 1) { sum1 += __shfl_down(sum1, o, 64); sum2 += __shfl_down(sum2, o, 64); }
  int wid = threadIdx.x >> 6;
  if ((threadIdx.x & 63) == 0) { red1[wid] = sum1; red2[wid] = sum2; }
  __syncthreads();
  float mean1 = (red1[0] + red1[1] + red1[2] + red1[3]) * (1.f / kND);
  float mean2 = (red2[0] + red2[1] + red2[2] + red2[3]) * (1.f / kND);
  __syncthreads();
  float v1 = 0.f, v2 = 0.f;
#pragma unroll
  for (int i = 0; i < 12; i++) {
    float d1 = x1[i] - mean1, d2 = x2[i] - mean2;
    v1 += d1 * d1; v2 += d2 * d2;
  }
#pragma unroll
  for (int o = 32; o > 0; o >>= 1) { v1 += __shfl_down(v1, o, 64); v2 += __shfl_down(v2, o, 64); }
  if ((threadIdx.x & 63) == 0) { red1[wid] = v1; red2[wid] = v2; }
  __syncthreads();
  float r1 = rsqrtf((red1[0] + red1[1] + red1[2] + red1[3]) * (1.f / kND) + 1e-5f);
  float r2 = rsqrtf((red2[0] + red2[1] + red2[2] + red2[3]) * (1.f / kND) + 1e-5f);
#pragma unroll
  for (int i = 0; i < 12; i++) {
    int c = threadIdx.x + 256 * i;
    float gc = g[c], bc = be[c];
    float o = (x1[i] - mean1) * r1 * gc + bc + (x2[i] - mean2) * r2 * gc + bc;
    a2[(size_t)row * kND + c] = o;
    a2b[(size_t)row * kND + c] = __float2bfloat16(o);
  }
}

// out = LN(a + b); writes fp32 + bf16
__global__ __launch_bounds__(256) void add_ln_dual_kernel(
    const float* __restrict__ a, const float* __restrict__ b,
    const float* __restrict__ g, const float* __restrict__ be,
    float* __restrict__ out, bf16* __restrict__ outb)
{
  int row = blockIdx.x;
  const float* ar = a + (size_t)row * kND;
  const float* br = b + (size_t)row * kND;
  float v[12];
  float s = 0.f;
#pragma unroll
  for (int i = 0; i < 12; i++) {
    int c = threadIdx.x + 256 * i;
    float x = ar[c] + br[c];
    v[i] = x; s += x;
  }
  __shared__ float red[4];
#pragma unroll
  for (int o = 32; o > 0; o >>= 1) s += __shfl_down(s, o, 64);
  int wid = threadIdx.x >> 6;
  if ((threadIdx.x & 63) == 0) red[wid] = s;
  __syncthreads();
  float mean = (red[0] + red[1] + red[2] + red[3]) * (1.f / kND);
  __syncthreads();
  float vs = 0.f;
#pragma unroll
  for (int i = 0; i < 12; i++) { float d = v[i] - mean; vs += d * d; }
#pragma unroll
  for (int o = 32; o > 0; o >>= 1) vs += __shfl_down(vs, o, 64);
  if ((threadIdx.x & 63) == 0) red[wid] = vs;
  __syncthreads();
  float rstd = rsqrtf((red[0] + red[1] + red[2] + red[3]) * (1.f / kND) + 1e-5f);
#pragma unroll
  for (int i = 0; i < 12; i++) {
    int c = threadIdx.x + 256 * i;
    float o = (v[i] - mean) * rstd * g[c] + be[c];
    out[(size_t)row * kND + c] = o;
    outb[(size_t)row * kND + c] = __float2bfloat16(o);
  }
}

// FF1 split-K reduce: f1b[i] = bf16(p0+p1+p2 + bias[col])
__global__ __launch_bounds__(256) void ff1_reduce_kernel(
    const float* __restrict__ part, const float* __restrict__ bias,
    bf16* __restrict__ out)
{
  int i4 = (blockIdx.x * 256 + threadIdx.x) * 4;   // grid covers kP*kFF/4
  const size_t S = (size_t)kP * kFF;
  float4 p0 = *(const float4*)(part + i4);
  float4 p1 = *(const float4*)(part + S + i4);
  float4 p2 = *(const float4*)(part + 2 * S + i4);
  int col = i4 & (kFF - 1);
#pragma unroll
  for (int j = 0; j < 4; j++) {
    float v = ((const float*)&p0)[j] + ((const float*)&p1)[j] + ((const float*)&p2)[j]
            + bias[col + j];
    out[i4 + j] = __float2bfloat16(v);
  }
}

// Final: out[b,t,c] = sum_z part[z][(t*B+b)*216+c] + fin_b[c] + inputs[b,t,c]
__global__ __launch_bounds__(256) void final_reduce_add_kernel(
    const float* __restrict__ part, const float* __restrict__ fin_b,
    const float* __restrict__ inp, float* __restrict__ out)
{
  int i = blockIdx.x * 256 + threadIdx.x;
  if (i >= kB * kT * kNM) return;
  int c = i % kNM;
  int rem = i / kNM;
  int t = rem % kT, b = rem / kT;
  size_t pi = (size_t)(t * kB + b) * kNM + c;
  const size_t S = (size_t)kP * kNM;
  float v = fin_b[c] + inp[i];
#pragma unroll
  for (int z = 0; z < 8; z++) v += part[z * S + pi];
  out[i] = v;
}

// ---------------------------------------------------------------------------
extern "C" void kernel_launch(void* const* d_in, const int* in_sizes, int n_in,
                              void* d_out, int out_size, void* d_ws, size_t ws_size,
                              hipStream_t stream)
{
  const float* inputs   = (const float*)d_in[0];
  const float* emb_W    = (const float*)d_in[1];
  const float* emb_b    = (const float*)d_in[2];
  const float* sp_Wq    = (const float*)d_in[3];
  const float* sp_bq    = (const float*)d_in[4];
  const float* sp_Wk    = (const float*)d_in[5];
  const float* sp_bk    = (const float*)d_in[6];
  const float* sp_Wv    = (const float*)d_in[7];
  const float* sp_bv    = (const float*)d_in[8];
  const float* tmp_Win  = (const float*)d_in[9];
  const float* tmp_bin  = (const float*)d_in[10];
  const float* tmp_Wout = (const float*)d_in[11];
  const float* tmp_bout = (const float*)d_in[12];
  const float* ff_W1    = (const float*)d_in[13];
  const float* ff_b1    = (const float*)d_in[14];
  const float* ff_W2    = (const float*)d_in[15];
  const float* ff_b2    = (const float*)d_in[16];
  const float* ln_g     = (const float*)d_in[17];
  const float* ln_b     = (const float*)d_in[18];
  const float* fin_W    = (const float*)d_in[19];
  const float* fin_b    = (const float*)d_in[20];
  float* out = (float*)d_out;

  // ---- workspace layout ----
  char* wp = (char*)d_ws;
  size_t off = 0;
  auto alloc = [&](size_t bytes) { void* p = wp + off; off += (bytes + 255) & ~(size_t)255; return p; };
  bf16* spW   = (bf16*)alloc((size_t)kL * 24 * 768 * 128 * 2);  // fused qkv weights
  bf16* toWb  = (bf16*)alloc((size_t)kL * 24 * 128 * 128 * 2);
  bf16* W1t   = (bf16*)alloc((size_t)kL * kFF * kND * 2);
  bf16* W2t   = (bf16*)alloc((size_t)kL * kND * kFF * 2);
  bf16* finWt = (bf16*)alloc((size_t)kNM * kND * 2);
  float* spbc = (float*)alloc((size_t)kL * 24 * 768 * 4);
  float* hb   = (float*)alloc((size_t)kP * kND * 4);
  bf16*  hbb  = (bf16*) alloc((size_t)kP * kND * 2);
  bf16*  qkvb = (bf16*) alloc((size_t)24 * kP * 768 * 2);   // fused spatial+temporal qkv
  float* sp   = (float*)alloc((size_t)kP * kND * 4);        // spatial out; FF1 partials
  float* tp   = (float*)alloc((size_t)kP * kND * 4);        // temporal out; FF2 out; final partials
  float* a2   = (float*)alloc((size_t)kP * kND * 4);
  bf16*  a2b  = (bf16*) alloc((size_t)kP * kND * 2);
  bf16*  f1b  = (bf16*) alloc((size_t)kP * kFF * 2);
  bf16*  otb  = (bf16*) alloc((size_t)24 * kP * 128 * 2);
  float* ffpart  = sp;   // 3 * kP*kFF fp32 = 12 MB (sp dead during FF)
  float* finpart = tp;   // 8 * kP*kNM fp32 = 6.9 MB (tp dead after loop)

  // ---- weight prep ----
  trans_cvt_kernel<<<dim3(kFF / 64, kND / 64, kL), 256, 0, stream>>>(
      ff_W1, W1t, kND, kFF, (long)kND * kFF, (long)kFF * kND);
  trans_cvt_kernel<<<dim3(kND / 64, kFF / 64, kL), 256, 0, stream>>>(
      ff_W2, W2t, kFF, kND, (long)kFF * kND, (long)kND * kFF);
  trans_cvt_kernel<<<dim3((kNM + 63) / 64, kND / 64, 1), 256, 0, stream>>>(
      fin_W, finWt, kND, kNM, 0L, 0L);
  cvt_kernel<<<(kL * 24 * 128 * 128 + 255) / 256, 256, 0, stream>>>(
      tmp_Wout, toWb, kL * 24 * 128 * 128);
  build_spW_kernel<<<(kL * 24 * 768 * 128) / 256, 256, 0, stream>>>(
      sp_Wq, sp_Wk, sp_Wv, tmp_Win, spW);
  build_spb_kernel<<<(kL * 24 * 768 + 255) / 256, 256, 0, stream>>>(
      sp_bq, sp_bk, sp_bv, tmp_bin, spbc);

  emb_kernel<<<kP, 256, 0, stream>>>(inputs, emb_W, emb_b, hb, hbb);

  for (int l = 0; l < kL; l++) {
    const float* lg = ln_g + (size_t)l * kND;
    const float* lb = ln_b + (size_t)l * kND;

    // fused spatial+temporal qkv: groups n; C = qkvb (n, p, 768) bf16
    mfma_gemm<128, 128, true><<<dim3(6, 8, 24), 256, 0, stream>>>(
        hbb, spW + (size_t)l * 24 * 768 * 128, spbc + (size_t)l * 24 * 768, qkvb,
        kP, 768, 128, /*ldB*/128, /*sAi*/kND, /*sCi*/768,
        /*offAg*/128, /*offBg*/768 * 128, /*offCg*/(long)kP * 768, /*sBg*/768);

    sp_attn_kernel<<<kP, 192, 0, stream>>>(qkvb, sp);
    t_attn_mfma<<<kB * 24 * 8, 128, 0, stream>>>(qkvb, otb);

    // temporal out-proj: 64x64 tiles -> 768 blocks (3 blocks/CU)
    mfma_gemm<64, 64, false><<<dim3(2, 16, 24), 256, 0, stream>>>(
        otb, toWb + (size_t)l * 24 * 128 * 128, tmp_bout + (size_t)l * 24 * 128, tp,
        kP, 128, 128, /*ldB*/128, /*sAi*/128, /*sCi*/kND,
        /*offAg*/(long)kP * 128, /*offBg*/128 * 128, /*offCg*/128, /*sBg*/128);

    fuse_a2_kernel<<<kP, 256, 0, stream>>>(sp, tp, hb, lg, lb, a2, a2b);

    // FF1 split-K=3: 768 blocks, K-chunk 1024, fp32 partials -> ffpart
    mfma_gemm<64, 64, false><<<dim3(kFF / 64, kP / 64, 3), 256, 0, stream>>>(
        a2b, W1t + (size_t)l * kFF * kND, nullptr, ffpart,
        kP, kFF, /*K*/kND / 3, /*ldB*/kND, /*sAi*/kND, /*sCi*/kFF,
        /*offAg*/kND / 3, /*offBg*/kND / 3, /*offCg*/(long)kP * kFF, /*sBg*/0);
    ff1_reduce_kernel<<<(kP * kFF / 4) / 256, 256, 0, stream>>>(
        ffpart, ff_b1 + (size_t)l * kFF, f1b);

    // FF2: 64x64 tiles -> 768 blocks
    mfma_gemm<64, 64, false><<<dim3(kND / 64, kP / 64, 1), 256, 0, stream>>>(
        f1b, W2t + (size_t)l * kND * kFF, ff_b2 + (size_t)l * kND, tp,
        kP, kND, kFF, /*ldB*/kFF, /*sAi*/kFF, /*sCi*/kND, 0, 0, 0, 0);

    add_ln_dual_kernel<<<kP, 256, 0, stream>>>(tp, a2, lg, lb, hb, hbb);
  }

  // final projection: split-K=8 (K-chunk 384) -> 512 blocks; fused reduce+residual
  mfma_gemm<64, 64, false><<<dim3((kNM + 63) / 64, kP / 64, 8), 256, 0, stream>>>(
      hbb, finWt, nullptr, finpart,
      kP, kNM, /*K*/kND / 8, /*ldB*/kND, /*sAi*/kND, /*sCi*/kNM,
      /*offAg*/kND / 8, /*offBg*/kND / 8, /*offCg*/(long)kP * kNM, /*sBg*/0);
  final_reduce_add_kernel<<<(kB * kT * kNM + 255) / 256, 256, 0, stream>>>(
      finpart, fin_b, inputs, out);
}

// Round 6
// 862.497 us; speedup vs baseline: 6.4382x; 1.0401x over previous
//
#include <hip/hip_runtime.h>
#include <hip/hip_bf16.h>
#include <math.h>

// Problem constants
constexpr int kB = 8, kT = 128, kN = 24, kD = 128, kM = 9, kH = 8, kL = 4, kFF = 1024;
constexpr int kF = 16;          // D/H
constexpr int kHD = 16;         // D/H
constexpr int kND = kN * kD;    // 3072
constexpr int kNM = kN * kM;    // 216
constexpr int kP = kB * kT;     // 1024 tokens, p = t*B + b

using bf16x8 = __attribute__((ext_vector_type(8))) short;
using f32x4  = __attribute__((ext_vector_type(4))) float;
typedef __hip_bfloat16 bf16;

__device__ __forceinline__ void load_lds16(const void* g, void* l) {
  __builtin_amdgcn_global_load_lds(
      (const __attribute__((address_space(1))) void*)g,
      (__attribute__((address_space(3))) void*)l, 16, 0, 0);
}

// ---------------------------------------------------------------------------
// MFMA bf16 GEMM, BK=64, XOR-swizzled LDS layout (bank-conflict-free b128
// fragment reads at the 8-cycle floor; staging stays wave-contiguous for
// global_load_lds). A (M x K) bf16 row stride sAi. B (Nc x ldB) bf16
// pre-transposed. C (M x Nc) stride sCi, fp32 or bf16. blockIdx.z = g:
//   A += offAg*g ; Bm += offBg*g ; C += offCg*g ; bias += sBg*g.
// 256 threads, 4 waves 2x2; wave tile (BM/2)x(BN/2).
// LDS slot s (16 B) of row m holds global k-chunk (s&7)^(m&7).
// ---------------------------------------------------------------------------
template<int BM, int BN, bool OUTBF>
__global__ __launch_bounds__(256) void mfma_gemm(
    const bf16* __restrict__ A, const bf16* __restrict__ Bm,
    const float* __restrict__ bias, void* __restrict__ Cv,
    int M, int Nc, int K, int ldB, int sAi, int sCi,
    long offAg, long offBg, long offCg, int sBg)
{
  constexpr int WM = BM / 2, WN = BN / 2;
  constexpr int MT = WM / 16, NT = WN / 16;
  constexpr int ASLOTS = BM * 8;   // 16-B slots (BM rows x 128 B per k-chunk)
  constexpr int BSLOTS = BN * 8;
  constexpr int CSTR = BN + 4;     // repack stride (floats)
  __shared__ __align__(16) char smem[(BM + BN) * 64 * 2];
  bf16* As = (bf16*)smem;
  bf16* Bs = (bf16*)(smem + BM * 64 * 2);
  float* Cs = (float*)smem;        // epilogue repack area

  int g = blockIdx.z;
  A  += offAg * g;
  Bm += offBg * g;
  long cbase = offCg * (long)g;
  int bOff = sBg * g;

  int m0 = blockIdx.y * BM, n0 = blockIdx.x * BN;
  int tid = threadIdx.x, lane = tid & 63, wave = tid >> 6;
  int wm = wave >> 1, wn = wave & 1;
  int fr = lane & 15, fq = lane >> 4;

  f32x4 acc[MT][NT] = {};

  for (int kk = 0; kk < K; kk += 64) {
#pragma unroll
    for (int s = tid; s < ASLOTS; s += 256) {
      int m = s >> 3, kq = (s & 7) ^ (m & 7);     // XOR swizzle
      load_lds16(A + (size_t)(m0 + m) * sAi + (kk + kq * 8), &As[s * 8]);
    }
#pragma unroll
    for (int s = tid; s < BSLOTS; s += 256) {
      int n = s >> 3, kq = (s & 7) ^ (n & 7);
      int nr = n0 + n; if (nr > Nc - 1) nr = Nc - 1;   // clamp ragged N
      load_lds16(Bm + (size_t)nr * ldB + (kk + kq * 8), &Bs[s * 8]);
    }
    __syncthreads();
#pragma unroll
    for (int ks = 0; ks < 2; ks++) {
      bf16x8 af[MT], bfr[NT];
#pragma unroll
      for (int i = 0; i < MT; i++) {
        int row = wm * WM + i * 16 + fr;
        af[i] = *(const bf16x8*)&As[row * 64 + (((ks * 4 + fq) ^ (row & 7)) * 8)];
      }
#pragma unroll
      for (int j = 0; j < NT; j++) {
        int row = wn * WN + j * 16 + fr;
        bfr[j] = *(const bf16x8*)&Bs[row * 64 + (((ks * 4 + fq) ^ (row & 7)) * 8)];
      }
#pragma unroll
      for (int i = 0; i < MT; i++)
#pragma unroll
        for (int j = 0; j < NT; j++)
          acc[i][j] = __builtin_amdgcn_mfma_f32_16x16x32_bf16(af[i], bfr[j], acc[i][j], 0, 0, 0);
    }
    __syncthreads();
  }

  // ---- epilogue: per m-tile round, repack 32 rows x BN through LDS ----
  constexpr int NCHUNK = BN / 16;
  int tcol = tid & (NCHUNK - 1);
  int trow = tid / NCHUNK;          // row within the 32-row round
  int colbase = n0 + tcol * 16;
  float vb[16];
  if (trow < 32) {
#pragma unroll
    for (int jj = 0; jj < 16; jj++)
      vb[jj] = bias ? bias[bOff + colbase + jj] : 0.f;
  }
#pragma unroll
  for (int i = 0; i < MT; i++) {
    __syncthreads();
#pragma unroll
    for (int j = 0; j < NT; j++)
#pragma unroll
      for (int r = 0; r < 4; r++)
        Cs[(wm * 16 + fq * 4 + r) * CSTR + wn * WN + j * 16 + fr] = acc[i][j][r];
    __syncthreads();
    if (trow < 32) {
      int row = m0 + (trow >> 4) * WM + i * 16 + (trow & 15);
      float vals[16];
#pragma unroll
      for (int jj = 0; jj < 4; jj++)
        *(float4*)&vals[jj * 4] = *(const float4*)&Cs[trow * CSTR + tcol * 16 + jj * 4];
#pragma unroll
      for (int jj = 0; jj < 16; jj++) vals[jj] += vb[jj];
      if (OUTBF) {
        bf16* cp = (bf16*)Cv + cbase + (size_t)row * sCi + colbase;
        union { bf16 h[8]; uint4 v; } pk;
#pragma unroll
        for (int half = 0; half < 2; half++) {
          if (colbase + half * 8 + 8 <= Nc) {
#pragma unroll
            for (int jj = 0; jj < 8; jj++) pk.h[jj] = __float2bfloat16(vals[half * 8 + jj]);
            *(uint4*)(cp + half * 8) = pk.v;
          }
        }
      } else {
        float* cp = (float*)Cv + cbase + (size_t)row * sCi + colbase;
#pragma unroll
        for (int jj = 0; jj < 4; jj++)
          if (colbase + jj * 4 + 4 <= Nc) *(float4*)(cp + jj * 4) = *(float4*)&vals[jj * 4];
      }
    }
  }
}

// ---------------------------------------------------------------------------
// Weight prep kernels (run every call; harness re-poisons d_ws each call)
// ---------------------------------------------------------------------------

// fp32 (R x C) -> bf16 (C x R), batched over z
__global__ __launch_bounds__(256) void trans_cvt_kernel(
    const float* __restrict__ in, bf16* __restrict__ out,
    int R, int C, long inStrideZ, long outStrideZ)
{
  __shared__ float t[64][65];
  int c0 = blockIdx.x * 64, r0 = blockIdx.y * 64;
  in  += inStrideZ  * blockIdx.z;
  out += outStrideZ * blockIdx.z;
  int tx = threadIdx.x & 63, ty = threadIdx.x >> 6;
  for (int rr = ty; rr < 64; rr += 4) {
    int r = r0 + rr, c = c0 + tx;
    t[rr][tx] = (r < R && c < C) ? in[(size_t)r * C + c] : 0.f;
  }
  __syncthreads();
  for (int cc = ty; cc < 64; cc += 4) {
    int c = c0 + cc, r = r0 + tx;
    if (c < C && r < R) out[(size_t)c * R + r] = __float2bfloat16(t[tx][cc]);
  }
}

__global__ __launch_bounds__(256) void cvt_kernel(
    const float* __restrict__ in, bf16* __restrict__ out, int n)
{
  int i = blockIdx.x * 256 + threadIdx.x;
  if (i < n) out[i] = __float2bfloat16(in[i]);
}

// Combined qkv weight (spatial + temporal): out[((l*24+n)*768 + r)*128 + d]
__global__ __launch_bounds__(256) void build_spW_kernel(
    const float* __restrict__ Wq, const float* __restrict__ Wk,
    const float* __restrict__ Wv, const float* __restrict__ Win,
    bf16* __restrict__ outW)
{
  int i = blockIdx.x * 256 + threadIdx.x;   // total L*24*768*128
  int d = i & 127;
  int rest = i >> 7;
  int r = rest % 768;
  int n = (rest / 768) % 24;
  int l = rest / (768 * 24);
  int hh = (r & 127) >> 4, f = r & 15;
  float v;
  if (r < 128)      v = Wq[((((size_t)l * kH + hh) * kN + n) * kD + d) * kF + f];
  else if (r < 256) v = Wk[(((size_t)l * kH + hh) * kD + d) * kF + f];
  else if (r < 384) v = Wv[(((size_t)l * kH + hh) * kD + d) * kF + f];
  else              v = Win[(((size_t)l * kN + n) * 384 + (r - 384)) * kD + d];
  outW[i] = __float2bfloat16(v);
}

__global__ __launch_bounds__(256) void build_spb_kernel(
    const float* __restrict__ bq, const float* __restrict__ bk,
    const float* __restrict__ bv, const float* __restrict__ bin,
    float* __restrict__ outb)
{
  int i = blockIdx.x * 256 + threadIdx.x;   // total L*24*768
  if (i >= kL * 24 * 768) return;
  int r = i % 768;
  int n = (i / 768) % 24;
  int l = i / (768 * 24);
  int hh = (r & 127) >> 4, f = r & 15;
  float v;
  if (r < 128)      v = bq[(((size_t)l * kH + hh) * kN + n) * kF + f];
  else if (r < 256) v = bk[((size_t)l * kH + hh) * kF + f];
  else if (r < 384) v = bv[((size_t)l * kH + hh) * kF + f];
  else              v = bin[((size_t)l * kN + n) * 384 + (r - 384)];
  outb[i] = v;
}

// ---------------------------------------------------------------------------
// Embedding
// ---------------------------------------------------------------------------
__global__ __launch_bounds__(256) void emb_kernel(
    const float* __restrict__ inp, const float* __restrict__ W,
    const float* __restrict__ bias, float* __restrict__ h, bf16* __restrict__ hbb)
{
  int p = blockIdx.x;
  int t = p / kB, b = p % kB;
  __shared__ float xs[kNM];
  for (int i = threadIdx.x; i < kNM; i += 256)
    xs[i] = inp[((size_t)b * kT + t) * kNM + i];
  __syncthreads();
  const float c1 = -logf(10000.f) / (float)kND;
  for (int c = threadIdx.x; c < kND; c += 256) {
    int n = c / kD, d = c % kD;
    float acc = bias[n * kD + d];
#pragma unroll
    for (int m = 0; m < kM; m++)
      acc += xs[n * kM + m] * W[(n * kM + m) * kD + d];
    float ang = (float)b * expf((float)(c & ~1) * c1);
    acc += (c & 1) ? cosf(ang) : sinf(ang);
    h[(size_t)p * kND + c] = acc;
    hbb[(size_t)p * kND + c] = __float2bfloat16(acc);
  }
}

// ---------------------------------------------------------------------------
// Spatial attention. qkv bf16 (n, p, 768): q at c=h*16+f, k at +128, v at +256
// out sp[p, n*128 + h*16 + f] fp32
// ---------------------------------------------------------------------------
__global__ __launch_bounds__(192) void sp_attn_kernel(
    const bf16* __restrict__ qkv, float* __restrict__ out)
{
  int p = blockIdx.x;
  __shared__ float s[24 * 388];
  for (int i = threadIdx.x; i < 2304; i += 192) {
    int n = i / 96, c4 = (i % 96) * 4;
    ushort4 u = *(const ushort4*)((const ushort*)qkv + ((size_t)n * kP + p) * 768 + c4);
    float4 f;
    f.x = __bfloat162float(*(const bf16*)&u.x);
    f.y = __bfloat162float(*(const bf16*)&u.y);
    f.z = __bfloat162float(*(const bf16*)&u.z);
    f.w = __bfloat162float(*(const bf16*)&u.w);
    *(float4*)&s[n * 388 + c4] = f;
  }
  __syncthreads();
  int hh = threadIdx.x / 24, n = threadIdx.x % 24;
  const float* qr = s + n * 388 + hh * 16;
  float sc[24];
  float mx = -1e30f;
#pragma unroll
  for (int m = 0; m < 24; m++) {
    const float* kr = s + m * 388 + 128 + hh * 16;
    float d = 0.f;
#pragma unroll
    for (int f = 0; f < 16; f++) d += qr[f] * kr[f];
    d *= 0.25f;
    sc[m] = d;
    mx = fmaxf(mx, d);
  }
  float sum = 0.f;
#pragma unroll
  for (int m = 0; m < 24; m++) { float e = __expf(sc[m] - mx); sc[m] = e; sum += e; }
  float inv = 1.f / sum;
  float* orow = out + (size_t)p * kND + n * kD + hh * 16;
#pragma unroll
  for (int f = 0; f < 16; f++) {
    float acc = 0.f;
#pragma unroll
    for (int m = 0; m < 24; m++) acc += sc[m] * s[m * 388 + 256 + hh * 16 + f];
    orow[f] = acc * inv;
  }
}

// ---------------------------------------------------------------------------
// Temporal attention via MFMA. qkv bf16 (n, p, 768): temporal q at 384+h*16+e,
// k at 512+h*16+e, v at 640+h*16+e. One block per (b,n,h), 128 threads (2 waves).
// Qs/Ks rows padded to 40 ushorts (80 B) -> b128 fragment reads at bank floor.
// ---------------------------------------------------------------------------
__global__ __launch_bounds__(128) void t_attn_mfma(
    const bf16* __restrict__ qkv, bf16* __restrict__ ot)
{
  int g = blockIdx.x;
  int hh = g & 7, n = (g >> 3) % 24, b = g / 192;
  __shared__ __align__(16) ushort Qs[128][40];    // 10 KB, cols 16..31 zero
  __shared__ __align__(16) ushort Ks[128][40];    // 10 KB
  __shared__ __align__(16) ushort Vt[16][136];    // V^T [e][s], padded
  __shared__ __align__(16) ushort Ps[128][136];   // P [t][s], padded

  for (int idx = threadIdx.x; idx < 512; idx += 128) {
    int t = idx >> 2, e4 = (idx & 3) * 4;
    const ushort* src = (const ushort*)qkv +
        ((size_t)n * kP + (size_t)t * kB + b) * 768 + 384 + hh * 16 + e4;
    ushort4 q4 = *(const ushort4*)(src);
    ushort4 k4 = *(const ushort4*)(src + 128);
    ushort4 v4 = *(const ushort4*)(src + 256);
    *(ushort4*)&Qs[t][e4] = q4;
    *(ushort4*)&Ks[t][e4] = k4;
    *(ushort4*)&Qs[t][16 + e4] = make_ushort4(0, 0, 0, 0);
    *(ushort4*)&Ks[t][16 + e4] = make_ushort4(0, 0, 0, 0);
    Vt[e4][t] = v4.x; Vt[e4 + 1][t] = v4.y; Vt[e4 + 2][t] = v4.z; Vt[e4 + 3][t] = v4.w;
  }
  __syncthreads();

  int lane = threadIdx.x & 63, w = threadIdx.x >> 6;
  int c = lane & 15, quad = lane >> 4;

  // S = Q K^T
  bf16x8 aq[4];
#pragma unroll
  for (int mt = 0; mt < 4; mt++)
    aq[mt] = *(const bf16x8*)&Qs[w * 64 + mt * 16 + c][quad * 8];
  f32x4 acc[4][8];
#pragma unroll
  for (int nt = 0; nt < 8; nt++) {
    bf16x8 bk = *(const bf16x8*)&Ks[nt * 16 + c][quad * 8];
#pragma unroll
    for (int mt = 0; mt < 4; mt++) {
      f32x4 z = {0.f, 0.f, 0.f, 0.f};
      acc[mt][nt] = __builtin_amdgcn_mfma_f32_16x16x32_bf16(aq[mt], bk, z, 0, 0, 0);
    }
  }

  // softmax per row; rows t = w*64 + mt*16 + quad*4 + r, cols s = nt*16 + c
  f32x4 invv[4];
#pragma unroll
  for (int mt = 0; mt < 4; mt++) {
    int tbase = w * 64 + mt * 16 + quad * 4;
    f32x4 rm = {-1e30f, -1e30f, -1e30f, -1e30f};
#pragma unroll
    for (int nt = 0; nt < 8; nt++) {
      int s = nt * 16 + c;
#pragma unroll
      for (int r = 0; r < 4; r++) {
        float x = acc[mt][nt][r] * 0.25f + ((s < tbase + r) ? 1.f : 0.f);
        acc[mt][nt][r] = x;
        rm[r] = fmaxf(rm[r], x);
      }
    }
#pragma unroll
    for (int off = 1; off < 16; off <<= 1)
#pragma unroll
      for (int r = 0; r < 4; r++) rm[r] = fmaxf(rm[r], __shfl_xor(rm[r], off, 64));
    f32x4 rs = {0.f, 0.f, 0.f, 0.f};
#pragma unroll
    for (int nt = 0; nt < 8; nt++)
#pragma unroll
      for (int r = 0; r < 4; r++) {
        float pp = __expf(acc[mt][nt][r] - rm[r]);
        acc[mt][nt][r] = pp;
        rs[r] += pp;
      }
#pragma unroll
    for (int off = 1; off < 16; off <<= 1)
#pragma unroll
      for (int r = 0; r < 4; r++) rs[r] += __shfl_xor(rs[r], off, 64);
#pragma unroll
    for (int r = 0; r < 4; r++) invv[mt][r] = 1.f / rs[r];
#pragma unroll
    for (int nt = 0; nt < 8; nt++)
#pragma unroll
      for (int r = 0; r < 4; r++) {
        bf16 pb = __float2bfloat16(acc[mt][nt][r]);
        Ps[tbase + r][nt * 16 + c] = *(ushort*)&pb;
      }
  }

  // O = P V (in-wave Ps reuse only)
  f32x4 o[4] = {};
#pragma unroll
  for (int ks = 0; ks < 128; ks += 32) {
    bf16x8 bv = *(const bf16x8*)&Vt[c][ks + quad * 8];
#pragma unroll
    for (int mt = 0; mt < 4; mt++) {
      bf16x8 ap = *(const bf16x8*)&Ps[w * 64 + mt * 16 + c][ks + quad * 8];
      o[mt] = __builtin_amdgcn_mfma_f32_16x16x32_bf16(ap, bv, o[mt], 0, 0, 0);
    }
  }

#pragma unroll
  for (int mt = 0; mt < 4; mt++) {
#pragma unroll
    for (int r = 0; r < 4; r++) {
      int t = w * 64 + mt * 16 + quad * 4 + r;
      float val = o[mt][r] * invv[mt][r];
      ot[((size_t)n * kP + (size_t)t * kB + b) * 128 + hh * 16 + c] = __float2bfloat16(val);
    }
  }
}

// ---------------------------------------------------------------------------
// Fused: a2 = LN(sp+h) + LN(tp+h); writes a2 fp32 + bf16
// ---------------------------------------------------------------------------
__global__ __launch_bounds__(256) void fuse_a2_kernel(
    const float* __restrict__ sp, const float* __restrict__ tp,
    const float* __restrict__ h, const float* __restrict__ g,
    const float* __restrict__ be, float* __restrict__ a2, bf16* __restrict__ a2b)
{
  int row = blockIdx.x;
  const float* s1p = sp + (size_t)row * kND;
  const float* s2p = tp + (size_t)row * kND;
  const float* hp  = h  + (size_t)row * kND;
  float x1[12], x2[12];
  float sum1 = 0.f, sum2 = 0.f;
#pragma unroll
  for (int i = 0; i < 12; i++) {
    int c = threadIdx.x + 256 * i;
    float hv = hp[c];
    x1[i] = s1p[c] + hv; x2[i] = s2p[c] + hv;
    sum1 += x1[i]; sum2 += x2[i];
  }
  __shared__ float red1[4], red2[4];
#pragma unroll
  for (int o = 32; o > 0; o >>= 1) { sum1 += __shfl_down(sum1, o, 64); sum2 += __shfl_down(sum2, o, 64); }
  int wid = threadIdx.x >> 6;
  if ((threadIdx.x & 63) == 0) { red1[wid] = sum1; red2[wid] = sum2; }
  __syncthreads();
  float mean1 = (red1[0] + red1[1] + red1[2] + red1[3]) * (1.f / kND);
  float mean2 = (red2[0] + red2[1] + red2[2] + red2[3]) * (1.f / kND);
  __syncthreads();
  float v1 = 0.f, v2 = 0.f;
#pragma unroll
  for (int i = 0; i < 12; i++) {
    float d1 = x1[i] - mean1, d2 = x2[i] - mean2;
    v1 += d1 * d1; v2 += d2 * d2;
  }
#pragma unroll
  for (int o = 32; o > 0; o >>= 1) { v1 += __shfl_down(v1, o, 64); v2 += __shfl_down(v2, o, 64); }
  if ((threadIdx.x & 63) == 0) { red1[wid] = v1; red2[wid] = v2; }
  __syncthreads();
  float r1 = rsqrtf((red1[0] + red1[1] + red1[2] + red1[3]) * (1.f / kND) + 1e-5f);
  float r2 = rsqrtf((red2[0] + red2[1] + red2[2] + red2[3]) * (1.f / kND) + 1e-5f);
#pragma unroll
  for (int i = 0; i < 12; i++) {
    int c = threadIdx.x + 256 * i;
    float gc = g[c], bc = be[c];
    float o = (x1[i] - mean1) * r1 * gc + bc + (x2[i] - mean2) * r2 * gc + bc;
    a2[(size_t)row * kND + c] = o;
    a2b[(size_t)row * kND + c] = __float2bfloat16(o);
  }
}

// out = LN(a + b); writes fp32 + bf16
__global__ __launch_bounds__(256) void add_ln_dual_kernel(
    const float* __restrict__ a, const float* __restrict__ b,
    const float* __restrict__ g, const float* __restrict__ be,
    float* __restrict__ out, bf16* __restrict__ outb)
{
  int row = blockIdx.x;
  const float* ar = a + (size_t)row * kND;
  const float* br = b + (size_t)row * kND;
  float v[12];
  float s = 0.f;
#pragma unroll
  for (int i = 0; i < 12; i++) {
    int c = threadIdx.x + 256 * i;
    float x = ar[c] + br[c];
    v[i] = x; s += x;
  }
  __shared__ float red[4];
#pragma unroll
  for (int o = 32; o > 0; o >>= 1) s += __shfl_down(s, o, 64);
  int wid = threadIdx.x >> 6;
  if ((threadIdx.x & 63) == 0) red[wid] = s;
  __syncthreads();
  float mean = (red[0] + red[1] + red[2] + red[3]) * (1.f / kND);
  __syncthreads();
  float vs = 0.f;
#pragma unroll
  for (int i = 0; i < 12; i++) { float d = v[i] - mean; vs += d * d; }
#pragma unroll
  for (int o = 32; o > 0; o >>= 1) vs += __shfl_down(vs, o, 64);
  if ((threadIdx.x & 63) == 0) red[wid] = vs;
  __syncthreads();
  float rstd = rsqrtf((red[0] + red[1] + red[2] + red[3]) * (1.f / kND) + 1e-5f);
#pragma unroll
  for (int i = 0; i < 12; i++) {
    int c = threadIdx.x + 256 * i;
    float o = (v[i] - mean) * rstd * g[c] + be[c];
    out[(size_t)row * kND + c] = o;
    outb[(size_t)row * kND + c] = __float2bfloat16(o);
  }
}

// FF1 split-K reduce: f1b[i] = bf16(p0+p1+p2 + bias[col])
__global__ __launch_bounds__(256) void ff1_reduce_kernel(
    const float* __restrict__ part, const float* __restrict__ bias,
    bf16* __restrict__ out)
{
  int i4 = (blockIdx.x * 256 + threadIdx.x) * 4;   // grid covers kP*kFF/4
  const size_t S = (size_t)kP * kFF;
  float4 p0 = *(const float4*)(part + i4);
  float4 p1 = *(const float4*)(part + S + i4);
  float4 p2 = *(const float4*)(part + 2 * S + i4);
  int col = i4 & (kFF - 1);
#pragma unroll
  for (int j = 0; j < 4; j++) {
    float v = ((const float*)&p0)[j] + ((const float*)&p1)[j] + ((const float*)&p2)[j]
            + bias[col + j];
    out[i4 + j] = __float2bfloat16(v);
  }
}

// Final: out[b,t,c] = sum_z part[z][(t*B+b)*216+c] + fin_b[c] + inputs[b,t,c]
__global__ __launch_bounds__(256) void final_reduce_add_kernel(
    const float* __restrict__ part, const float* __restrict__ fin_b,
    const float* __restrict__ inp, float* __restrict__ out)
{
  int i = blockIdx.x * 256 + threadIdx.x;
  if (i >= kB * kT * kNM) return;
  int c = i % kNM;
  int rem = i / kNM;
  int t = rem % kT, b = rem / kT;
  size_t pi = (size_t)(t * kB + b) * kNM + c;
  const size_t S = (size_t)kP * kNM;
  float v = fin_b[c] + inp[i];
#pragma unroll
  for (int z = 0; z < 8; z++) v += part[z * S + pi];
  out[i] = v;
}

// ---------------------------------------------------------------------------
extern "C" void kernel_launch(void* const* d_in, const int* in_sizes, int n_in,
                              void* d_out, int out_size, void* d_ws, size_t ws_size,
                              hipStream_t stream)
{
  const float* inputs   = (const float*)d_in[0];
  const float* emb_W    = (const float*)d_in[1];
  const float* emb_b    = (const float*)d_in[2];
  const float* sp_Wq    = (const float*)d_in[3];
  const float* sp_bq    = (const float*)d_in[4];
  const float* sp_Wk    = (const float*)d_in[5];
  const float* sp_bk    = (const float*)d_in[6];
  const float* sp_Wv    = (const float*)d_in[7];
  const float* sp_bv    = (const float*)d_in[8];
  const float* tmp_Win  = (const float*)d_in[9];
  const float* tmp_bin  = (const float*)d_in[10];
  const float* tmp_Wout = (const float*)d_in[11];
  const float* tmp_bout = (const float*)d_in[12];
  const float* ff_W1    = (const float*)d_in[13];
  const float* ff_b1    = (const float*)d_in[14];
  const float* ff_W2    = (const float*)d_in[15];
  const float* ff_b2    = (const float*)d_in[16];
  const float* ln_g     = (const float*)d_in[17];
  const float* ln_b     = (const float*)d_in[18];
  const float* fin_W    = (const float*)d_in[19];
  const float* fin_b    = (const float*)d_in[20];
  float* out = (float*)d_out;

  // ---- workspace layout ----
  char* wp = (char*)d_ws;
  size_t off = 0;
  auto alloc = [&](size_t bytes) { void* p = wp + off; off += (bytes + 255) & ~(size_t)255; return p; };
  bf16* spW   = (bf16*)alloc((size_t)kL * 24 * 768 * 128 * 2);  // fused qkv weights
  bf16* toWb  = (bf16*)alloc((size_t)kL * 24 * 128 * 128 * 2);
  bf16* W1t   = (bf16*)alloc((size_t)kL * kFF * kND * 2);
  bf16* W2t   = (bf16*)alloc((size_t)kL * kND * kFF * 2);
  bf16* finWt = (bf16*)alloc((size_t)kNM * kND * 2);
  float* spbc = (float*)alloc((size_t)kL * 24 * 768 * 4);
  float* hb   = (float*)alloc((size_t)kP * kND * 4);
  bf16*  hbb  = (bf16*) alloc((size_t)kP * kND * 2);
  bf16*  qkvb = (bf16*) alloc((size_t)24 * kP * 768 * 2);   // fused spatial+temporal qkv
  float* sp   = (float*)alloc((size_t)kP * kND * 4);        // spatial out; FF1 partials
  float* tp   = (float*)alloc((size_t)kP * kND * 4);        // temporal out; FF2 out; final partials
  float* a2   = (float*)alloc((size_t)kP * kND * 4);
  bf16*  a2b  = (bf16*) alloc((size_t)kP * kND * 2);
  bf16*  f1b  = (bf16*) alloc((size_t)kP * kFF * 2);
  bf16*  otb  = (bf16*) alloc((size_t)24 * kP * 128 * 2);
  float* ffpart  = sp;   // 3 * kP*kFF fp32 = 12 MB (sp dead during FF)
  float* finpart = tp;   // 8 * kP*kNM fp32 = 6.9 MB (tp dead after loop)

  // ---- weight prep ----
  trans_cvt_kernel<<<dim3(kFF / 64, kND / 64, kL), 256, 0, stream>>>(
      ff_W1, W1t, kND, kFF, (long)kND * kFF, (long)kFF * kND);
  trans_cvt_kernel<<<dim3(kND / 64, kFF / 64, kL), 256, 0, stream>>>(
      ff_W2, W2t, kFF, kND, (long)kFF * kND, (long)kND * kFF);
  trans_cvt_kernel<<<dim3((kNM + 63) / 64, kND / 64, 1), 256, 0, stream>>>(
      fin_W, finWt, kND, kNM, 0L, 0L);
  cvt_kernel<<<(kL * 24 * 128 * 128 + 255) / 256, 256, 0, stream>>>(
      tmp_Wout, toWb, kL * 24 * 128 * 128);
  build_spW_kernel<<<(kL * 24 * 768 * 128) / 256, 256, 0, stream>>>(
      sp_Wq, sp_Wk, sp_Wv, tmp_Win, spW);
  build_spb_kernel<<<(kL * 24 * 768 + 255) / 256, 256, 0, stream>>>(
      sp_bq, sp_bk, sp_bv, tmp_bin, spbc);

  emb_kernel<<<kP, 256, 0, stream>>>(inputs, emb_W, emb_b, hb, hbb);

  for (int l = 0; l < kL; l++) {
    const float* lg = ln_g + (size_t)l * kND;
    const float* lb = ln_b + (size_t)l * kND;

    // fused spatial+temporal qkv: groups n; C = qkvb (n, p, 768) bf16
    mfma_gemm<128, 128, true><<<dim3(6, 8, 24), 256, 0, stream>>>(
        hbb, spW + (size_t)l * 24 * 768 * 128, spbc + (size_t)l * 24 * 768, qkvb,
        kP, 768, 128, /*ldB*/128, /*sAi*/kND, /*sCi*/768,
        /*offAg*/128, /*offBg*/768 * 128, /*offCg*/(long)kP * 768, /*sBg*/768);

    sp_attn_kernel<<<kP, 192, 0, stream>>>(qkvb, sp);
    t_attn_mfma<<<kB * 24 * 8, 128, 0, stream>>>(qkvb, otb);

    // temporal out-proj: 64x64 tiles -> 768 blocks (3 blocks/CU)
    mfma_gemm<64, 64, false><<<dim3(2, 16, 24), 256, 0, stream>>>(
        otb, toWb + (size_t)l * 24 * 128 * 128, tmp_bout + (size_t)l * 24 * 128, tp,
        kP, 128, 128, /*ldB*/128, /*sAi*/128, /*sCi*/kND,
        /*offAg*/(long)kP * 128, /*offBg*/128 * 128, /*offCg*/128, /*sBg*/128);

    fuse_a2_kernel<<<kP, 256, 0, stream>>>(sp, tp, hb, lg, lb, a2, a2b);

    // FF1 split-K=3: 768 blocks, K-chunk 1024, fp32 partials -> ffpart
    mfma_gemm<64, 64, false><<<dim3(kFF / 64, kP / 64, 3), 256, 0, stream>>>(
        a2b, W1t + (size_t)l * kFF * kND, nullptr, ffpart,
        kP, kFF, /*K*/kND / 3, /*ldB*/kND, /*sAi*/kND, /*sCi*/kFF,
        /*offAg*/kND / 3, /*offBg*/kND / 3, /*offCg*/(long)kP * kFF, /*sBg*/0);
    ff1_reduce_kernel<<<(kP * kFF / 4) / 256, 256, 0, stream>>>(
        ffpart, ff_b1 + (size_t)l * kFF, f1b);

    // FF2: 64x64 tiles -> 768 blocks
    mfma_gemm<64, 64, false><<<dim3(kND / 64, kP / 64, 1), 256, 0, stream>>>(
        f1b, W2t + (size_t)l * kND * kFF, ff_b2 + (size_t)l * kND, tp,
        kP, kND, kFF, /*ldB*/kFF, /*sAi*/kFF, /*sCi*/kND, 0, 0, 0, 0);

    add_ln_dual_kernel<<<kP, 256, 0, stream>>>(tp, a2, lg, lb, hb, hbb);
  }

  // final projection: split-K=8 (K-chunk 384) -> 512 blocks; fused reduce+residual
  mfma_gemm<64, 64, false><<<dim3((kNM + 63) / 64, kP / 64, 8), 256, 0, stream>>>(
      hbb, finWt, nullptr, finpart,
      kP, kNM, /*K*/kND / 8, /*ldB*/kND, /*sAi*/kND, /*sCi*/kNM,
      /*offAg*/kND / 8, /*offBg*/kND / 8, /*offCg*/(long)kP * kNM, /*sBg*/0);
  final_reduce_add_kernel<<<(kB * kT * kNM + 255) / 256, 256, 0, stream>>>(
      finpart, fin_b, inputs, out);
}

// Round 7
// 799.358 us; speedup vs baseline: 6.9467x; 1.0790x over previous
//
#include <hip/hip_runtime.h>
#include <hip/hip_bf16.h>
#include <math.h>

// Problem constants
constexpr int kB = 8, kT = 128, kN = 24, kD = 128, kM = 9, kH = 8, kL = 4, kFF = 1024;
constexpr int kF = 16;          // D/H
constexpr int kHD = 16;         // D/H
constexpr int kND = kN * kD;    // 3072
constexpr int kNM = kN * kM;    // 216
constexpr int kP = kB * kT;     // 1024 tokens, p = t*B + b

using bf16x8 = __attribute__((ext_vector_type(8))) short;
using f32x4  = __attribute__((ext_vector_type(4))) float;
typedef __hip_bfloat16 bf16;

__device__ __forceinline__ void load_lds16(const void* g, void* l) {
  __builtin_amdgcn_global_load_lds(
      (const __attribute__((address_space(1))) void*)g,
      (__attribute__((address_space(3))) void*)l, 16, 0, 0);
}

// ---------------------------------------------------------------------------
// MFMA bf16 GEMM, BK=64, XOR-swizzled LDS (conflict-free b128 fragment reads,
// wave-contiguous global_load_lds staging). See r5/r6 notes.
// ---------------------------------------------------------------------------
template<int BM, int BN, bool OUTBF>
__global__ __launch_bounds__(256) void mfma_gemm(
    const bf16* __restrict__ A, const bf16* __restrict__ Bm,
    const float* __restrict__ bias, void* __restrict__ Cv,
    int M, int Nc, int K, int ldB, int sAi, int sCi,
    long offAg, long offBg, long offCg, int sBg)
{
  constexpr int WM = BM / 2, WN = BN / 2;
  constexpr int MT = WM / 16, NT = WN / 16;
  constexpr int ASLOTS = BM * 8;   // 16-B slots (BM rows x 128 B per k-chunk)
  constexpr int BSLOTS = BN * 8;
  constexpr int CSTR = BN + 4;     // repack stride (floats)
  __shared__ __align__(16) char smem[(BM + BN) * 64 * 2];
  bf16* As = (bf16*)smem;
  bf16* Bs = (bf16*)(smem + BM * 64 * 2);
  float* Cs = (float*)smem;        // epilogue repack area

  int g = blockIdx.z;
  A  += offAg * g;
  Bm += offBg * g;
  long cbase = offCg * (long)g;
  int bOff = sBg * g;

  int m0 = blockIdx.y * BM, n0 = blockIdx.x * BN;
  int tid = threadIdx.x, lane = tid & 63, wave = tid >> 6;
  int wm = wave >> 1, wn = wave & 1;
  int fr = lane & 15, fq = lane >> 4;

  f32x4 acc[MT][NT] = {};

  for (int kk = 0; kk < K; kk += 64) {
#pragma unroll
    for (int s = tid; s < ASLOTS; s += 256) {
      int m = s >> 3, kq = (s & 7) ^ (m & 7);     // XOR swizzle
      load_lds16(A + (size_t)(m0 + m) * sAi + (kk + kq * 8), &As[s * 8]);
    }
#pragma unroll
    for (int s = tid; s < BSLOTS; s += 256) {
      int n = s >> 3, kq = (s & 7) ^ (n & 7);
      int nr = n0 + n; if (nr > Nc - 1) nr = Nc - 1;   // clamp ragged N
      load_lds16(Bm + (size_t)nr * ldB + (kk + kq * 8), &Bs[s * 8]);
    }
    __syncthreads();
#pragma unroll
    for (int ks = 0; ks < 2; ks++) {
      bf16x8 af[MT], bfr[NT];
#pragma unroll
      for (int i = 0; i < MT; i++) {
        int row = wm * WM + i * 16 + fr;
        af[i] = *(const bf16x8*)&As[row * 64 + (((ks * 4 + fq) ^ (row & 7)) * 8)];
      }
#pragma unroll
      for (int j = 0; j < NT; j++) {
        int row = wn * WN + j * 16 + fr;
        bfr[j] = *(const bf16x8*)&Bs[row * 64 + (((ks * 4 + fq) ^ (row & 7)) * 8)];
      }
#pragma unroll
      for (int i = 0; i < MT; i++)
#pragma unroll
        for (int j = 0; j < NT; j++)
          acc[i][j] = __builtin_amdgcn_mfma_f32_16x16x32_bf16(af[i], bfr[j], acc[i][j], 0, 0, 0);
    }
    __syncthreads();
  }

  // ---- epilogue: per m-tile round, repack 32 rows x BN through LDS ----
  constexpr int NCHUNK = BN / 16;
  int tcol = tid & (NCHUNK - 1);
  int trow = tid / NCHUNK;          // row within the 32-row round
  int colbase = n0 + tcol * 16;
  float vb[16];
  if (trow < 32) {
#pragma unroll
    for (int jj = 0; jj < 16; jj++)
      vb[jj] = bias ? bias[bOff + colbase + jj] : 0.f;
  }
#pragma unroll
  for (int i = 0; i < MT; i++) {
    __syncthreads();
#pragma unroll
    for (int j = 0; j < NT; j++)
#pragma unroll
      for (int r = 0; r < 4; r++)
        Cs[(wm * 16 + fq * 4 + r) * CSTR + wn * WN + j * 16 + fr] = acc[i][j][r];
    __syncthreads();
    if (trow < 32) {
      int row = m0 + (trow >> 4) * WM + i * 16 + (trow & 15);
      float vals[16];
#pragma unroll
      for (int jj = 0; jj < 4; jj++)
        *(float4*)&vals[jj * 4] = *(const float4*)&Cs[trow * CSTR + tcol * 16 + jj * 4];
#pragma unroll
      for (int jj = 0; jj < 16; jj++) vals[jj] += vb[jj];
      if (OUTBF) {
        bf16* cp = (bf16*)Cv + cbase + (size_t)row * sCi + colbase;
        union { bf16 h[8]; uint4 v; } pk;
#pragma unroll
        for (int half = 0; half < 2; half++) {
          if (colbase + half * 8 + 8 <= Nc) {
#pragma unroll
            for (int jj = 0; jj < 8; jj++) pk.h[jj] = __float2bfloat16(vals[half * 8 + jj]);
            *(uint4*)(cp + half * 8) = pk.v;
          }
        }
      } else {
        float* cp = (float*)Cv + cbase + (size_t)row * sCi + colbase;
#pragma unroll
        for (int jj = 0; jj < 4; jj++)
          if (colbase + jj * 4 + 4 <= Nc) *(float4*)(cp + jj * 4) = *(float4*)&vals[jj * 4];
      }
    }
  }
}

// ---------------------------------------------------------------------------
// Weight prep kernels (run every call; harness re-poisons d_ws each call)
// ---------------------------------------------------------------------------

// fp32 (R x C) -> bf16 (C x R), batched over z. R must be multiple of 64.
// Vectorized: float4 loads, uint4 (8x bf16) stores.
__global__ __launch_bounds__(256) void trans_cvt_kernel(
    const float* __restrict__ in, bf16* __restrict__ out,
    int R, int C, long inStrideZ, long outStrideZ)
{
  __shared__ float t[64][65];
  int c0 = blockIdx.x * 64, r0 = blockIdx.y * 64;
  in  += inStrideZ  * blockIdx.z;
  out += outStrideZ * blockIdx.z;
  int tid = threadIdx.x;
  for (int s = tid; s < 1024; s += 256) {
    int rr = s >> 4, c4 = (s & 15) * 4;
    int r = r0 + rr, c = c0 + c4;
    float4 v;
    if (c + 4 <= C) v = *(const float4*)&in[(size_t)r * C + c];
    else {
      float tmp[4];
#pragma unroll
      for (int j = 0; j < 4; j++) tmp[j] = (c + j < C) ? in[(size_t)r * C + c + j] : 0.f;
      v = *(float4*)tmp;
    }
    *(float4*)&t[rr][c4] = v;
  }
  __syncthreads();
  for (int s = tid; s < 512; s += 256) {
    int cc = s >> 3, r8 = (s & 7) * 8;
    int c = c0 + cc;
    if (c < C) {
      union { bf16 h[8]; uint4 v; } pk;
#pragma unroll
      for (int j = 0; j < 8; j++) pk.h[j] = __float2bfloat16(t[r8 + j][cc]);
      *(uint4*)&out[(size_t)c * R + r0 + r8] = pk.v;
    }
  }
}

__global__ __launch_bounds__(256) void cvt_kernel(
    const float* __restrict__ in, bf16* __restrict__ out, int n)
{
  int i8 = (blockIdx.x * 256 + threadIdx.x) * 8;
  if (i8 + 8 > n) return;
  float4 v0 = *(const float4*)(in + i8);
  float4 v1 = *(const float4*)(in + i8 + 4);
  union { bf16 h[8]; uint4 v; } pk;
  pk.h[0] = __float2bfloat16(v0.x); pk.h[1] = __float2bfloat16(v0.y);
  pk.h[2] = __float2bfloat16(v0.z); pk.h[3] = __float2bfloat16(v0.w);
  pk.h[4] = __float2bfloat16(v1.x); pk.h[5] = __float2bfloat16(v1.y);
  pk.h[6] = __float2bfloat16(v1.z); pk.h[7] = __float2bfloat16(v1.w);
  *(uint4*)(out + i8) = pk.v;
}

// Combined qkv weight (spatial + temporal): out[((l*24+n)*768 + r)*128 + d]
// 8 consecutive d per thread, packed uint4 store.
__global__ __launch_bounds__(256) void build_spW_kernel(
    const float* __restrict__ Wq, const float* __restrict__ Wk,
    const float* __restrict__ Wv, const float* __restrict__ Win,
    bf16* __restrict__ outW)
{
  int i8 = (blockIdx.x * 256 + threadIdx.x) * 8;   // total L*24*768*128
  int d = i8 & 127;
  int rest = i8 >> 7;
  int r = rest % 768;
  int n = (rest / 768) % 24;
  int l = rest / (768 * 24);
  int hh = (r & 127) >> 4, f = r & 15;
  union { bf16 h[8]; uint4 v; } pk;
  if (r >= 384) {
    const float* src = &Win[((((size_t)l * kN + n) * 384) + (r - 384)) * kD + d];
    float4 v0 = *(const float4*)src, v1 = *(const float4*)(src + 4);
    pk.h[0] = __float2bfloat16(v0.x); pk.h[1] = __float2bfloat16(v0.y);
    pk.h[2] = __float2bfloat16(v0.z); pk.h[3] = __float2bfloat16(v0.w);
    pk.h[4] = __float2bfloat16(v1.x); pk.h[5] = __float2bfloat16(v1.y);
    pk.h[6] = __float2bfloat16(v1.z); pk.h[7] = __float2bfloat16(v1.w);
  } else {
    const float* base;
    if (r < 128)      base = &Wq[((((size_t)l * kH + hh) * kN + n) * kD + d) * kF + f];
    else if (r < 256) base = &Wk[(((size_t)l * kH + hh) * kD + d) * kF + f];
    else              base = &Wv[(((size_t)l * kH + hh) * kD + d) * kF + f];
#pragma unroll
    for (int j = 0; j < 8; j++) pk.h[j] = __float2bfloat16(base[(size_t)j * kF]);
  }
  *(uint4*)&outW[i8] = pk.v;
}

__global__ __launch_bounds__(256) void build_spb_kernel(
    const float* __restrict__ bq, const float* __restrict__ bk,
    const float* __restrict__ bv, const float* __restrict__ bin,
    float* __restrict__ outb)
{
  int i = blockIdx.x * 256 + threadIdx.x;   // total L*24*768
  if (i >= kL * 24 * 768) return;
  int r = i % 768;
  int n = (i / 768) % 24;
  int l = i / (768 * 24);
  int hh = (r & 127) >> 4, f = r & 15;
  float v;
  if (r < 128)      v = bq[(((size_t)l * kH + hh) * kN + n) * kF + f];
  else if (r < 256) v = bk[((size_t)l * kH + hh) * kF + f];
  else if (r < 384) v = bv[((size_t)l * kH + hh) * kF + f];
  else              v = bin[((size_t)l * kN + n) * 384 + (r - 384)];
  outb[i] = v;
}

// ---------------------------------------------------------------------------
// Embedding — float4 W loads (coalesced across threads), packed bf16 stores.
// ---------------------------------------------------------------------------
__global__ __launch_bounds__(256) void emb_kernel(
    const float* __restrict__ inp, const float* __restrict__ W,
    const float* __restrict__ bias, float* __restrict__ h, bf16* __restrict__ hbb)
{
  int p = blockIdx.x;
  int t = p / kB, b = p % kB;
  __shared__ float xs[kNM];
  if (threadIdx.x < kNM)
    xs[threadIdx.x] = inp[((size_t)b * kT + t) * kNM + threadIdx.x];
  __syncthreads();
  const float c1 = -logf(10000.f) / (float)kND;
  for (int c4 = threadIdx.x; c4 < kND / 4; c4 += 256) {
    int c = c4 * 4;
    int n = c >> 7, d = c & 127;
    float4 acc = *(const float4*)&bias[n * kD + d];
#pragma unroll
    for (int m = 0; m < kM; m++) {
      float xv = xs[n * kM + m];
      float4 w = *(const float4*)&W[((size_t)(n * kM + m)) * kD + d];
      acc.x += xv * w.x; acc.y += xv * w.y; acc.z += xv * w.z; acc.w += xv * w.w;
    }
    float ang0 = (float)b * expf((float)c * c1);
    float ang1 = (float)b * expf((float)(c + 2) * c1);
    acc.x += sinf(ang0); acc.y += cosf(ang0);
    acc.z += sinf(ang1); acc.w += cosf(ang1);
    *(float4*)&h[(size_t)p * kND + c] = acc;
    union { bf16 h4[4]; uint2 v; } pk;
    pk.h4[0] = __float2bfloat16(acc.x); pk.h4[1] = __float2bfloat16(acc.y);
    pk.h4[2] = __float2bfloat16(acc.z); pk.h4[3] = __float2bfloat16(acc.w);
    *(uint2*)&hbb[(size_t)p * kND + c] = pk.v;
  }
}

// ---------------------------------------------------------------------------
// Spatial attention — float4 LDS traffic throughout.
// qkv bf16 (n, p, 768): q at c=h*16+f, k at +128, v at +256
// out sp[p, n*128 + h*16 + f] fp32
// ---------------------------------------------------------------------------
__global__ __launch_bounds__(192) void sp_attn_kernel(
    const bf16* __restrict__ qkv, float* __restrict__ out)
{
  int p = blockIdx.x;
  __shared__ float s[24 * 388];
  for (int i = threadIdx.x; i < 2304; i += 192) {
    int n = i / 96, c4 = (i % 96) * 4;
    ushort4 u = *(const ushort4*)((const ushort*)qkv + ((size_t)n * kP + p) * 768 + c4);
    float4 f;
    f.x = __bfloat162float(*(const bf16*)&u.x);
    f.y = __bfloat162float(*(const bf16*)&u.y);
    f.z = __bfloat162float(*(const bf16*)&u.z);
    f.w = __bfloat162float(*(const bf16*)&u.w);
    *(float4*)&s[n * 388 + c4] = f;
  }
  __syncthreads();
  int hh = threadIdx.x / 24, n = threadIdx.x % 24;
  const float4* qr = (const float4*)(s + n * 388 + hh * 16);
  float4 q0 = qr[0], q1 = qr[1], q2 = qr[2], q3 = qr[3];
  float sc[24];
  float mx = -1e30f;
#pragma unroll
  for (int m = 0; m < 24; m++) {
    const float4* kr = (const float4*)(s + m * 388 + 128 + hh * 16);
    float4 k0 = kr[0], k1 = kr[1], k2 = kr[2], k3 = kr[3];
    float d = q0.x * k0.x + q0.y * k0.y + q0.z * k0.z + q0.w * k0.w
            + q1.x * k1.x + q1.y * k1.y + q1.z * k1.z + q1.w * k1.w
            + q2.x * k2.x + q2.y * k2.y + q2.z * k2.z + q2.w * k2.w
            + q3.x * k3.x + q3.y * k3.y + q3.z * k3.z + q3.w * k3.w;
    d *= 0.25f;
    sc[m] = d;
    mx = fmaxf(mx, d);
  }
  float sum = 0.f;
#pragma unroll
  for (int m = 0; m < 24; m++) { float e = __expf(sc[m] - mx); sc[m] = e; sum += e; }
  float inv = 1.f / sum;
  float4 o0 = {0,0,0,0}, o1 = {0,0,0,0}, o2 = {0,0,0,0}, o3 = {0,0,0,0};
#pragma unroll
  for (int m = 0; m < 24; m++) {
    const float4* vr = (const float4*)(s + m * 388 + 256 + hh * 16);
    float4 v0 = vr[0], v1 = vr[1], v2 = vr[2], v3 = vr[3];
    float w = sc[m];
    o0.x += w * v0.x; o0.y += w * v0.y; o0.z += w * v0.z; o0.w += w * v0.w;
    o1.x += w * v1.x; o1.y += w * v1.y; o1.z += w * v1.z; o1.w += w * v1.w;
    o2.x += w * v2.x; o2.y += w * v2.y; o2.z += w * v2.z; o2.w += w * v2.w;
    o3.x += w * v3.x; o3.y += w * v3.y; o3.z += w * v3.z; o3.w += w * v3.w;
  }
  float* orow = out + (size_t)p * kND + n * kD + hh * 16;
  o0.x *= inv; o0.y *= inv; o0.z *= inv; o0.w *= inv;
  o1.x *= inv; o1.y *= inv; o1.z *= inv; o1.w *= inv;
  o2.x *= inv; o2.y *= inv; o2.z *= inv; o2.w *= inv;
  o3.x *= inv; o3.y *= inv; o3.z *= inv; o3.w *= inv;
  *(float4*)(orow)      = o0;
  *(float4*)(orow + 4)  = o1;
  *(float4*)(orow + 8)  = o2;
  *(float4*)(orow + 12) = o3;
}

// ---------------------------------------------------------------------------
// Temporal attention via MFMA. qkv bf16 (n, p, 768): temporal q at 384+h*16+e,
// k at 512+h*16+e, v at 640+h*16+e. One block per (b,n,h), 128 threads (2 waves).
// Qs/Ks rows padded to 40 ushorts (80 B) -> b128 fragment reads at bank floor.
// ---------------------------------------------------------------------------
__global__ __launch_bounds__(128) void t_attn_mfma(
    const bf16* __restrict__ qkv, bf16* __restrict__ ot)
{
  int g = blockIdx.x;
  int hh = g & 7, n = (g >> 3) % 24, b = g / 192;
  __shared__ __align__(16) ushort Qs[128][40];    // 10 KB, cols 16..31 zero
  __shared__ __align__(16) ushort Ks[128][40];    // 10 KB
  __shared__ __align__(16) ushort Vt[16][136];    // V^T [e][s], padded
  __shared__ __align__(16) ushort Ps[128][136];   // P [t][s], padded

  for (int idx = threadIdx.x; idx < 256; idx += 128) {
    int t = idx >> 1, e8 = (idx & 1) * 8;
    const ushort* src = (const ushort*)qkv +
        ((size_t)n * kP + (size_t)t * kB + b) * 768 + 384 + hh * 16 + e8;
    uint4 q = *(const uint4*)(src);
    uint4 k = *(const uint4*)(src + 128);
    uint4 v = *(const uint4*)(src + 256);
    *(uint4*)&Qs[t][e8] = q;
    *(uint4*)&Ks[t][e8] = k;
    *(uint4*)&Qs[t][16 + e8] = make_uint4(0, 0, 0, 0);
    *(uint4*)&Ks[t][16 + e8] = make_uint4(0, 0, 0, 0);
    const ushort* vp = (const ushort*)&v;
#pragma unroll
    for (int j = 0; j < 8; j++) Vt[e8 + j][t] = vp[j];
  }
  __syncthreads();

  int lane = threadIdx.x & 63, w = threadIdx.x >> 6;
  int c = lane & 15, quad = lane >> 4;

  // S = Q K^T
  bf16x8 aq[4];
#pragma unroll
  for (int mt = 0; mt < 4; mt++)
    aq[mt] = *(const bf16x8*)&Qs[w * 64 + mt * 16 + c][quad * 8];
  f32x4 acc[4][8];
#pragma unroll
  for (int nt = 0; nt < 8; nt++) {
    bf16x8 bk = *(const bf16x8*)&Ks[nt * 16 + c][quad * 8];
#pragma unroll
    for (int mt = 0; mt < 4; mt++) {
      f32x4 z = {0.f, 0.f, 0.f, 0.f};
      acc[mt][nt] = __builtin_amdgcn_mfma_f32_16x16x32_bf16(aq[mt], bk, z, 0, 0, 0);
    }
  }

  // softmax per row; rows t = w*64 + mt*16 + quad*4 + r, cols s = nt*16 + c
  f32x4 invv[4];
#pragma unroll
  for (int mt = 0; mt < 4; mt++) {
    int tbase = w * 64 + mt * 16 + quad * 4;
    f32x4 rm = {-1e30f, -1e30f, -1e30f, -1e30f};
#pragma unroll
    for (int nt = 0; nt < 8; nt++) {
      int s = nt * 16 + c;
#pragma unroll
      for (int r = 0; r < 4; r++) {
        float x = acc[mt][nt][r] * 0.25f + ((s < tbase + r) ? 1.f : 0.f);
        acc[mt][nt][r] = x;
        rm[r] = fmaxf(rm[r], x);
      }
    }
#pragma unroll
    for (int off = 1; off < 16; off <<= 1)
#pragma unroll
      for (int r = 0; r < 4; r++) rm[r] = fmaxf(rm[r], __shfl_xor(rm[r], off, 64));
    f32x4 rs = {0.f, 0.f, 0.f, 0.f};
#pragma unroll
    for (int nt = 0; nt < 8; nt++)
#pragma unroll
      for (int r = 0; r < 4; r++) {
        float pp = __expf(acc[mt][nt][r] - rm[r]);
        acc[mt][nt][r] = pp;
        rs[r] += pp;
      }
#pragma unroll
    for (int off = 1; off < 16; off <<= 1)
#pragma unroll
      for (int r = 0; r < 4; r++) rs[r] += __shfl_xor(rs[r], off, 64);
#pragma unroll
    for (int r = 0; r < 4; r++) invv[mt][r] = 1.f / rs[r];
#pragma unroll
    for (int nt = 0; nt < 8; nt++)
#pragma unroll
      for (int r = 0; r < 4; r++) {
        bf16 pb = __float2bfloat16(acc[mt][nt][r]);
        Ps[tbase + r][nt * 16 + c] = *(ushort*)&pb;
      }
  }

  // O = P V (in-wave Ps reuse only)
  f32x4 o[4] = {};
#pragma unroll
  for (int ks = 0; ks < 128; ks += 32) {
    bf16x8 bv = *(const bf16x8*)&Vt[c][ks + quad * 8];
#pragma unroll
    for (int mt = 0; mt < 4; mt++) {
      bf16x8 ap = *(const bf16x8*)&Ps[w * 64 + mt * 16 + c][ks + quad * 8];
      o[mt] = __builtin_amdgcn_mfma_f32_16x16x32_bf16(ap, bv, o[mt], 0, 0, 0);
    }
  }

#pragma unroll
  for (int mt = 0; mt < 4; mt++) {
#pragma unroll
    for (int r = 0; r < 4; r++) {
      int t = w * 64 + mt * 16 + quad * 4 + r;
      float val = o[mt][r] * invv[mt][r];
      ot[((size_t)n * kP + (size_t)t * kB + b) * 128 + hh * 16 + c] = __float2bfloat16(val);
    }
  }
}

// ---------------------------------------------------------------------------
// Fused: a2 = LN(sp+h) + LN(tp+h); float4 traffic; writes a2 fp32 + bf16
// ---------------------------------------------------------------------------
__global__ __launch_bounds__(256) void fuse_a2_kernel(
    const float* __restrict__ sp, const float* __restrict__ tp,
    const float* __restrict__ h, const float* __restrict__ g,
    const float* __restrict__ be, float* __restrict__ a2, bf16* __restrict__ a2b)
{
  int row = blockIdx.x;
  const float4* s1p = (const float4*)(sp + (size_t)row * kND);
  const float4* s2p = (const float4*)(tp + (size_t)row * kND);
  const float4* hp  = (const float4*)(h  + (size_t)row * kND);
  float4 x1[3], x2[3];
  float sum1 = 0.f, sum2 = 0.f;
#pragma unroll
  for (int i = 0; i < 3; i++) {
    int c = threadIdx.x + 256 * i;
    float4 hv = hp[c], a = s1p[c], bb = s2p[c];
    a.x += hv.x; a.y += hv.y; a.z += hv.z; a.w += hv.w;
    bb.x += hv.x; bb.y += hv.y; bb.z += hv.z; bb.w += hv.w;
    x1[i] = a; x2[i] = bb;
    sum1 += a.x + a.y + a.z + a.w;
    sum2 += bb.x + bb.y + bb.z + bb.w;
  }
  __shared__ float red1[4], red2[4];
#pragma unroll
  for (int o = 32; o > 0; o >>= 1) { sum1 += __shfl_down(sum1, o, 64); sum2 += __shfl_down(sum2, o, 64); }
  int wid = threadIdx.x >> 6;
  if ((threadIdx.x & 63) == 0) { red1[wid] = sum1; red2[wid] = sum2; }
  __syncthreads();
  float mean1 = (red1[0] + red1[1] + red1[2] + red1[3]) * (1.f / kND);
  float mean2 = (red2[0] + red2[1] + red2[2] + red2[3]) * (1.f / kND);
  __syncthreads();
  float v1 = 0.f, v2 = 0.f;
#pragma unroll
  for (int i = 0; i < 3; i++) {
    float4 a = x1[i], bb = x2[i];
    v1 += (a.x - mean1) * (a.x - mean1) + (a.y - mean1) * (a.y - mean1)
        + (a.z - mean1) * (a.z - mean1) + (a.w - mean1) * (a.w - mean1);
    v2 += (bb.x - mean2) * (bb.x - mean2) + (bb.y - mean2) * (bb.y - mean2)
        + (bb.z - mean2) * (bb.z - mean2) + (bb.w - mean2) * (bb.w - mean2);
  }
#pragma unroll
  for (int o = 32; o > 0; o >>= 1) { v1 += __shfl_down(v1, o, 64); v2 += __shfl_down(v2, o, 64); }
  if ((threadIdx.x & 63) == 0) { red1[wid] = v1; red2[wid] = v2; }
  __syncthreads();
  float r1 = rsqrtf((red1[0] + red1[1] + red1[2] + red1[3]) * (1.f / kND) + 1e-5f);
  float r2 = rsqrtf((red2[0] + red2[1] + red2[2] + red2[3]) * (1.f / kND) + 1e-5f);
  const float4* g4 = (const float4*)g;
  const float4* b4 = (const float4*)be;
#pragma unroll
  for (int i = 0; i < 3; i++) {
    int c = threadIdx.x + 256 * i;
    float4 gc = g4[c], bc = b4[c];
    float4 a = x1[i], bb = x2[i], o;
    o.x = (a.x - mean1) * r1 * gc.x + bc.x + (bb.x - mean2) * r2 * gc.x + bc.x;
    o.y = (a.y - mean1) * r1 * gc.y + bc.y + (bb.y - mean2) * r2 * gc.y + bc.y;
    o.z = (a.z - mean1) * r1 * gc.z + bc.z + (bb.z - mean2) * r2 * gc.z + bc.z;
    o.w = (a.w - mean1) * r1 * gc.w + bc.w + (bb.w - mean2) * r2 * gc.w + bc.w;
    *(float4*)(a2 + (size_t)row * kND + c * 4) = o;
    union { bf16 h4[4]; uint2 v; } pk;
    pk.h4[0] = __float2bfloat16(o.x); pk.h4[1] = __float2bfloat16(o.y);
    pk.h4[2] = __float2bfloat16(o.z); pk.h4[3] = __float2bfloat16(o.w);
    *(uint2*)(a2b + (size_t)row * kND + c * 4) = pk.v;
  }
}

// out = LN(a + b); float4 traffic; writes fp32 + bf16
__global__ __launch_bounds__(256) void add_ln_dual_kernel(
    const float* __restrict__ a, const float* __restrict__ b,
    const float* __restrict__ g, const float* __restrict__ be,
    float* __restrict__ out, bf16* __restrict__ outb)
{
  int row = blockIdx.x;
  const float4* ar = (const float4*)(a + (size_t)row * kND);
  const float4* br = (const float4*)(b + (size_t)row * kND);
  float4 v[3];
  float s = 0.f;
#pragma unroll
  for (int i = 0; i < 3; i++) {
    int c = threadIdx.x + 256 * i;
    float4 x = ar[c], y = br[c];
    x.x += y.x; x.y += y.y; x.z += y.z; x.w += y.w;
    v[i] = x;
    s += x.x + x.y + x.z + x.w;
  }
  __shared__ float red[4];
#pragma unroll
  for (int o = 32; o > 0; o >>= 1) s += __shfl_down(s, o, 64);
  int wid = threadIdx.x >> 6;
  if ((threadIdx.x & 63) == 0) red[wid] = s;
  __syncthreads();
  float mean = (red[0] + red[1] + red[2] + red[3]) * (1.f / kND);
  __syncthreads();
  float vs = 0.f;
#pragma unroll
  for (int i = 0; i < 3; i++) {
    float4 x = v[i];
    vs += (x.x - mean) * (x.x - mean) + (x.y - mean) * (x.y - mean)
        + (x.z - mean) * (x.z - mean) + (x.w - mean) * (x.w - mean);
  }
#pragma unroll
  for (int o = 32; o > 0; o >>= 1) vs += __shfl_down(vs, o, 64);
  if ((threadIdx.x & 63) == 0) red[wid] = vs;
  __syncthreads();
  float rstd = rsqrtf((red[0] + red[1] + red[2] + red[3]) * (1.f / kND) + 1e-5f);
  const float4* g4 = (const float4*)g;
  const float4* b4 = (const float4*)be;
#pragma unroll
  for (int i = 0; i < 3; i++) {
    int c = threadIdx.x + 256 * i;
    float4 gc = g4[c], bc = b4[c], x = v[i], o;
    o.x = (x.x - mean) * rstd * gc.x + bc.x;
    o.y = (x.y - mean) * rstd * gc.y + bc.y;
    o.z = (x.z - mean) * rstd * gc.z + bc.z;
    o.w = (x.w - mean) * rstd * gc.w + bc.w;
    *(float4*)(out + (size_t)row * kND + c * 4) = o;
    union { bf16 h4[4]; uint2 v2; } pk;
    pk.h4[0] = __float2bfloat16(o.x); pk.h4[1] = __float2bfloat16(o.y);
    pk.h4[2] = __float2bfloat16(o.z); pk.h4[3] = __float2bfloat16(o.w);
    *(uint2*)(outb + (size_t)row * kND + c * 4) = pk.v2;
  }
}

// FF1 split-K reduce: f1b[i] = bf16(p0+p1+p2 + bias[col])
__global__ __launch_bounds__(256) void ff1_reduce_kernel(
    const float* __restrict__ part, const float* __restrict__ bias,
    bf16* __restrict__ out)
{
  int i4 = (blockIdx.x * 256 + threadIdx.x) * 4;   // grid covers kP*kFF/4
  const size_t S = (size_t)kP * kFF;
  float4 p0 = *(const float4*)(part + i4);
  float4 p1 = *(const float4*)(part + S + i4);
  float4 p2 = *(const float4*)(part + 2 * S + i4);
  int col = i4 & (kFF - 1);
  float4 bb = *(const float4*)(bias + col);
  union { bf16 h4[4]; uint2 v; } pk;
  pk.h4[0] = __float2bfloat16(p0.x + p1.x + p2.x + bb.x);
  pk.h4[1] = __float2bfloat16(p0.y + p1.y + p2.y + bb.y);
  pk.h4[2] = __float2bfloat16(p0.z + p1.z + p2.z + bb.z);
  pk.h4[3] = __float2bfloat16(p0.w + p1.w + p2.w + bb.w);
  *(uint2*)(out + i4) = pk.v;
}

// Final: out[b,t,c] = sum_z part[z][(t*B+b)*216+c] + fin_b[c] + inputs[b,t,c]
__global__ __launch_bounds__(256) void final_reduce_add_kernel(
    const float* __restrict__ part, const float* __restrict__ fin_b,
    const float* __restrict__ inp, float* __restrict__ out)
{
  int i = blockIdx.x * 256 + threadIdx.x;
  if (i >= kB * kT * kNM) return;
  int c = i % kNM;
  int rem = i / kNM;
  int t = rem % kT, b = rem / kT;
  size_t pi = (size_t)(t * kB + b) * kNM + c;
  const size_t S = (size_t)kP * kNM;
  float v = fin_b[c] + inp[i];
#pragma unroll
  for (int z = 0; z < 8; z++) v += part[z * S + pi];
  out[i] = v;
}

// ---------------------------------------------------------------------------
extern "C" void kernel_launch(void* const* d_in, const int* in_sizes, int n_in,
                              void* d_out, int out_size, void* d_ws, size_t ws_size,
                              hipStream_t stream)
{
  const float* inputs   = (const float*)d_in[0];
  const float* emb_W    = (const float*)d_in[1];
  const float* emb_b    = (const float*)d_in[2];
  const float* sp_Wq    = (const float*)d_in[3];
  const float* sp_bq    = (const float*)d_in[4];
  const float* sp_Wk    = (const float*)d_in[5];
  const float* sp_bk    = (const float*)d_in[6];
  const float* sp_Wv    = (const float*)d_in[7];
  const float* sp_bv    = (const float*)d_in[8];
  const float* tmp_Win  = (const float*)d_in[9];
  const float* tmp_bin  = (const float*)d_in[10];
  const float* tmp_Wout = (const float*)d_in[11];
  const float* tmp_bout = (const float*)d_in[12];
  const float* ff_W1    = (const float*)d_in[13];
  const float* ff_b1    = (const float*)d_in[14];
  const float* ff_W2    = (const float*)d_in[15];
  const float* ff_b2    = (const float*)d_in[16];
  const float* ln_g     = (const float*)d_in[17];
  const float* ln_b     = (const float*)d_in[18];
  const float* fin_W    = (const float*)d_in[19];
  const float* fin_b    = (const float*)d_in[20];
  float* out = (float*)d_out;

  // ---- workspace layout ----
  char* wp = (char*)d_ws;
  size_t off = 0;
  auto alloc = [&](size_t bytes) { void* p = wp + off; off += (bytes + 255) & ~(size_t)255; return p; };
  bf16* spW   = (bf16*)alloc((size_t)kL * 24 * 768 * 128 * 2);  // fused qkv weights
  bf16* toWb  = (bf16*)alloc((size_t)kL * 24 * 128 * 128 * 2);
  bf16* W1t   = (bf16*)alloc((size_t)kL * kFF * kND * 2);
  bf16* W2t   = (bf16*)alloc((size_t)kL * kND * kFF * 2);
  bf16* finWt = (bf16*)alloc((size_t)kNM * kND * 2);
  float* spbc = (float*)alloc((size_t)kL * 24 * 768 * 4);
  float* hb   = (float*)alloc((size_t)kP * kND * 4);
  bf16*  hbb  = (bf16*) alloc((size_t)kP * kND * 2);
  bf16*  qkvb = (bf16*) alloc((size_t)24 * kP * 768 * 2);   // fused spatial+temporal qkv
  float* sp   = (float*)alloc((size_t)kP * kND * 4);        // spatial out; FF1 partials
  float* tp   = (float*)alloc((size_t)kP * kND * 4);        // temporal out; FF2 out; final partials
  float* a2   = (float*)alloc((size_t)kP * kND * 4);
  bf16*  a2b  = (bf16*) alloc((size_t)kP * kND * 2);
  bf16*  f1b  = (bf16*) alloc((size_t)kP * kFF * 2);
  bf16*  otb  = (bf16*) alloc((size_t)24 * kP * 128 * 2);
  float* ffpart  = sp;   // 3 * kP*kFF fp32 = 12 MB (sp dead during FF)
  float* finpart = tp;   // 8 * kP*kNM fp32 = 6.9 MB (tp dead after loop)

  // ---- weight prep ----
  trans_cvt_kernel<<<dim3(kFF / 64, kND / 64, kL), 256, 0, stream>>>(
      ff_W1, W1t, kND, kFF, (long)kND * kFF, (long)kFF * kND);
  trans_cvt_kernel<<<dim3(kND / 64, kFF / 64, kL), 256, 0, stream>>>(
      ff_W2, W2t, kFF, kND, (long)kFF * kND, (long)kND * kFF);
  trans_cvt_kernel<<<dim3((kNM + 63) / 64, kND / 64, 1), 256, 0, stream>>>(
      fin_W, finWt, kND, kNM, 0L, 0L);
  cvt_kernel<<<(kL * 24 * 128 * 128 / 8) / 256, 256, 0, stream>>>(
      tmp_Wout, toWb, kL * 24 * 128 * 128);
  build_spW_kernel<<<(kL * 24 * 768 * 128 / 8) / 256, 256, 0, stream>>>(
      sp_Wq, sp_Wk, sp_Wv, tmp_Win, spW);
  build_spb_kernel<<<(kL * 24 * 768 + 255) / 256, 256, 0, stream>>>(
      sp_bq, sp_bk, sp_bv, tmp_bin, spbc);

  emb_kernel<<<kP, 256, 0, stream>>>(inputs, emb_W, emb_b, hb, hbb);

  for (int l = 0; l < kL; l++) {
    const float* lg = ln_g + (size_t)l * kND;
    const float* lb = ln_b + (size_t)l * kND;

    // fused spatial+temporal qkv: groups n; C = qkvb (n, p, 768) bf16
    mfma_gemm<128, 128, true><<<dim3(6, 8, 24), 256, 0, stream>>>(
        hbb, spW + (size_t)l * 24 * 768 * 128, spbc + (size_t)l * 24 * 768, qkvb,
        kP, 768, 128, /*ldB*/128, /*sAi*/kND, /*sCi*/768,
        /*offAg*/128, /*offBg*/768 * 128, /*offCg*/(long)kP * 768, /*sBg*/768);

    sp_attn_kernel<<<kP, 192, 0, stream>>>(qkvb, sp);
    t_attn_mfma<<<kB * 24 * 8, 128, 0, stream>>>(qkvb, otb);

    // temporal out-proj: 64x64 tiles -> 768 blocks (3 blocks/CU)
    mfma_gemm<64, 64, false><<<dim3(2, 16, 24), 256, 0, stream>>>(
        otb, toWb + (size_t)l * 24 * 128 * 128, tmp_bout + (size_t)l * 24 * 128, tp,
        kP, 128, 128, /*ldB*/128, /*sAi*/128, /*sCi*/kND,
        /*offAg*/(long)kP * 128, /*offBg*/128 * 128, /*offCg*/128, /*sBg*/128);

    fuse_a2_kernel<<<kP, 256, 0, stream>>>(sp, tp, hb, lg, lb, a2, a2b);

    // FF1 split-K=3: 768 blocks, K-chunk 1024, fp32 partials -> ffpart
    mfma_gemm<64, 64, false><<<dim3(kFF / 64, kP / 64, 3), 256, 0, stream>>>(
        a2b, W1t + (size_t)l * kFF * kND, nullptr, ffpart,
        kP, kFF, /*K*/kND / 3, /*ldB*/kND, /*sAi*/kND, /*sCi*/kFF,
        /*offAg*/kND / 3, /*offBg*/kND / 3, /*offCg*/(long)kP * kFF, /*sBg*/0);
    ff1_reduce_kernel<<<(kP * kFF / 4) / 256, 256, 0, stream>>>(
        ffpart, ff_b1 + (size_t)l * kFF, f1b);

    // FF2: 64x64 tiles -> 768 blocks
    mfma_gemm<64, 64, false><<<dim3(kND / 64, kP / 64, 1), 256, 0, stream>>>(
        f1b, W2t + (size_t)l * kND * kFF, ff_b2 + (size_t)l * kND, tp,
        kP, kND, kFF, /*ldB*/kFF, /*sAi*/kFF, /*sCi*/kND, 0, 0, 0, 0);

    add_ln_dual_kernel<<<kP, 256, 0, stream>>>(tp, a2, lg, lb, hb, hbb);
  }

  // final projection: split-K=8 (K-chunk 384) -> 512 blocks; fused reduce+residual
  mfma_gemm<64, 64, false><<<dim3((kNM + 63) / 64, kP / 64, 8), 256, 0, stream>>>(
      hbb, finWt, nullptr, finpart,
      kP, kNM, /*K*/kND / 8, /*ldB*/kND, /*sAi*/kND, /*sCi*/kNM,
      /*offAg*/kND / 8, /*offBg*/kND / 8, /*offCg*/(long)kP * kNM, /*sBg*/0);
  final_reduce_add_kernel<<<(kB * kT * kNM + 255) / 256, 256, 0, stream>>>(
      finpart, fin_b, inputs, out);
}